// Round 10
// baseline (730.131 us; speedup 1.0000x reference)
//
#include <hip/hip_runtime.h>
#include <hip/hip_bf16.h>

#define D128 128

typedef __attribute__((ext_vector_type(8))) short bf16x8;
typedef __attribute__((ext_vector_type(4))) float f32x4;
typedef __attribute__((ext_vector_type(2))) float f32x2;
typedef unsigned int uint;
typedef unsigned short ushort_t;

union U4 { uint4 u; bf16x8 h; };
__device__ __forceinline__ bf16x8 as_h(uint4 u) { U4 x; x.u = u; return x.h; }

__device__ __forceinline__ short f2bf(float f) {
  union { float f; unsigned u; } v; v.f = f;
  unsigned r = v.u + 0x7FFFu + ((v.u >> 16) & 1u);  // RNE
  return (short)(r >> 16);
}
__device__ __forceinline__ float bf_lo(uint v) {
  union { uint u; float f; } x; x.u = v << 16; return x.f;
}
__device__ __forceinline__ float bf_hi(uint v) {
  union { uint u; float f; } x; x.u = v & 0xFFFF0000u; return x.f;
}
__device__ __forceinline__ uint pack2(float a, float b) {
  return (uint)(unsigned short)f2bf(a) | ((uint)(unsigned short)f2bf(b) << 16);
}

// ---- 4 weight tensors in one launch (65536 f32 each = 16384 float4) ----
__global__ __launch_bounds__(256)
void cvtW_k(const float* __restrict__ w0, const float* __restrict__ w1,
            const float* __restrict__ w2, const float* __restrict__ w3,
            ushort_t* __restrict__ o0, ushort_t* __restrict__ o1,
            ushort_t* __restrict__ o2, ushort_t* __restrict__ o3) {
  int y = blockIdx.y;
  const float* in = y == 0 ? w0 : y == 1 ? w1 : y == 2 ? w2 : w3;
  ushort_t* out = y == 0 ? o0 : y == 1 ? o1 : y == 2 ? o2 : o3;
  int i = blockIdx.x * 256 + threadIdx.x;
  if (i >= 16384) return;
  float4 v = ((const float4*)in)[i];
  ushort4 o;
  o.x = (unsigned short)f2bf(v.x); o.y = (unsigned short)f2bf(v.y);
  o.z = (unsigned short)f2bf(v.z); o.w = (unsigned short)f2bf(v.w);
  ((ushort4*)out)[i] = o;
}

// ---- fused preprocessing: embedding cvt (BW-bound) + poscount (latency-bound)
//      in one launch; disjoint block ranges, overlapping pipes ----
__global__ __launch_bounds__(256)
void pre_k(const float* __restrict__ ia, const float* __restrict__ im,
           const float* __restrict__ id, ushort_t* __restrict__ oa,
           ushort_t* __restrict__ om, ushort_t* __restrict__ od,
           int na4, int nm4, int nd4, int nbC,
           const int* __restrict__ d0, const int* __restrict__ d1,
           const int* __restrict__ d2, const int* __restrict__ d3,
           int* __restrict__ cnt, int* __restrict__ pos,
           int nE, int nbE, int b0, int b1, int b2, int b3) {
  int bx = blockIdx.x, tid = threadIdx.x;
  if (bx < nbC) {
    int i = bx * 256 + tid;
    const float* in; ushort_t* out; int k;
    if (i < na4) { in = ia; out = oa; k = i; }
    else if (i < na4 + nm4) { in = im; out = om; k = i - na4; }
    else if (i < na4 + nm4 + nd4) { in = id; out = od; k = i - na4 - nm4; }
    else return;
    float4 v = ((const float4*)in)[k];
    ushort4 o;
    o.x = (unsigned short)f2bf(v.x); o.y = (unsigned short)f2bf(v.y);
    o.z = (unsigned short)f2bf(v.z); o.w = (unsigned short)f2bf(v.w);
    ((ushort4*)out)[k] = o;
  } else {
    int r = bx - nbC;
    int y = r / nbE;
    int i = (r - y * nbE) * 256 + tid;
    if (i >= nE) return;
    const int* d = y == 0 ? d0 : y == 1 ? d1 : y == 2 ? d2 : d3;
    int base = y == 0 ? b0 : y == 1 ? b1 : y == 2 ? b2 : b3;
    int p = atomicAdd(&cnt[base + d[i]], 1);
    pos[(size_t)y * nE + i] = p;
  }
}

// ---- scan stage 1 ----
__device__ __forceinline__ int wave_incl_scan(int v, int lane) {
#pragma unroll
  for (int off = 1; off < 64; off <<= 1) {
    int y = __shfl_up(v, off);
    if (lane >= off) v += y;
  }
  return v;
}

__global__ __launch_bounds__(256) void scan1_k(const int* __restrict__ cnt,
                                               int* __restrict__ bsum, int n) {
  int b = blockIdx.x, tid = threadIdx.x;
  int i = b * 256 + tid;
  int v = (i < n) ? cnt[i] : 0;
  int lane = tid & 63, wid = tid >> 6;
  __shared__ int ws[4];
  int s = wave_incl_scan(v, lane);
  if (lane == 63) ws[wid] = s;
  __syncthreads();
  if (tid == 0) bsum[b] = ws[0] + ws[1] + ws[2] + ws[3];
}

// ---- scan stage 2 (+ inv fold) ----
__global__ __launch_bounds__(256) void scan2_k(const int* __restrict__ cnt,
                                               const int* __restrict__ bsum,
                                               int* __restrict__ ofs,
                                               float* __restrict__ inv, int n) {
  int b = blockIdx.x, tid = threadIdx.x;
  int lane = tid & 63, wid = tid >> 6;
  __shared__ int wsA[4], wsB[4];
  int p = 0;
  for (int j = tid; j < b; j += 256) p += bsum[j];
#pragma unroll
  for (int off = 32; off; off >>= 1) p += __shfl_xor(p, off);
  if (lane == 0) wsA[wid] = p;
  __syncthreads();
  int base = wsA[0] + wsA[1] + wsA[2] + wsA[3];
  int i = b * 256 + tid;
  int v = (i < n) ? cnt[i] : 0;
  int s = wave_incl_scan(v, lane);
  if (lane == 63) wsB[wid] = s;
  __syncthreads();
  int woff = 0;
  for (int w = 0; w < wid; w++) woff += wsB[w];
  int excl = base + woff + s - v;
  if (i < n) {
    ofs[i] = excl;
    inv[i] = 1.0f / (float)(v > 1 ? v : 1);
  }
}

// ---- reorder: bucket fill with NO atomics (uses precomputed pos) ----
__global__ __launch_bounds__(256)
void reorder4_k(const int* __restrict__ e0, const int* __restrict__ e1,
                const int* __restrict__ e2, const int* __restrict__ e3,
                const int* __restrict__ ofs, const int* __restrict__ pos,
                int* __restrict__ bucket,
                int nE, int b0, int b1, int b2, int b3) {
  int i = blockIdx.x * 256 + threadIdx.x;
  if (i >= nE) return;
  int y = blockIdx.y;
  const int* e = y == 0 ? e0 : y == 1 ? e1 : y == 2 ? e2 : e3;
  int base = y == 0 ? b0 : y == 1 ? b1 : y == 2 ? b2 : b3;
  int s = e[i];
  int d = e[nE + i];
  int p = pos[(size_t)y * nE + i];
  bucket[ofs[base + d] + p] = s;
}

// ---- dual CSR gather-mean: blockIdx.y selects independent job A or B ----
//  4 x 16-lane groups over edges, unroll-4 (16 rows in flight/wave),
//  f32x2 packed accumulation (v_pk_add_f32), inv folded, 256B row store.
struct GJob {
  const ushort_t* x;
  const int* ofs;
  const int* cnt;
  const float* inv;
  ushort_t* agg;
  int n;
};

template <int RELU>
__global__ __launch_bounds__(256)
void agg2_k(GJob A, GJob B, const int* __restrict__ bucket) {
  const GJob& J = blockIdx.y ? B : A;
  int w = (int)(((size_t)blockIdx.x * 256 + threadIdx.x) >> 6);
  int lane = threadIdx.x & 63;
  if (w >= J.n) return;
  int g = lane >> 4, sl = lane & 15;
  int beg = J.ofs[w], c = J.cnt[w];
  float iv = J.inv[w];
  const ushort_t* xsrc = J.x;
  f32x2 a0 = {0.f, 0.f}, a1 = {0.f, 0.f}, a2 = {0.f, 0.f}, a3 = {0.f, 0.f};

  auto accum = [&](uint4 v) {
    f32x2 p0 = {bf_lo(v.x), bf_hi(v.x)};
    f32x2 p1 = {bf_lo(v.y), bf_hi(v.y)};
    f32x2 p2 = {bf_lo(v.z), bf_hi(v.z)};
    f32x2 p3 = {bf_lo(v.w), bf_hi(v.w)};
    if (RELU) {
      p0[0] = fmaxf(p0[0], 0.f); p0[1] = fmaxf(p0[1], 0.f);
      p1[0] = fmaxf(p1[0], 0.f); p1[1] = fmaxf(p1[1], 0.f);
      p2[0] = fmaxf(p2[0], 0.f); p2[1] = fmaxf(p2[1], 0.f);
      p3[0] = fmaxf(p3[0], 0.f); p3[1] = fmaxf(p3[1], 0.f);
    }
    a0 += p0; a1 += p1; a2 += p2; a3 += p3;
  };

  int j = g;
  for (; j + 12 < c; j += 16) {  // 4 edges per group in flight
    int s0 = bucket[beg + j];
    int s1 = bucket[beg + j + 4];
    int s2 = bucket[beg + j + 8];
    int s3 = bucket[beg + j + 12];
    uint4 v0 = *(const uint4*)(xsrc + (size_t)s0 * D128 + sl * 8);
    uint4 v1 = *(const uint4*)(xsrc + (size_t)s1 * D128 + sl * 8);
    uint4 v2 = *(const uint4*)(xsrc + (size_t)s2 * D128 + sl * 8);
    uint4 v3 = *(const uint4*)(xsrc + (size_t)s3 * D128 + sl * 8);
    accum(v0); accum(v1); accum(v2); accum(v3);
  }
  for (; j < c; j += 4) {
    int s0 = bucket[beg + j];
    uint4 v0 = *(const uint4*)(xsrc + (size_t)s0 * D128 + sl * 8);
    accum(v0);
  }

#pragma unroll
  for (int off = 16; off <= 32; off <<= 1) {
    a0[0] += __shfl_xor(a0[0], off); a0[1] += __shfl_xor(a0[1], off);
    a1[0] += __shfl_xor(a1[0], off); a1[1] += __shfl_xor(a1[1], off);
    a2[0] += __shfl_xor(a2[0], off); a2[1] += __shfl_xor(a2[1], off);
    a3[0] += __shfl_xor(a3[0], off); a3[1] += __shfl_xor(a3[1], off);
  }
  if (g == 0) {
    uint4 o;
    o.x = pack2(a0[0] * iv, a0[1] * iv);
    o.y = pack2(a1[0] * iv, a1[1] * iv);
    o.z = pack2(a2[0] * iv, a2[1] * iv);
    o.w = pack2(a3[0] * iv, a3[1] * iv);
    *(uint4*)(J.agg + (size_t)w * D128 + sl * 8) = o;
  }
}

// ---- fused SAGE transform (single edge type), LDS-staged weights ----
//  (unchanged -- proven since R5)
template <int XBF, int ACC, int BFOUT, int OUTRELU, int CLF>
__global__ __launch_bounds__(512)
void sage5(const ushort_t* __restrict__ agg, const void* __restrict__ xv,
           const ushort_t* __restrict__ wl, const ushort_t* __restrict__ wr,
           const float* __restrict__ bias, const float* __restrict__ prevf,
           const float* __restrict__ clfW, const float* __restrict__ clfb,
           void* __restrict__ outv, int ntiles) {
  extern __shared__ char smem[];  // 65536 = 2 x (128x128 bf16) swizzled
  const int tid = threadIdx.x;

  for (int c = tid; c < 4096; c += 512) {
    int m = c >> 11, cc = c & 2047;
    int row = cc >> 4, slot = cc & 15;
    const ushort_t* W = m ? wr : wl;
    uint4 v = *((const uint4*)W + cc);
    *(uint4*)(smem + m * 32768 + row * 256 + ((slot ^ (row & 15)) << 4)) = v;
  }
  __syncthreads();

  int wid = tid >> 6, lane = tid & 63;
  int r = lane & 15, kh = lane >> 4;
  int tile = blockIdx.x * 8 + wid;
  if (tile >= ntiles) return;
  size_t n0 = (size_t)tile * 16;

  const ushort_t* ap = agg + (n0 + r) * D128 + kh * 8;
  uint4 A[4];
  bf16x8 XF[4];
#pragma unroll
  for (int kk = 0; kk < 4; kk++) A[kk] = *(const uint4*)(ap + kk * 32);
  if (XBF) {
    const ushort_t* xp = (const ushort_t*)xv + (n0 + r) * D128 + kh * 8;
#pragma unroll
    for (int kk = 0; kk < 4; kk++) XF[kk] = as_h(*(const uint4*)(xp + kk * 32));
  } else {
    const float* xp = (const float*)xv + (n0 + r) * D128 + kh * 8;
#pragma unroll
    for (int kk = 0; kk < 4; kk++) {
      f32x4 x0 = *(const f32x4*)(xp + kk * 32);
      f32x4 x1 = *(const f32x4*)(xp + kk * 32 + 4);
#pragma unroll
      for (int j = 0; j < 4; j++) {
        XF[kk][j] = f2bf(x0[j]);
        XF[kk][j + 4] = f2bf(x1[j]);
      }
    }
  }

  f32x4 acc[8];
#pragma unroll
  for (int t = 0; t < 8; t++) acc[t] = (f32x4){0.f, 0.f, 0.f, 0.f};

#pragma unroll
  for (int kk = 0; kk < 4; kk++) {
    int so = (((kk << 2) + kh) ^ r) << 4;
    bf16x8 af = as_h(A[kk]);
    bf16x8 xf = XF[kk];
#pragma unroll
    for (int t = 0; t < 8; t++) {
      const char* p = smem + t * 4096 + r * 256 + so;
      bf16x8 bwl = *(const bf16x8*)(p);
      bf16x8 bwr = *(const bf16x8*)(p + 32768);
      acc[t] = __builtin_amdgcn_mfma_f32_16x16x32_bf16(af, bwl, acc[t], 0, 0, 0);
      acc[t] = __builtin_amdgcn_mfma_f32_16x16x32_bf16(xf, bwr, acc[t], 0, 0, 0);
    }
  }

  float s[4] = {0.f, 0.f, 0.f, 0.f};
#pragma unroll
  for (int t = 0; t < 8; t++) {
    float bv = bias[t * 16 + r];
#pragma unroll
    for (int q = 0; q < 4; q++) {
      float c = acc[t][q] + bv;
      acc[t][q] = c;
      s[q] += c * c;
    }
  }
#pragma unroll
  for (int off = 1; off < 16; off <<= 1) {
#pragma unroll
    for (int q = 0; q < 4; q++) s[q] += __shfl_xor(s[q], off);
  }
  float rn[4];
#pragma unroll
  for (int q = 0; q < 4; q++) rn[q] = 1.0f / fmaxf(sqrtf(s[q]), 1e-12f);

  if (CLF) {
    float w0[8], w1[8];
#pragma unroll
    for (int t = 0; t < 8; t++) {
      w0[t] = clfW[t * 16 + r];
      w1[t] = clfW[D128 + t * 16 + r];
    }
    float p0[4] = {0.f, 0.f, 0.f, 0.f}, p1[4] = {0.f, 0.f, 0.f, 0.f};
#pragma unroll
    for (int t = 0; t < 8; t++) {
#pragma unroll
      for (int q = 0; q < 4; q++) {
        float val = acc[t][q] * rn[q];
        if (ACC) {
          size_t node = n0 + kh * 4 + q;
          val += prevf[node * D128 + t * 16 + r];
        }
        p0[q] += val * w0[t];
        p1[q] += val * w1[t];
      }
    }
#pragma unroll
    for (int off = 1; off < 16; off <<= 1) {
#pragma unroll
      for (int q = 0; q < 4; q++) {
        p0[q] += __shfl_xor(p0[q], off);
        p1[q] += __shfl_xor(p1[q], off);
      }
    }
    if (r == 0) {
      float cb0 = clfb[0], cb1 = clfb[1];
#pragma unroll
      for (int q = 0; q < 4; q++) {
        size_t node = n0 + kh * 4 + q;
        float2 o; o.x = p0[q] + cb0; o.y = p1[q] + cb1;
        *(float2*)((float*)outv + node * 2) = o;
      }
    }
  } else {
#pragma unroll
    for (int t = 0; t < 8; t++) {
#pragma unroll
      for (int q = 0; q < 4; q++) {
        float val = acc[t][q] * rn[q];
        size_t node = n0 + kh * 4 + q;
        if (ACC) val += prevf[node * D128 + t * 16 + r];
        if (OUTRELU) val = fmaxf(val, 0.f);
        if (BFOUT) {
          float pv = __shfl_xor(val, 1);
          if ((r & 1) == 0)
            *(uint*)((ushort_t*)outv + node * D128 + t * 16 + r) = pack2(val, pv);
        } else {
          ((float*)outv)[node * D128 + t * 16 + r] = val;
        }
      }
    }
  }
}

// ---- dual SAGE: two independent (XBF=1, BFOUT=1, OUTRELU=1) jobs ----
struct SJob {
  const ushort_t* agg;
  const ushort_t* x;
  const ushort_t* wl;
  const ushort_t* wr;
  const float* bias;
  ushort_t* out;
  int ntiles;
};

__global__ __launch_bounds__(512)
void sage_pair(SJob A, SJob B) {
  extern __shared__ char smem[];
  const SJob& J = blockIdx.y ? B : A;
  const int tid = threadIdx.x;

  for (int c = tid; c < 4096; c += 512) {
    int m = c >> 11, cc = c & 2047;
    int row = cc >> 4, slot = cc & 15;
    const ushort_t* W = m ? J.wr : J.wl;
    uint4 v = *((const uint4*)W + cc);
    *(uint4*)(smem + m * 32768 + row * 256 + ((slot ^ (row & 15)) << 4)) = v;
  }
  __syncthreads();

  int wid = tid >> 6, lane = tid & 63;
  int r = lane & 15, kh = lane >> 4;
  int tile = blockIdx.x * 8 + wid;
  if (tile >= J.ntiles) return;
  size_t n0 = (size_t)tile * 16;

  const ushort_t* ap = J.agg + (n0 + r) * D128 + kh * 8;
  const ushort_t* xp = J.x + (n0 + r) * D128 + kh * 8;
  uint4 A4[4], X4[4];
#pragma unroll
  for (int kk = 0; kk < 4; kk++) {
    A4[kk] = *(const uint4*)(ap + kk * 32);
    X4[kk] = *(const uint4*)(xp + kk * 32);
  }

  f32x4 acc[8];
#pragma unroll
  for (int t = 0; t < 8; t++) acc[t] = (f32x4){0.f, 0.f, 0.f, 0.f};

#pragma unroll
  for (int kk = 0; kk < 4; kk++) {
    int so = (((kk << 2) + kh) ^ r) << 4;
    bf16x8 af = as_h(A4[kk]);
    bf16x8 xf = as_h(X4[kk]);
#pragma unroll
    for (int t = 0; t < 8; t++) {
      const char* p = smem + t * 4096 + r * 256 + so;
      bf16x8 bwl = *(const bf16x8*)(p);
      bf16x8 bwr = *(const bf16x8*)(p + 32768);
      acc[t] = __builtin_amdgcn_mfma_f32_16x16x32_bf16(af, bwl, acc[t], 0, 0, 0);
      acc[t] = __builtin_amdgcn_mfma_f32_16x16x32_bf16(xf, bwr, acc[t], 0, 0, 0);
    }
  }

  float s[4] = {0.f, 0.f, 0.f, 0.f};
#pragma unroll
  for (int t = 0; t < 8; t++) {
    float bv = J.bias[t * 16 + r];
#pragma unroll
    for (int q = 0; q < 4; q++) {
      float c = acc[t][q] + bv;
      acc[t][q] = c;
      s[q] += c * c;
    }
  }
#pragma unroll
  for (int off = 1; off < 16; off <<= 1) {
#pragma unroll
    for (int q = 0; q < 4; q++) s[q] += __shfl_xor(s[q], off);
  }
  float rn[4];
#pragma unroll
  for (int q = 0; q < 4; q++) rn[q] = 1.0f / fmaxf(sqrtf(s[q]), 1e-12f);

#pragma unroll
  for (int t = 0; t < 8; t++) {
#pragma unroll
    for (int q = 0; q < 4; q++) {
      float val = fmaxf(acc[t][q] * rn[q], 0.f);
      float pv = __shfl_xor(val, 1);
      if ((r & 1) == 0) {
        size_t node = n0 + kh * 4 + q;
        *(uint*)(J.out + node * D128 + t * 16 + r) = pack2(val, pv);
      }
    }
  }
}

extern "C" void kernel_launch(void* const* d_in, const int* in_sizes, int n_in,
                              void* d_out, int out_size, void* d_ws, size_t ws_size,
                              hipStream_t stream) {
  const float* emb_app = (const float*)d_in[0];
  const float* emb_mer = (const float*)d_in[1];
  const float* emb_dev = (const float*)d_in[2];
  const float* c1Wl = (const float*)d_in[3];
  const float* c1bl = (const float*)d_in[4];
  const float* c1Wr = (const float*)d_in[5];
  const float* c2Wl = (const float*)d_in[6];
  const float* c2bl = (const float*)d_in[7];
  const float* c2Wr = (const float*)d_in[8];
  const float* clfW = (const float*)d_in[9];
  const float* clfb = (const float*)d_in[10];
  const int* e0 = (const int*)d_in[11];
  const int* e1 = (const int*)d_in[12];
  const int* e2 = (const int*)d_in[13];
  const int* e3 = (const int*)d_in[14];

  const int NA = in_sizes[0] / D128;
  const int NM = in_sizes[1] / D128;
  const int ND = in_sizes[2] / D128;
  const int E = in_sizes[11] / 2;
  float* out = (float*)d_out;

  char* wsb = (char*)d_ws;
  size_t off = 0;
  auto alloc = [&](size_t bytes) -> char* {
    char* p = wsb + off;
    off += (bytes + 511) & ~(size_t)511;
    return p;
  };
  ushort_t* wl1 = (ushort_t*)alloc((size_t)4 * 16384 * 2);
  ushort_t* wr1 = (ushort_t*)alloc((size_t)4 * 16384 * 2);
  ushort_t* wl2 = (ushort_t*)alloc((size_t)4 * 16384 * 2);
  ushort_t* wr2 = (ushort_t*)alloc((size_t)4 * 16384 * 2);

  // overlay: L1 = [emer | edev | eapp] bf16, L2 = h2a f32 (proven R9)
  size_t embBytes = ((size_t)NM + ND + NA) * D128 * 2;
  size_t h2aBytes = (size_t)NA * D128 * 4;
  char* big = alloc(embBytes > h2aBytes ? embBytes : h2aBytes);
  ushort_t* emer = (ushort_t*)big;
  ushort_t* edev = emer + (size_t)NM * D128;
  ushort_t* eapp = edev + (size_t)ND * D128;
  float* h2a = (float*)big;

  ushort_t* h1m = (ushort_t*)alloc((size_t)NM * D128 * 2);
  ushort_t* h1d = (ushort_t*)alloc((size_t)ND * D128 * 2);
  float* h1a = (float*)alloc((size_t)NA * D128 * 4);
  ushort_t* aggA = (ushort_t*)alloc((size_t)NA * D128 * 2);
  ushort_t* aggB = (ushort_t*)alloc((size_t)NA * D128 * 2);
  int ncnt = NM + NA + ND + NA;
  int nb = (ncnt + 255) / 256;
  int* cnt = (int*)alloc((size_t)ncnt * 4);
  float* inv = (float*)alloc((size_t)ncnt * 4);
  int* ofs = (int*)alloc((size_t)ncnt * 4);
  int* bsum = (int*)alloc((size_t)nb * 4);
  int* pos = (int*)alloc((size_t)4 * E * 4);
  int* bucket = (int*)alloc((size_t)4 * E * 4);
  (void)ws_size;  // ~369 MB total (R9-proven)

  int b0 = 0, b1 = NM, b2 = NM + NA, b3 = NM + NA + ND;

  const int SMEM = 65536;
  hipFuncSetAttribute((const void*)sage5<1, 0, 1, 0, 0>,
                      hipFuncAttributeMaxDynamicSharedMemorySize, SMEM);
  hipFuncSetAttribute((const void*)sage5<1, 0, 0, 0, 0>,
                      hipFuncAttributeMaxDynamicSharedMemorySize, SMEM);
  hipFuncSetAttribute((const void*)sage5<1, 1, 0, 1, 0>,
                      hipFuncAttributeMaxDynamicSharedMemorySize, SMEM);
  hipFuncSetAttribute((const void*)sage5<0, 0, 0, 0, 0>,
                      hipFuncAttributeMaxDynamicSharedMemorySize, SMEM);
  hipFuncSetAttribute((const void*)sage5<0, 1, 0, 0, 1>,
                      hipFuncAttributeMaxDynamicSharedMemorySize, SMEM);
  hipFuncSetAttribute((const void*)sage_pair,
                      hipFuncAttributeMaxDynamicSharedMemorySize, SMEM);

  // ---- weights cvt + fused {embedding cvt, poscount} ----
  dim3 wg(64, 4);
  cvtW_k<<<wg, 256, 0, stream>>>(c1Wl, c1Wr, c2Wl, c2Wr, wl1, wr1, wl2, wr2);
  hipMemsetAsync(cnt, 0, (size_t)ncnt * 4, stream);
  int na4 = NA * 32, nm4 = NM * 32, nd4 = ND * 32;
  int nbC = (na4 + nm4 + nd4 + 255) / 256;
  int nbE = (E + 255) / 256;
  pre_k<<<nbC + 4 * nbE, 256, 0, stream>>>(
      emb_app, emb_mer, emb_dev, eapp, emer, edev, na4, nm4, nd4, nbC,
      e0 + E, e1 + E, e2 + E, e3 + E, cnt, pos, E, nbE, b0, b1, b2, b3);
  scan1_k<<<nb, 256, 0, stream>>>(cnt, bsum, ncnt);
  scan2_k<<<nb, 256, 0, stream>>>(cnt, bsum, ofs, inv, ncnt);
  dim3 eg(nbE, 4);
  reorder4_k<<<eg, 256, 0, stream>>>(e0, e1, e2, e3, ofs, pos, bucket,
                                     E, b0, b1, b2, b3);

  auto wgrid = [](int n) { return (n + 3) / 4; };
  auto g8 = [](int nt) { return (nt + 7) / 8; };
  int tA = NA / 16, tM = NM / 16, tD = ND / 16;

  auto J = [&](const ushort_t* x, int b, ushort_t* a, int n) {
    GJob j; j.x = x; j.ofs = ofs + b; j.cnt = cnt + b; j.inv = inv + b;
    j.agg = a; j.n = n; return j;
  };

  // ---- layer 1 ----
  {
    dim3 gg(wgrid(NM > ND ? NM : ND), 2);
    agg2_k<0><<<gg, 256, 0, stream>>>(J(eapp, b0, aggA, NM), J(eapp, b2, aggB, ND), bucket);
  }
  {
    SJob SA; SA.agg = aggA; SA.x = emer; SA.wl = wl1 + 0 * 16384;
    SA.wr = wr1 + 0 * 16384; SA.bias = c1bl + 0 * D128; SA.out = h1m; SA.ntiles = tM;
    SJob SB; SB.agg = aggB; SB.x = edev; SB.wl = wl1 + 2 * 16384;
    SB.wr = wr1 + 2 * 16384; SB.bias = c1bl + 2 * D128; SB.out = h1d; SB.ntiles = tD;
    dim3 sg(g8(tM > tD ? tM : tD), 2);
    sage_pair<<<sg, 512, SMEM, stream>>>(SA, SB);
  }
  {
    dim3 gg(wgrid(NA), 2);
    agg2_k<0><<<gg, 256, 0, stream>>>(J(emer, b1, aggA, NA), J(edev, b3, aggB, NA), bucket);
  }
  sage5<1, 0, 0, 0, 0><<<g8(tA), 512, SMEM, stream>>>(aggA, eapp,
      wl1 + 1 * 16384, wr1 + 1 * 16384, c1bl + 1 * D128, nullptr, nullptr, nullptr, h1a, tA);
  sage5<1, 1, 0, 1, 0><<<g8(tA), 512, SMEM, stream>>>(aggB, eapp,
      wl1 + 3 * 16384, wr1 + 3 * 16384, c1bl + 3 * D128, h1a, nullptr, nullptr, h1a, tA);

  // ---- layer 2 (dst=app only; `big` region reused as h2a) ----
  {
    dim3 gg(wgrid(NA), 2);
    agg2_k<1><<<gg, 256, 0, stream>>>(J(h1m, b1, aggA, NA), J(h1d, b3, aggB, NA), bucket);
  }
  sage5<0, 0, 0, 0, 0><<<g8(tA), 512, SMEM, stream>>>(aggA, h1a,
      wl2 + 1 * 16384, wr2 + 1 * 16384, c2bl + 1 * D128, nullptr, nullptr, nullptr, h2a, tA);
  sage5<0, 1, 0, 0, 1><<<g8(tA), 512, SMEM, stream>>>(aggB, h1a,
      wl2 + 3 * 16384, wr2 + 3 * 16384, c2bl + 3 * D128, h2a, clfW, clfb, out, tA);
}

// Round 11
// 690.794 us; speedup vs baseline: 1.0569x; 1.0569x over previous
//
#include <hip/hip_runtime.h>
#include <hip/hip_bf16.h>

#define D128 128

typedef __attribute__((ext_vector_type(8))) short bf16x8;
typedef __attribute__((ext_vector_type(4))) float f32x4;
typedef __attribute__((ext_vector_type(2))) float f32x2;
typedef unsigned int uint;
typedef unsigned short ushort_t;

union U4 { uint4 u; bf16x8 h; };
__device__ __forceinline__ bf16x8 as_h(uint4 u) { U4 x; x.u = u; return x.h; }

__device__ __forceinline__ short f2bf(float f) {
  union { float f; unsigned u; } v; v.f = f;
  unsigned r = v.u + 0x7FFFu + ((v.u >> 16) & 1u);  // RNE
  return (short)(r >> 16);
}
__device__ __forceinline__ float bf_lo(uint v) {
  union { uint u; float f; } x; x.u = v << 16; return x.f;
}
__device__ __forceinline__ float bf_hi(uint v) {
  union { uint u; float f; } x; x.u = v & 0xFFFF0000u; return x.f;
}
__device__ __forceinline__ uint pack2(float a, float b) {
  return (uint)(unsigned short)f2bf(a) | ((uint)(unsigned short)f2bf(b) << 16);
}

// ---- 4 weight tensors in one launch (65536 f32 each = 16384 float4) ----
__global__ __launch_bounds__(256)
void cvtW_k(const float* __restrict__ w0, const float* __restrict__ w1,
            const float* __restrict__ w2, const float* __restrict__ w3,
            ushort_t* __restrict__ o0, ushort_t* __restrict__ o1,
            ushort_t* __restrict__ o2, ushort_t* __restrict__ o3) {
  int y = blockIdx.y;
  const float* in = y == 0 ? w0 : y == 1 ? w1 : y == 2 ? w2 : w3;
  ushort_t* out = y == 0 ? o0 : y == 1 ? o1 : y == 2 ? o2 : o3;
  int i = blockIdx.x * 256 + threadIdx.x;
  if (i >= 16384) return;
  float4 v = ((const float4*)in)[i];
  ushort4 o;
  o.x = (unsigned short)f2bf(v.x); o.y = (unsigned short)f2bf(v.y);
  o.z = (unsigned short)f2bf(v.z); o.w = (unsigned short)f2bf(v.w);
  ((ushort4*)out)[i] = o;
}

// ---- fused preprocessing, INTERLEAVED block mapping:
//  cvt blocks (BW-bound) and poscount blocks (atomic-latency, 4 edges/thread)
//  are proportionally interleaved so both kinds are co-resident on the CUs
//  and the atomic stalls hide under the conversion bandwidth. ----
__global__ __launch_bounds__(256)
void pre2_k(const float* __restrict__ ia, const float* __restrict__ im,
            const float* __restrict__ id, ushort_t* __restrict__ oa,
            ushort_t* __restrict__ om, ushort_t* __restrict__ od,
            int na4, int nm4, int nd4, int nbC,
            const int* __restrict__ d0, const int* __restrict__ d1,
            const int* __restrict__ d2, const int* __restrict__ d3,
            int* __restrict__ cnt, int* __restrict__ pos,
            int nE, int nbE4, int nbA,
            int b0, int b1, int b2, int b3) {
  int bx = blockIdx.x, tid = threadIdx.x;
  int total = nbC + nbA;
  long long s = ((long long)bx * nbA) / total;
  long long t = ((long long)(bx + 1) * nbA) / total;
  if (t > s) {
    // atomic task: block index s in [0, nbA); 4 edges/thread (MLP)
    int ab = (int)s;
    int y = ab / nbE4;
    int blk = ab - y * nbE4;
    const int* d = y == 0 ? d0 : y == 1 ? d1 : y == 2 ? d2 : d3;
    int base = y == 0 ? b0 : y == 1 ? b1 : y == 2 ? b2 : b3;
#pragma unroll
    for (int u = 0; u < 4; u++) {
      int i = blk * 1024 + u * 256 + tid;
      if (i < nE) {
        int p = atomicAdd(&cnt[base + d[i]], 1);
        pos[(size_t)y * nE + i] = p;
      }
    }
  } else {
    // cvt task: block index bx - s in [0, nbC)
    int i = (int)(bx - s) * 256 + tid;
    const float* in; ushort_t* out; int k;
    if (i < na4) { in = ia; out = oa; k = i; }
    else if (i < na4 + nm4) { in = im; out = om; k = i - na4; }
    else if (i < na4 + nm4 + nd4) { in = id; out = od; k = i - na4 - nm4; }
    else return;
    float4 v = ((const float4*)in)[k];
    ushort4 o;
    o.x = (unsigned short)f2bf(v.x); o.y = (unsigned short)f2bf(v.y);
    o.z = (unsigned short)f2bf(v.z); o.w = (unsigned short)f2bf(v.w);
    ((ushort4*)out)[k] = o;
  }
}

// ---- scan stage 1 ----
__device__ __forceinline__ int wave_incl_scan(int v, int lane) {
#pragma unroll
  for (int off = 1; off < 64; off <<= 1) {
    int y = __shfl_up(v, off);
    if (lane >= off) v += y;
  }
  return v;
}

__global__ __launch_bounds__(256) void scan1_k(const int* __restrict__ cnt,
                                               int* __restrict__ bsum, int n) {
  int b = blockIdx.x, tid = threadIdx.x;
  int i = b * 256 + tid;
  int v = (i < n) ? cnt[i] : 0;
  int lane = tid & 63, wid = tid >> 6;
  __shared__ int ws[4];
  int s = wave_incl_scan(v, lane);
  if (lane == 63) ws[wid] = s;
  __syncthreads();
  if (tid == 0) bsum[b] = ws[0] + ws[1] + ws[2] + ws[3];
}

// ---- scan stage 2 (+ inv fold) ----
__global__ __launch_bounds__(256) void scan2_k(const int* __restrict__ cnt,
                                               const int* __restrict__ bsum,
                                               int* __restrict__ ofs,
                                               float* __restrict__ inv, int n) {
  int b = blockIdx.x, tid = threadIdx.x;
  int lane = tid & 63, wid = tid >> 6;
  __shared__ int wsA[4], wsB[4];
  int p = 0;
  for (int j = tid; j < b; j += 256) p += bsum[j];
#pragma unroll
  for (int off = 32; off; off >>= 1) p += __shfl_xor(p, off);
  if (lane == 0) wsA[wid] = p;
  __syncthreads();
  int base = wsA[0] + wsA[1] + wsA[2] + wsA[3];
  int i = b * 256 + tid;
  int v = (i < n) ? cnt[i] : 0;
  int s = wave_incl_scan(v, lane);
  if (lane == 63) wsB[wid] = s;
  __syncthreads();
  int woff = 0;
  for (int w = 0; w < wid; w++) woff += wsB[w];
  int excl = base + woff + s - v;
  if (i < n) {
    ofs[i] = excl;
    inv[i] = 1.0f / (float)(v > 1 ? v : 1);
  }
}

// ---- reorder: bucket fill with NO atomics, 2 edges/thread ----
__global__ __launch_bounds__(256)
void reorder4_k(const int* __restrict__ e0, const int* __restrict__ e1,
                const int* __restrict__ e2, const int* __restrict__ e3,
                const int* __restrict__ ofs, const int* __restrict__ pos,
                int* __restrict__ bucket,
                int nE, int b0, int b1, int b2, int b3) {
  int y = blockIdx.y;
  const int* e = y == 0 ? e0 : y == 1 ? e1 : y == 2 ? e2 : e3;
  int base = y == 0 ? b0 : y == 1 ? b1 : y == 2 ? b2 : b3;
#pragma unroll
  for (int u = 0; u < 2; u++) {
    int i = blockIdx.x * 512 + u * 256 + threadIdx.x;
    if (i < nE) {
      int s = e[i];
      int d = e[nE + i];
      int p = pos[(size_t)y * nE + i];
      bucket[ofs[base + d] + p] = s;
    }
  }
}

// ---- dual CSR gather-mean: blockIdx.y selects independent job A or B ----
//  4 x 16-lane groups over edges, unroll-4 (16 rows in flight/wave),
//  f32x2 packed accumulation, inv folded, 256B row store. (R10-proven)
struct GJob {
  const ushort_t* x;
  const int* ofs;
  const int* cnt;
  const float* inv;
  ushort_t* agg;
  int n;
};

template <int RELU>
__global__ __launch_bounds__(256)
void agg2_k(GJob A, GJob B, const int* __restrict__ bucket) {
  const GJob& J = blockIdx.y ? B : A;
  int w = (int)(((size_t)blockIdx.x * 256 + threadIdx.x) >> 6);
  int lane = threadIdx.x & 63;
  if (w >= J.n) return;
  int g = lane >> 4, sl = lane & 15;
  int beg = J.ofs[w], c = J.cnt[w];
  float iv = J.inv[w];
  const ushort_t* xsrc = J.x;
  f32x2 a0 = {0.f, 0.f}, a1 = {0.f, 0.f}, a2 = {0.f, 0.f}, a3 = {0.f, 0.f};

  auto accum = [&](uint4 v) {
    f32x2 p0 = {bf_lo(v.x), bf_hi(v.x)};
    f32x2 p1 = {bf_lo(v.y), bf_hi(v.y)};
    f32x2 p2 = {bf_lo(v.z), bf_hi(v.z)};
    f32x2 p3 = {bf_lo(v.w), bf_hi(v.w)};
    if (RELU) {
      p0[0] = fmaxf(p0[0], 0.f); p0[1] = fmaxf(p0[1], 0.f);
      p1[0] = fmaxf(p1[0], 0.f); p1[1] = fmaxf(p1[1], 0.f);
      p2[0] = fmaxf(p2[0], 0.f); p2[1] = fmaxf(p2[1], 0.f);
      p3[0] = fmaxf(p3[0], 0.f); p3[1] = fmaxf(p3[1], 0.f);
    }
    a0 += p0; a1 += p1; a2 += p2; a3 += p3;
  };

  int j = g;
  for (; j + 12 < c; j += 16) {
    int s0 = bucket[beg + j];
    int s1 = bucket[beg + j + 4];
    int s2 = bucket[beg + j + 8];
    int s3 = bucket[beg + j + 12];
    uint4 v0 = *(const uint4*)(xsrc + (size_t)s0 * D128 + sl * 8);
    uint4 v1 = *(const uint4*)(xsrc + (size_t)s1 * D128 + sl * 8);
    uint4 v2 = *(const uint4*)(xsrc + (size_t)s2 * D128 + sl * 8);
    uint4 v3 = *(const uint4*)(xsrc + (size_t)s3 * D128 + sl * 8);
    accum(v0); accum(v1); accum(v2); accum(v3);
  }
  for (; j < c; j += 4) {
    int s0 = bucket[beg + j];
    uint4 v0 = *(const uint4*)(xsrc + (size_t)s0 * D128 + sl * 8);
    accum(v0);
  }

#pragma unroll
  for (int off = 16; off <= 32; off <<= 1) {
    a0[0] += __shfl_xor(a0[0], off); a0[1] += __shfl_xor(a0[1], off);
    a1[0] += __shfl_xor(a1[0], off); a1[1] += __shfl_xor(a1[1], off);
    a2[0] += __shfl_xor(a2[0], off); a2[1] += __shfl_xor(a2[1], off);
    a3[0] += __shfl_xor(a3[0], off); a3[1] += __shfl_xor(a3[1], off);
  }
  if (g == 0) {
    uint4 o;
    o.x = pack2(a0[0] * iv, a0[1] * iv);
    o.y = pack2(a1[0] * iv, a1[1] * iv);
    o.z = pack2(a2[0] * iv, a2[1] * iv);
    o.w = pack2(a3[0] * iv, a3[1] * iv);
    *(uint4*)(J.agg + (size_t)w * D128 + sl * 8) = o;
  }
}

// ---- fused SAGE transform (single edge type), LDS-staged weights ----
//  (unchanged -- proven since R5)
template <int XBF, int ACC, int BFOUT, int OUTRELU, int CLF>
__global__ __launch_bounds__(512)
void sage5(const ushort_t* __restrict__ agg, const void* __restrict__ xv,
           const ushort_t* __restrict__ wl, const ushort_t* __restrict__ wr,
           const float* __restrict__ bias, const float* __restrict__ prevf,
           const float* __restrict__ clfW, const float* __restrict__ clfb,
           void* __restrict__ outv, int ntiles) {
  extern __shared__ char smem[];
  const int tid = threadIdx.x;

  for (int c = tid; c < 4096; c += 512) {
    int m = c >> 11, cc = c & 2047;
    int row = cc >> 4, slot = cc & 15;
    const ushort_t* W = m ? wr : wl;
    uint4 v = *((const uint4*)W + cc);
    *(uint4*)(smem + m * 32768 + row * 256 + ((slot ^ (row & 15)) << 4)) = v;
  }
  __syncthreads();

  int wid = tid >> 6, lane = tid & 63;
  int r = lane & 15, kh = lane >> 4;
  int tile = blockIdx.x * 8 + wid;
  if (tile >= ntiles) return;
  size_t n0 = (size_t)tile * 16;

  const ushort_t* ap = agg + (n0 + r) * D128 + kh * 8;
  uint4 A[4];
  bf16x8 XF[4];
#pragma unroll
  for (int kk = 0; kk < 4; kk++) A[kk] = *(const uint4*)(ap + kk * 32);
  if (XBF) {
    const ushort_t* xp = (const ushort_t*)xv + (n0 + r) * D128 + kh * 8;
#pragma unroll
    for (int kk = 0; kk < 4; kk++) XF[kk] = as_h(*(const uint4*)(xp + kk * 32));
  } else {
    const float* xp = (const float*)xv + (n0 + r) * D128 + kh * 8;
#pragma unroll
    for (int kk = 0; kk < 4; kk++) {
      f32x4 x0 = *(const f32x4*)(xp + kk * 32);
      f32x4 x1 = *(const f32x4*)(xp + kk * 32 + 4);
#pragma unroll
      for (int j = 0; j < 4; j++) {
        XF[kk][j] = f2bf(x0[j]);
        XF[kk][j + 4] = f2bf(x1[j]);
      }
    }
  }

  f32x4 acc[8];
#pragma unroll
  for (int t = 0; t < 8; t++) acc[t] = (f32x4){0.f, 0.f, 0.f, 0.f};

#pragma unroll
  for (int kk = 0; kk < 4; kk++) {
    int so = (((kk << 2) + kh) ^ r) << 4;
    bf16x8 af = as_h(A[kk]);
    bf16x8 xf = XF[kk];
#pragma unroll
    for (int t = 0; t < 8; t++) {
      const char* p = smem + t * 4096 + r * 256 + so;
      bf16x8 bwl = *(const bf16x8*)(p);
      bf16x8 bwr = *(const bf16x8*)(p + 32768);
      acc[t] = __builtin_amdgcn_mfma_f32_16x16x32_bf16(af, bwl, acc[t], 0, 0, 0);
      acc[t] = __builtin_amdgcn_mfma_f32_16x16x32_bf16(xf, bwr, acc[t], 0, 0, 0);
    }
  }

  float s[4] = {0.f, 0.f, 0.f, 0.f};
#pragma unroll
  for (int t = 0; t < 8; t++) {
    float bv = bias[t * 16 + r];
#pragma unroll
    for (int q = 0; q < 4; q++) {
      float c = acc[t][q] + bv;
      acc[t][q] = c;
      s[q] += c * c;
    }
  }
#pragma unroll
  for (int off = 1; off < 16; off <<= 1) {
#pragma unroll
    for (int q = 0; q < 4; q++) s[q] += __shfl_xor(s[q], off);
  }
  float rn[4];
#pragma unroll
  for (int q = 0; q < 4; q++) rn[q] = 1.0f / fmaxf(sqrtf(s[q]), 1e-12f);

  if (CLF) {
    float w0[8], w1[8];
#pragma unroll
    for (int t = 0; t < 8; t++) {
      w0[t] = clfW[t * 16 + r];
      w1[t] = clfW[D128 + t * 16 + r];
    }
    float p0[4] = {0.f, 0.f, 0.f, 0.f}, p1[4] = {0.f, 0.f, 0.f, 0.f};
#pragma unroll
    for (int t = 0; t < 8; t++) {
#pragma unroll
      for (int q = 0; q < 4; q++) {
        float val = acc[t][q] * rn[q];
        if (ACC) {
          size_t node = n0 + kh * 4 + q;
          val += prevf[node * D128 + t * 16 + r];
        }
        p0[q] += val * w0[t];
        p1[q] += val * w1[t];
      }
    }
#pragma unroll
    for (int off = 1; off < 16; off <<= 1) {
#pragma unroll
      for (int q = 0; q < 4; q++) {
        p0[q] += __shfl_xor(p0[q], off);
        p1[q] += __shfl_xor(p1[q], off);
      }
    }
    if (r == 0) {
      float cb0 = clfb[0], cb1 = clfb[1];
#pragma unroll
      for (int q = 0; q < 4; q++) {
        size_t node = n0 + kh * 4 + q;
        float2 o; o.x = p0[q] + cb0; o.y = p1[q] + cb1;
        *(float2*)((float*)outv + node * 2) = o;
      }
    }
  } else {
#pragma unroll
    for (int t = 0; t < 8; t++) {
#pragma unroll
      for (int q = 0; q < 4; q++) {
        float val = acc[t][q] * rn[q];
        size_t node = n0 + kh * 4 + q;
        if (ACC) val += prevf[node * D128 + t * 16 + r];
        if (OUTRELU) val = fmaxf(val, 0.f);
        if (BFOUT) {
          float pv = __shfl_xor(val, 1);
          if ((r & 1) == 0)
            *(uint*)((ushort_t*)outv + node * D128 + t * 16 + r) = pack2(val, pv);
        } else {
          ((float*)outv)[node * D128 + t * 16 + r] = val;
        }
      }
    }
  }
}

// ---- dual SAGE: two independent (XBF=1, BFOUT=1, OUTRELU=1) jobs ----
struct SJob {
  const ushort_t* agg;
  const ushort_t* x;
  const ushort_t* wl;
  const ushort_t* wr;
  const float* bias;
  ushort_t* out;
  int ntiles;
};

__global__ __launch_bounds__(512)
void sage_pair(SJob A, SJob B) {
  extern __shared__ char smem[];
  const SJob& J = blockIdx.y ? B : A;
  const int tid = threadIdx.x;

  for (int c = tid; c < 4096; c += 512) {
    int m = c >> 11, cc = c & 2047;
    int row = cc >> 4, slot = cc & 15;
    const ushort_t* W = m ? J.wr : J.wl;
    uint4 v = *((const uint4*)W + cc);
    *(uint4*)(smem + m * 32768 + row * 256 + ((slot ^ (row & 15)) << 4)) = v;
  }
  __syncthreads();

  int wid = tid >> 6, lane = tid & 63;
  int r = lane & 15, kh = lane >> 4;
  int tile = blockIdx.x * 8 + wid;
  if (tile >= J.ntiles) return;
  size_t n0 = (size_t)tile * 16;

  const ushort_t* ap = J.agg + (n0 + r) * D128 + kh * 8;
  const ushort_t* xp = J.x + (n0 + r) * D128 + kh * 8;
  uint4 A4[4], X4[4];
#pragma unroll
  for (int kk = 0; kk < 4; kk++) {
    A4[kk] = *(const uint4*)(ap + kk * 32);
    X4[kk] = *(const uint4*)(xp + kk * 32);
  }

  f32x4 acc[8];
#pragma unroll
  for (int t = 0; t < 8; t++) acc[t] = (f32x4){0.f, 0.f, 0.f, 0.f};

#pragma unroll
  for (int kk = 0; kk < 4; kk++) {
    int so = (((kk << 2) + kh) ^ r) << 4;
    bf16x8 af = as_h(A4[kk]);
    bf16x8 xf = as_h(X4[kk]);
#pragma unroll
    for (int t = 0; t < 8; t++) {
      const char* p = smem + t * 4096 + r * 256 + so;
      bf16x8 bwl = *(const bf16x8*)(p);
      bf16x8 bwr = *(const bf16x8*)(p + 32768);
      acc[t] = __builtin_amdgcn_mfma_f32_16x16x32_bf16(af, bwl, acc[t], 0, 0, 0);
      acc[t] = __builtin_amdgcn_mfma_f32_16x16x32_bf16(xf, bwr, acc[t], 0, 0, 0);
    }
  }

  float s[4] = {0.f, 0.f, 0.f, 0.f};
#pragma unroll
  for (int t = 0; t < 8; t++) {
    float bv = J.bias[t * 16 + r];
#pragma unroll
    for (int q = 0; q < 4; q++) {
      float c = acc[t][q] + bv;
      acc[t][q] = c;
      s[q] += c * c;
    }
  }
#pragma unroll
  for (int off = 1; off < 16; off <<= 1) {
#pragma unroll
    for (int q = 0; q < 4; q++) s[q] += __shfl_xor(s[q], off);
  }
  float rn[4];
#pragma unroll
  for (int q = 0; q < 4; q++) rn[q] = 1.0f / fmaxf(sqrtf(s[q]), 1e-12f);

#pragma unroll
  for (int t = 0; t < 8; t++) {
#pragma unroll
    for (int q = 0; q < 4; q++) {
      float val = fmaxf(acc[t][q] * rn[q], 0.f);
      float pv = __shfl_xor(val, 1);
      if ((r & 1) == 0) {
        size_t node = n0 + kh * 4 + q;
        *(uint*)(J.out + node * D128 + t * 16 + r) = pack2(val, pv);
      }
    }
  }
}

extern "C" void kernel_launch(void* const* d_in, const int* in_sizes, int n_in,
                              void* d_out, int out_size, void* d_ws, size_t ws_size,
                              hipStream_t stream) {
  const float* emb_app = (const float*)d_in[0];
  const float* emb_mer = (const float*)d_in[1];
  const float* emb_dev = (const float*)d_in[2];
  const float* c1Wl = (const float*)d_in[3];
  const float* c1bl = (const float*)d_in[4];
  const float* c1Wr = (const float*)d_in[5];
  const float* c2Wl = (const float*)d_in[6];
  const float* c2bl = (const float*)d_in[7];
  const float* c2Wr = (const float*)d_in[8];
  const float* clfW = (const float*)d_in[9];
  const float* clfb = (const float*)d_in[10];
  const int* e0 = (const int*)d_in[11];
  const int* e1 = (const int*)d_in[12];
  const int* e2 = (const int*)d_in[13];
  const int* e3 = (const int*)d_in[14];

  const int NA = in_sizes[0] / D128;
  const int NM = in_sizes[1] / D128;
  const int ND = in_sizes[2] / D128;
  const int E = in_sizes[11] / 2;
  float* out = (float*)d_out;

  char* wsb = (char*)d_ws;
  size_t off = 0;
  auto alloc = [&](size_t bytes) -> char* {
    char* p = wsb + off;
    off += (bytes + 511) & ~(size_t)511;
    return p;
  };
  ushort_t* wl1 = (ushort_t*)alloc((size_t)4 * 16384 * 2);
  ushort_t* wr1 = (ushort_t*)alloc((size_t)4 * 16384 * 2);
  ushort_t* wl2 = (ushort_t*)alloc((size_t)4 * 16384 * 2);
  ushort_t* wr2 = (ushort_t*)alloc((size_t)4 * 16384 * 2);

  // overlay: L1 = [emer | edev | eapp] bf16, L2 = h2a f32 (proven R9)
  size_t embBytes = ((size_t)NM + ND + NA) * D128 * 2;
  size_t h2aBytes = (size_t)NA * D128 * 4;
  char* big = alloc(embBytes > h2aBytes ? embBytes : h2aBytes);
  ushort_t* emer = (ushort_t*)big;
  ushort_t* edev = emer + (size_t)NM * D128;
  ushort_t* eapp = edev + (size_t)ND * D128;
  float* h2a = (float*)big;

  ushort_t* h1m = (ushort_t*)alloc((size_t)NM * D128 * 2);
  ushort_t* h1d = (ushort_t*)alloc((size_t)ND * D128 * 2);
  float* h1a = (float*)alloc((size_t)NA * D128 * 4);
  ushort_t* aggA = (ushort_t*)alloc((size_t)NA * D128 * 2);
  ushort_t* aggB = (ushort_t*)alloc((size_t)NA * D128 * 2);
  int ncnt = NM + NA + ND + NA;
  int nb = (ncnt + 255) / 256;
  int* cnt = (int*)alloc((size_t)ncnt * 4);
  float* inv = (float*)alloc((size_t)ncnt * 4);
  int* ofs = (int*)alloc((size_t)ncnt * 4);
  int* bsum = (int*)alloc((size_t)nb * 4);
  int* pos = (int*)alloc((size_t)4 * E * 4);
  int* bucket = (int*)alloc((size_t)4 * E * 4);
  (void)ws_size;  // ~369 MB total (R9-proven)

  int b0 = 0, b1 = NM, b2 = NM + NA, b3 = NM + NA + ND;

  const int SMEM = 65536;
  hipFuncSetAttribute((const void*)sage5<1, 0, 0, 0, 0>,
                      hipFuncAttributeMaxDynamicSharedMemorySize, SMEM);
  hipFuncSetAttribute((const void*)sage5<1, 1, 0, 1, 0>,
                      hipFuncAttributeMaxDynamicSharedMemorySize, SMEM);
  hipFuncSetAttribute((const void*)sage5<0, 0, 0, 0, 0>,
                      hipFuncAttributeMaxDynamicSharedMemorySize, SMEM);
  hipFuncSetAttribute((const void*)sage5<0, 1, 0, 0, 1>,
                      hipFuncAttributeMaxDynamicSharedMemorySize, SMEM);
  hipFuncSetAttribute((const void*)sage_pair,
                      hipFuncAttributeMaxDynamicSharedMemorySize, SMEM);

  // ---- weights cvt + interleaved {embedding cvt ∥ poscount} ----
  dim3 wg(64, 4);
  cvtW_k<<<wg, 256, 0, stream>>>(c1Wl, c1Wr, c2Wl, c2Wr, wl1, wr1, wl2, wr2);
  hipMemsetAsync(cnt, 0, (size_t)ncnt * 4, stream);
  int na4 = NA * 32, nm4 = NM * 32, nd4 = ND * 32;
  int nbC = (na4 + nm4 + nd4 + 255) / 256;
  int nbE4 = (E + 1023) / 1024;
  int nbA = 4 * nbE4;
  pre2_k<<<nbC + nbA, 256, 0, stream>>>(
      emb_app, emb_mer, emb_dev, eapp, emer, edev, na4, nm4, nd4, nbC,
      e0 + E, e1 + E, e2 + E, e3 + E, cnt, pos, E, nbE4, nbA, b0, b1, b2, b3);
  scan1_k<<<nb, 256, 0, stream>>>(cnt, bsum, ncnt);
  scan2_k<<<nb, 256, 0, stream>>>(cnt, bsum, ofs, inv, ncnt);
  dim3 eg((E + 511) / 512, 4);
  reorder4_k<<<eg, 256, 0, stream>>>(e0, e1, e2, e3, ofs, pos, bucket,
                                     E, b0, b1, b2, b3);

  auto wgrid = [](int n) { return (n + 3) / 4; };
  auto g8 = [](int nt) { return (nt + 7) / 8; };
  int tA = NA / 16, tM = NM / 16, tD = ND / 16;

  auto J = [&](const ushort_t* x, int b, ushort_t* a, int n) {
    GJob j; j.x = x; j.ofs = ofs + b; j.cnt = cnt + b; j.inv = inv + b;
    j.agg = a; j.n = n; return j;
  };

  // ---- layer 1 ----
  {
    dim3 gg(wgrid(NM > ND ? NM : ND), 2);
    agg2_k<0><<<gg, 256, 0, stream>>>(J(eapp, b0, aggA, NM), J(eapp, b2, aggB, ND), bucket);
  }
  {
    SJob SA; SA.agg = aggA; SA.x = emer; SA.wl = wl1 + 0 * 16384;
    SA.wr = wr1 + 0 * 16384; SA.bias = c1bl + 0 * D128; SA.out = h1m; SA.ntiles = tM;
    SJob SB; SB.agg = aggB; SB.x = edev; SB.wl = wl1 + 2 * 16384;
    SB.wr = wr1 + 2 * 16384; SB.bias = c1bl + 2 * D128; SB.out = h1d; SB.ntiles = tD;
    dim3 sg(g8(tM > tD ? tM : tD), 2);
    sage_pair<<<sg, 512, SMEM, stream>>>(SA, SB);
  }
  {
    dim3 gg(wgrid(NA), 2);
    agg2_k<0><<<gg, 256, 0, stream>>>(J(emer, b1, aggA, NA), J(edev, b3, aggB, NA), bucket);
  }
  sage5<1, 0, 0, 0, 0><<<g8(tA), 512, SMEM, stream>>>(aggA, eapp,
      wl1 + 1 * 16384, wr1 + 1 * 16384, c1bl + 1 * D128, nullptr, nullptr, nullptr, h1a, tA);
  sage5<1, 1, 0, 1, 0><<<g8(tA), 512, SMEM, stream>>>(aggB, eapp,
      wl1 + 3 * 16384, wr1 + 3 * 16384, c1bl + 3 * D128, h1a, nullptr, nullptr, h1a, tA);

  // ---- layer 2 (dst=app only; `big` region reused as h2a) ----
  {
    dim3 gg(wgrid(NA), 2);
    agg2_k<1><<<gg, 256, 0, stream>>>(J(h1m, b1, aggA, NA), J(h1d, b3, aggB, NA), bucket);
  }
  sage5<0, 0, 0, 0, 0><<<g8(tA), 512, SMEM, stream>>>(aggA, h1a,
      wl2 + 1 * 16384, wr2 + 1 * 16384, c2bl + 1 * D128, nullptr, nullptr, nullptr, h2a, tA);
  sage5<0, 1, 0, 0, 1><<<g8(tA), 512, SMEM, stream>>>(aggB, h1a,
      wl2 + 3 * 16384, wr2 + 3 * 16384, c2bl + 3 * D128, h2a, clfW, clfb, out, tA);
}

// Round 12
// 681.918 us; speedup vs baseline: 1.0707x; 1.0130x over previous
//
#include <hip/hip_runtime.h>
#include <hip/hip_bf16.h>

#define D128 128

typedef __attribute__((ext_vector_type(8))) short bf16x8;
typedef __attribute__((ext_vector_type(4))) float f32x4;
typedef __attribute__((ext_vector_type(2))) float f32x2;
typedef unsigned int uint;
typedef unsigned short ushort_t;

union U4 { uint4 u; bf16x8 h; };
__device__ __forceinline__ bf16x8 as_h(uint4 u) { U4 x; x.u = u; return x.h; }

__device__ __forceinline__ short f2bf(float f) {
  union { float f; unsigned u; } v; v.f = f;
  unsigned r = v.u + 0x7FFFu + ((v.u >> 16) & 1u);  // RNE
  return (short)(r >> 16);
}
__device__ __forceinline__ float bf_lo(uint v) {
  union { uint u; float f; } x; x.u = v << 16; return x.f;
}
__device__ __forceinline__ float bf_hi(uint v) {
  union { uint u; float f; } x; x.u = v & 0xFFFF0000u; return x.f;
}
__device__ __forceinline__ uint pack2(float a, float b) {
  return (uint)(unsigned short)f2bf(a) | ((uint)(unsigned short)f2bf(b) << 16);
}

// ---- 4 weight tensors in one launch (65536 f32 each = 16384 float4) ----
__global__ __launch_bounds__(256)
void cvtW_k(const float* __restrict__ w0, const float* __restrict__ w1,
            const float* __restrict__ w2, const float* __restrict__ w3,
            ushort_t* __restrict__ o0, ushort_t* __restrict__ o1,
            ushort_t* __restrict__ o2, ushort_t* __restrict__ o3) {
  int y = blockIdx.y;
  const float* in = y == 0 ? w0 : y == 1 ? w1 : y == 2 ? w2 : w3;
  ushort_t* out = y == 0 ? o0 : y == 1 ? o1 : y == 2 ? o2 : o3;
  int i = blockIdx.x * 256 + threadIdx.x;
  if (i >= 16384) return;
  float4 v = ((const float4*)in)[i];
  ushort4 o;
  o.x = (unsigned short)f2bf(v.x); o.y = (unsigned short)f2bf(v.y);
  o.z = (unsigned short)f2bf(v.z); o.w = (unsigned short)f2bf(v.w);
  ((ushort4*)out)[i] = o;
}

// ---- fused preprocessing, interleaved cvt ∥ poscount (R11-proven) ----
__global__ __launch_bounds__(256)
void pre2_k(const float* __restrict__ ia, const float* __restrict__ im,
            const float* __restrict__ id, ushort_t* __restrict__ oa,
            ushort_t* __restrict__ om, ushort_t* __restrict__ od,
            int na4, int nm4, int nd4, int nbC,
            const int* __restrict__ d0, const int* __restrict__ d1,
            const int* __restrict__ d2, const int* __restrict__ d3,
            int* __restrict__ cnt, int* __restrict__ pos,
            int nE, int nbE4, int nbA,
            int b0, int b1, int b2, int b3) {
  int bx = blockIdx.x, tid = threadIdx.x;
  int total = nbC + nbA;
  long long s = ((long long)bx * nbA) / total;
  long long t = ((long long)(bx + 1) * nbA) / total;
  if (t > s) {
    int ab = (int)s;
    int y = ab / nbE4;
    int blk = ab - y * nbE4;
    const int* d = y == 0 ? d0 : y == 1 ? d1 : y == 2 ? d2 : d3;
    int base = y == 0 ? b0 : y == 1 ? b1 : y == 2 ? b2 : b3;
#pragma unroll
    for (int u = 0; u < 4; u++) {
      int i = blk * 1024 + u * 256 + tid;
      if (i < nE) {
        int p = atomicAdd(&cnt[base + d[i]], 1);
        pos[(size_t)y * nE + i] = p;
      }
    }
  } else {
    int i = (int)(bx - s) * 256 + tid;
    const float* in; ushort_t* out; int k;
    if (i < na4) { in = ia; out = oa; k = i; }
    else if (i < na4 + nm4) { in = im; out = om; k = i - na4; }
    else if (i < na4 + nm4 + nd4) { in = id; out = od; k = i - na4 - nm4; }
    else return;
    float4 v = ((const float4*)in)[k];
    ushort4 o;
    o.x = (unsigned short)f2bf(v.x); o.y = (unsigned short)f2bf(v.y);
    o.z = (unsigned short)f2bf(v.z); o.w = (unsigned short)f2bf(v.w);
    ((ushort4*)out)[k] = o;
  }
}

// ---- scan stage 1 ----
__device__ __forceinline__ int wave_incl_scan(int v, int lane) {
#pragma unroll
  for (int off = 1; off < 64; off <<= 1) {
    int y = __shfl_up(v, off);
    if (lane >= off) v += y;
  }
  return v;
}

__global__ __launch_bounds__(256) void scan1_k(const int* __restrict__ cnt,
                                               int* __restrict__ bsum, int n) {
  int b = blockIdx.x, tid = threadIdx.x;
  int i = b * 256 + tid;
  int v = (i < n) ? cnt[i] : 0;
  int lane = tid & 63, wid = tid >> 6;
  __shared__ int ws[4];
  int s = wave_incl_scan(v, lane);
  if (lane == 63) ws[wid] = s;
  __syncthreads();
  if (tid == 0) bsum[b] = ws[0] + ws[1] + ws[2] + ws[3];
}

// ---- scan stage 2 (+ inv fold) ----
__global__ __launch_bounds__(256) void scan2_k(const int* __restrict__ cnt,
                                               const int* __restrict__ bsum,
                                               int* __restrict__ ofs,
                                               float* __restrict__ inv, int n) {
  int b = blockIdx.x, tid = threadIdx.x;
  int lane = tid & 63, wid = tid >> 6;
  __shared__ int wsA[4], wsB[4];
  int p = 0;
  for (int j = tid; j < b; j += 256) p += bsum[j];
#pragma unroll
  for (int off = 32; off; off >>= 1) p += __shfl_xor(p, off);
  if (lane == 0) wsA[wid] = p;
  __syncthreads();
  int base = wsA[0] + wsA[1] + wsA[2] + wsA[3];
  int i = b * 256 + tid;
  int v = (i < n) ? cnt[i] : 0;
  int s = wave_incl_scan(v, lane);
  if (lane == 63) wsB[wid] = s;
  __syncthreads();
  int woff = 0;
  for (int w = 0; w < wid; w++) woff += wsB[w];
  int excl = base + woff + s - v;
  if (i < n) {
    ofs[i] = excl;
    inv[i] = 1.0f / (float)(v > 1 ? v : 1);
  }
}

// ---- reorder: bucket fill with NO atomics, 2 edges/thread ----
__global__ __launch_bounds__(256)
void reorder4_k(const int* __restrict__ e0, const int* __restrict__ e1,
                const int* __restrict__ e2, const int* __restrict__ e3,
                const int* __restrict__ ofs, const int* __restrict__ pos,
                int* __restrict__ bucket,
                int nE, int b0, int b1, int b2, int b3) {
  int y = blockIdx.y;
  const int* e = y == 0 ? e0 : y == 1 ? e1 : y == 2 ? e2 : e3;
  int base = y == 0 ? b0 : y == 1 ? b1 : y == 2 ? b2 : b3;
#pragma unroll
  for (int u = 0; u < 2; u++) {
    int i = blockIdx.x * 512 + u * 256 + threadIdx.x;
    if (i < nE) {
      int s = e[i];
      int d = e[nE + i];
      int p = pos[(size_t)y * nE + i];
      bucket[ofs[base + d] + p] = s;
    }
  }
}

// ---- dual CSR gather-mean, degree-specialized ----
//  SERIAL=0 (high degree): 4 x 16-lane groups, unroll-2, butterfly (R9 form)
//  SERIAL=1 (degree ~2.5): one wave covers the full 256B row (uint/lane),
//     serial unroll-2 over edges, NO cross-lane reduction.
struct GJob {
  const ushort_t* x;
  const int* ofs;
  const int* cnt;
  const float* inv;
  ushort_t* agg;
  int n;
};

template <int RELU, int SERIAL>
__global__ __launch_bounds__(256)
void agg2_k(GJob A, GJob B, const int* __restrict__ bucket) {
  const GJob& J = blockIdx.y ? B : A;
  int w = (int)(((size_t)blockIdx.x * 256 + threadIdx.x) >> 6);
  int lane = threadIdx.x & 63;
  if (w >= J.n) return;
  int beg = J.ofs[w], c = J.cnt[w];
  float iv = J.inv[w];

  if (SERIAL) {
    const uint* xs = (const uint*)J.x;  // row = 64 uints (256B)
    f32x2 acc = {0.f, 0.f};
    int j = 0;
    for (; j + 2 <= c; j += 2) {
      int s0 = bucket[beg + j], s1 = bucket[beg + j + 1];
      uint u0 = xs[(size_t)s0 * 64 + lane];
      uint u1 = xs[(size_t)s1 * 64 + lane];
      f32x2 p0 = {bf_lo(u0), bf_hi(u0)};
      f32x2 p1 = {bf_lo(u1), bf_hi(u1)};
      if (RELU) {
        p0[0] = fmaxf(p0[0], 0.f); p0[1] = fmaxf(p0[1], 0.f);
        p1[0] = fmaxf(p1[0], 0.f); p1[1] = fmaxf(p1[1], 0.f);
      }
      acc += p0; acc += p1;
    }
    if (j < c) {
      uint u0 = xs[(size_t)bucket[beg + j] * 64 + lane];
      f32x2 p0 = {bf_lo(u0), bf_hi(u0)};
      if (RELU) { p0[0] = fmaxf(p0[0], 0.f); p0[1] = fmaxf(p0[1], 0.f); }
      acc += p0;
    }
    ((uint*)J.agg)[(size_t)w * 64 + lane] = pack2(acc[0] * iv, acc[1] * iv);
  } else {
    int g = lane >> 4, sl = lane & 15;
    const ushort_t* xsrc = J.x;
    float a[8] = {0.f, 0.f, 0.f, 0.f, 0.f, 0.f, 0.f, 0.f};
    auto accum = [&](uint4 v) {
      float x0 = bf_lo(v.x), x1 = bf_hi(v.x), x2 = bf_lo(v.y), x3 = bf_hi(v.y);
      float x4 = bf_lo(v.z), x5 = bf_hi(v.z), x6 = bf_lo(v.w), x7 = bf_hi(v.w);
      if (RELU) {
        x0 = fmaxf(x0, 0.f); x1 = fmaxf(x1, 0.f); x2 = fmaxf(x2, 0.f); x3 = fmaxf(x3, 0.f);
        x4 = fmaxf(x4, 0.f); x5 = fmaxf(x5, 0.f); x6 = fmaxf(x6, 0.f); x7 = fmaxf(x7, 0.f);
      }
      a[0] += x0; a[1] += x1; a[2] += x2; a[3] += x3;
      a[4] += x4; a[5] += x5; a[6] += x6; a[7] += x7;
    };
    int j = g;
    for (; j + 4 < c; j += 8) {
      int s0 = bucket[beg + j];
      int s1 = bucket[beg + j + 4];
      uint4 v0 = *(const uint4*)(xsrc + (size_t)s0 * D128 + sl * 8);
      uint4 v1 = *(const uint4*)(xsrc + (size_t)s1 * D128 + sl * 8);
      accum(v0); accum(v1);
    }
    if (j < c) {
      uint4 v0 = *(const uint4*)(xsrc + (size_t)bucket[beg + j] * D128 + sl * 8);
      accum(v0);
    }
#pragma unroll
    for (int k = 0; k < 8; k++) {
      a[k] += __shfl_xor(a[k], 16);
      a[k] += __shfl_xor(a[k], 32);
    }
    if (g == 0) {
      uint4 o;
      o.x = pack2(a[0] * iv, a[1] * iv);
      o.y = pack2(a[2] * iv, a[3] * iv);
      o.z = pack2(a[4] * iv, a[5] * iv);
      o.w = pack2(a[6] * iv, a[7] * iv);
      *(uint4*)(J.agg + (size_t)w * D128 + sl * 8) = o;
    }
  }
}

// ---- fused SAGE transform (single edge type), LDS-staged weights ----
//  (unchanged -- proven since R5)
template <int XBF, int ACC, int BFOUT, int OUTRELU, int CLF>
__global__ __launch_bounds__(512)
void sage5(const ushort_t* __restrict__ agg, const void* __restrict__ xv,
           const ushort_t* __restrict__ wl, const ushort_t* __restrict__ wr,
           const float* __restrict__ bias, const float* __restrict__ prevf,
           const float* __restrict__ clfW, const float* __restrict__ clfb,
           void* __restrict__ outv, int ntiles) {
  extern __shared__ char smem[];
  const int tid = threadIdx.x;

  for (int c = tid; c < 4096; c += 512) {
    int m = c >> 11, cc = c & 2047;
    int row = cc >> 4, slot = cc & 15;
    const ushort_t* W = m ? wr : wl;
    uint4 v = *((const uint4*)W + cc);
    *(uint4*)(smem + m * 32768 + row * 256 + ((slot ^ (row & 15)) << 4)) = v;
  }
  __syncthreads();

  int wid = tid >> 6, lane = tid & 63;
  int r = lane & 15, kh = lane >> 4;
  int tile = blockIdx.x * 8 + wid;
  if (tile >= ntiles) return;
  size_t n0 = (size_t)tile * 16;

  const ushort_t* ap = agg + (n0 + r) * D128 + kh * 8;
  uint4 A[4];
  bf16x8 XF[4];
#pragma unroll
  for (int kk = 0; kk < 4; kk++) A[kk] = *(const uint4*)(ap + kk * 32);
  if (XBF) {
    const ushort_t* xp = (const ushort_t*)xv + (n0 + r) * D128 + kh * 8;
#pragma unroll
    for (int kk = 0; kk < 4; kk++) XF[kk] = as_h(*(const uint4*)(xp + kk * 32));
  } else {
    const float* xp = (const float*)xv + (n0 + r) * D128 + kh * 8;
#pragma unroll
    for (int kk = 0; kk < 4; kk++) {
      f32x4 x0 = *(const f32x4*)(xp + kk * 32);
      f32x4 x1 = *(const f32x4*)(xp + kk * 32 + 4);
#pragma unroll
      for (int j = 0; j < 4; j++) {
        XF[kk][j] = f2bf(x0[j]);
        XF[kk][j + 4] = f2bf(x1[j]);
      }
    }
  }

  f32x4 acc[8];
#pragma unroll
  for (int t = 0; t < 8; t++) acc[t] = (f32x4){0.f, 0.f, 0.f, 0.f};

#pragma unroll
  for (int kk = 0; kk < 4; kk++) {
    int so = (((kk << 2) + kh) ^ r) << 4;
    bf16x8 af = as_h(A[kk]);
    bf16x8 xf = XF[kk];
#pragma unroll
    for (int t = 0; t < 8; t++) {
      const char* p = smem + t * 4096 + r * 256 + so;
      bf16x8 bwl = *(const bf16x8*)(p);
      bf16x8 bwr = *(const bf16x8*)(p + 32768);
      acc[t] = __builtin_amdgcn_mfma_f32_16x16x32_bf16(af, bwl, acc[t], 0, 0, 0);
      acc[t] = __builtin_amdgcn_mfma_f32_16x16x32_bf16(xf, bwr, acc[t], 0, 0, 0);
    }
  }

  float s[4] = {0.f, 0.f, 0.f, 0.f};
#pragma unroll
  for (int t = 0; t < 8; t++) {
    float bv = bias[t * 16 + r];
#pragma unroll
    for (int q = 0; q < 4; q++) {
      float c = acc[t][q] + bv;
      acc[t][q] = c;
      s[q] += c * c;
    }
  }
#pragma unroll
  for (int off = 1; off < 16; off <<= 1) {
#pragma unroll
    for (int q = 0; q < 4; q++) s[q] += __shfl_xor(s[q], off);
  }
  float rn[4];
#pragma unroll
  for (int q = 0; q < 4; q++) rn[q] = 1.0f / fmaxf(sqrtf(s[q]), 1e-12f);

  if (CLF) {
    float w0[8], w1[8];
#pragma unroll
    for (int t = 0; t < 8; t++) {
      w0[t] = clfW[t * 16 + r];
      w1[t] = clfW[D128 + t * 16 + r];
    }
    float p0[4] = {0.f, 0.f, 0.f, 0.f}, p1[4] = {0.f, 0.f, 0.f, 0.f};
#pragma unroll
    for (int t = 0; t < 8; t++) {
#pragma unroll
      for (int q = 0; q < 4; q++) {
        float val = acc[t][q] * rn[q];
        if (ACC) {
          size_t node = n0 + kh * 4 + q;
          val += prevf[node * D128 + t * 16 + r];
        }
        p0[q] += val * w0[t];
        p1[q] += val * w1[t];
      }
    }
#pragma unroll
    for (int off = 1; off < 16; off <<= 1) {
#pragma unroll
      for (int q = 0; q < 4; q++) {
        p0[q] += __shfl_xor(p0[q], off);
        p1[q] += __shfl_xor(p1[q], off);
      }
    }
    if (r == 0) {
      float cb0 = clfb[0], cb1 = clfb[1];
#pragma unroll
      for (int q = 0; q < 4; q++) {
        size_t node = n0 + kh * 4 + q;
        float2 o; o.x = p0[q] + cb0; o.y = p1[q] + cb1;
        *(float2*)((float*)outv + node * 2) = o;
      }
    }
  } else {
#pragma unroll
    for (int t = 0; t < 8; t++) {
#pragma unroll
      for (int q = 0; q < 4; q++) {
        float val = acc[t][q] * rn[q];
        size_t node = n0 + kh * 4 + q;
        if (ACC) val += prevf[node * D128 + t * 16 + r];
        if (OUTRELU) val = fmaxf(val, 0.f);
        if (BFOUT) {
          float pv = __shfl_xor(val, 1);
          if ((r & 1) == 0)
            *(uint*)((ushort_t*)outv + node * D128 + t * 16 + r) = pack2(val, pv);
        } else {
          ((float*)outv)[node * D128 + t * 16 + r] = val;
        }
      }
    }
  }
}

// ---- dual SAGE: two independent (XBF=1, BFOUT=1, OUTRELU=1) jobs ----
struct SJob {
  const ushort_t* agg;
  const ushort_t* x;
  const ushort_t* wl;
  const ushort_t* wr;
  const float* bias;
  ushort_t* out;
  int ntiles;
};

__global__ __launch_bounds__(512)
void sage_pair(SJob A, SJob B) {
  extern __shared__ char smem[];
  const SJob& J = blockIdx.y ? B : A;
  const int tid = threadIdx.x;

  for (int c = tid; c < 4096; c += 512) {
    int m = c >> 11, cc = c & 2047;
    int row = cc >> 4, slot = cc & 15;
    const ushort_t* W = m ? J.wr : J.wl;
    uint4 v = *((const uint4*)W + cc);
    *(uint4*)(smem + m * 32768 + row * 256 + ((slot ^ (row & 15)) << 4)) = v;
  }
  __syncthreads();

  int wid = tid >> 6, lane = tid & 63;
  int r = lane & 15, kh = lane >> 4;
  int tile = blockIdx.x * 8 + wid;
  if (tile >= J.ntiles) return;
  size_t n0 = (size_t)tile * 16;

  const ushort_t* ap = J.agg + (n0 + r) * D128 + kh * 8;
  const ushort_t* xp = J.x + (n0 + r) * D128 + kh * 8;
  uint4 A4[4], X4[4];
#pragma unroll
  for (int kk = 0; kk < 4; kk++) {
    A4[kk] = *(const uint4*)(ap + kk * 32);
    X4[kk] = *(const uint4*)(xp + kk * 32);
  }

  f32x4 acc[8];
#pragma unroll
  for (int t = 0; t < 8; t++) acc[t] = (f32x4){0.f, 0.f, 0.f, 0.f};

#pragma unroll
  for (int kk = 0; kk < 4; kk++) {
    int so = (((kk << 2) + kh) ^ r) << 4;
    bf16x8 af = as_h(A4[kk]);
    bf16x8 xf = as_h(X4[kk]);
#pragma unroll
    for (int t = 0; t < 8; t++) {
      const char* p = smem + t * 4096 + r * 256 + so;
      bf16x8 bwl = *(const bf16x8*)(p);
      bf16x8 bwr = *(const bf16x8*)(p + 32768);
      acc[t] = __builtin_amdgcn_mfma_f32_16x16x32_bf16(af, bwl, acc[t], 0, 0, 0);
      acc[t] = __builtin_amdgcn_mfma_f32_16x16x32_bf16(xf, bwr, acc[t], 0, 0, 0);
    }
  }

  float s[4] = {0.f, 0.f, 0.f, 0.f};
#pragma unroll
  for (int t = 0; t < 8; t++) {
    float bv = J.bias[t * 16 + r];
#pragma unroll
    for (int q = 0; q < 4; q++) {
      float c = acc[t][q] + bv;
      acc[t][q] = c;
      s[q] += c * c;
    }
  }
#pragma unroll
  for (int off = 1; off < 16; off <<= 1) {
#pragma unroll
    for (int q = 0; q < 4; q++) s[q] += __shfl_xor(s[q], off);
  }
  float rn[4];
#pragma unroll
  for (int q = 0; q < 4; q++) rn[q] = 1.0f / fmaxf(sqrtf(s[q]), 1e-12f);

#pragma unroll
  for (int t = 0; t < 8; t++) {
#pragma unroll
    for (int q = 0; q < 4; q++) {
      float val = fmaxf(acc[t][q] * rn[q], 0.f);
      float pv = __shfl_xor(val, 1);
      if ((r & 1) == 0) {
        size_t node = n0 + kh * 4 + q;
        *(uint*)(J.out + node * D128 + t * 16 + r) = pack2(val, pv);
      }
    }
  }
}

extern "C" void kernel_launch(void* const* d_in, const int* in_sizes, int n_in,
                              void* d_out, int out_size, void* d_ws, size_t ws_size,
                              hipStream_t stream) {
  const float* emb_app = (const float*)d_in[0];
  const float* emb_mer = (const float*)d_in[1];
  const float* emb_dev = (const float*)d_in[2];
  const float* c1Wl = (const float*)d_in[3];
  const float* c1bl = (const float*)d_in[4];
  const float* c1Wr = (const float*)d_in[5];
  const float* c2Wl = (const float*)d_in[6];
  const float* c2bl = (const float*)d_in[7];
  const float* c2Wr = (const float*)d_in[8];
  const float* clfW = (const float*)d_in[9];
  const float* clfb = (const float*)d_in[10];
  const int* e0 = (const int*)d_in[11];
  const int* e1 = (const int*)d_in[12];
  const int* e2 = (const int*)d_in[13];
  const int* e3 = (const int*)d_in[14];

  const int NA = in_sizes[0] / D128;
  const int NM = in_sizes[1] / D128;
  const int ND = in_sizes[2] / D128;
  const int E = in_sizes[11] / 2;
  float* out = (float*)d_out;

  char* wsb = (char*)d_ws;
  size_t off = 0;
  auto alloc = [&](size_t bytes) -> char* {
    char* p = wsb + off;
    off += (bytes + 511) & ~(size_t)511;
    return p;
  };
  ushort_t* wl1 = (ushort_t*)alloc((size_t)4 * 16384 * 2);
  ushort_t* wr1 = (ushort_t*)alloc((size_t)4 * 16384 * 2);
  ushort_t* wl2 = (ushort_t*)alloc((size_t)4 * 16384 * 2);
  ushort_t* wr2 = (ushort_t*)alloc((size_t)4 * 16384 * 2);

  // overlay: L1 = [emer | edev | eapp] bf16, L2 = h2a f32 (proven R9)
  size_t embBytes = ((size_t)NM + ND + NA) * D128 * 2;
  size_t h2aBytes = (size_t)NA * D128 * 4;
  char* big = alloc(embBytes > h2aBytes ? embBytes : h2aBytes);
  ushort_t* emer = (ushort_t*)big;
  ushort_t* edev = emer + (size_t)NM * D128;
  ushort_t* eapp = edev + (size_t)ND * D128;
  float* h2a = (float*)big;

  ushort_t* h1m = (ushort_t*)alloc((size_t)NM * D128 * 2);
  ushort_t* h1d = (ushort_t*)alloc((size_t)ND * D128 * 2);
  float* h1a = (float*)alloc((size_t)NA * D128 * 4);
  ushort_t* aggA = (ushort_t*)alloc((size_t)NA * D128 * 2);
  ushort_t* aggB = (ushort_t*)alloc((size_t)NA * D128 * 2);
  int ncnt = NM + NA + ND + NA;
  int nb = (ncnt + 255) / 256;
  int* cnt = (int*)alloc((size_t)ncnt * 4);
  float* inv = (float*)alloc((size_t)ncnt * 4);
  int* ofs = (int*)alloc((size_t)ncnt * 4);
  int* bsum = (int*)alloc((size_t)nb * 4);
  int* pos = (int*)alloc((size_t)4 * E * 4);
  int* bucket = (int*)alloc((size_t)4 * E * 4);
  (void)ws_size;  // ~369 MB total (R9-proven)

  int b0 = 0, b1 = NM, b2 = NM + NA, b3 = NM + NA + ND;

  const int SMEM = 65536;
  hipFuncSetAttribute((const void*)sage5<1, 0, 0, 0, 0>,
                      hipFuncAttributeMaxDynamicSharedMemorySize, SMEM);
  hipFuncSetAttribute((const void*)sage5<1, 1, 0, 1, 0>,
                      hipFuncAttributeMaxDynamicSharedMemorySize, SMEM);
  hipFuncSetAttribute((const void*)sage5<0, 0, 0, 0, 0>,
                      hipFuncAttributeMaxDynamicSharedMemorySize, SMEM);
  hipFuncSetAttribute((const void*)sage5<0, 1, 0, 0, 1>,
                      hipFuncAttributeMaxDynamicSharedMemorySize, SMEM);
  hipFuncSetAttribute((const void*)sage_pair,
                      hipFuncAttributeMaxDynamicSharedMemorySize, SMEM);

  // ---- weights cvt + interleaved {embedding cvt ∥ poscount} ----
  dim3 wg(64, 4);
  cvtW_k<<<wg, 256, 0, stream>>>(c1Wl, c1Wr, c2Wl, c2Wr, wl1, wr1, wl2, wr2);
  hipMemsetAsync(cnt, 0, (size_t)ncnt * 4, stream);
  int na4 = NA * 32, nm4 = NM * 32, nd4 = ND * 32;
  int nbC = (na4 + nm4 + nd4 + 255) / 256;
  int nbE4 = (E + 1023) / 1024;
  int nbA = 4 * nbE4;
  pre2_k<<<nbC + nbA, 256, 0, stream>>>(
      emb_app, emb_mer, emb_dev, eapp, emer, edev, na4, nm4, nd4, nbC,
      e0 + E, e1 + E, e2 + E, e3 + E, cnt, pos, E, nbE4, nbA, b0, b1, b2, b3);
  scan1_k<<<nb, 256, 0, stream>>>(cnt, bsum, ncnt);
  scan2_k<<<nb, 256, 0, stream>>>(cnt, bsum, ofs, inv, ncnt);
  dim3 eg((E + 511) / 512, 4);
  reorder4_k<<<eg, 256, 0, stream>>>(e0, e1, e2, e3, ofs, pos, bucket,
                                     E, b0, b1, b2, b3);

  auto wgrid = [](int n) { return (n + 3) / 4; };
  auto g8 = [](int nt) { return (nt + 7) / 8; };
  int tA = NA / 16, tM = NM / 16, tD = ND / 16;

  auto J = [&](const ushort_t* x, int b, ushort_t* a, int n) {
    GJob j; j.x = x; j.ofs = ofs + b; j.cnt = cnt + b; j.inv = inv + b;
    j.agg = a; j.n = n; return j;
  };

  // ---- layer 1 ----
  // k0 (app->mer, deg~10) + k2 (app->dev, deg~5): group-parallel
  {
    dim3 gg(wgrid(NM > ND ? NM : ND), 2);
    agg2_k<0, 0><<<gg, 256, 0, stream>>>(J(eapp, b0, aggA, NM), J(eapp, b2, aggB, ND), bucket);
  }
  {
    SJob SA; SA.agg = aggA; SA.x = emer; SA.wl = wl1 + 0 * 16384;
    SA.wr = wr1 + 0 * 16384; SA.bias = c1bl + 0 * D128; SA.out = h1m; SA.ntiles = tM;
    SJob SB; SB.agg = aggB; SB.x = edev; SB.wl = wl1 + 2 * 16384;
    SB.wr = wr1 + 2 * 16384; SB.bias = c1bl + 2 * D128; SB.out = h1d; SB.ntiles = tD;
    dim3 sg(g8(tM > tD ? tM : tD), 2);
    sage_pair<<<sg, 512, SMEM, stream>>>(SA, SB);
  }
  // k1 (mer->app) + k3 (dev->app): degree ~2.5 -> serial full-row
  {
    dim3 gg(wgrid(NA), 2);
    agg2_k<0, 1><<<gg, 256, 0, stream>>>(J(emer, b1, aggA, NA), J(edev, b3, aggB, NA), bucket);
  }
  sage5<1, 0, 0, 0, 0><<<g8(tA), 512, SMEM, stream>>>(aggA, eapp,
      wl1 + 1 * 16384, wr1 + 1 * 16384, c1bl + 1 * D128, nullptr, nullptr, nullptr, h1a, tA);
  sage5<1, 1, 0, 1, 0><<<g8(tA), 512, SMEM, stream>>>(aggB, eapp,
      wl1 + 3 * 16384, wr1 + 3 * 16384, c1bl + 3 * D128, h1a, nullptr, nullptr, h1a, tA);

  // ---- layer 2 (dst=app only; `big` region reused as h2a) ----
  {
    dim3 gg(wgrid(NA), 2);
    agg2_k<1, 1><<<gg, 256, 0, stream>>>(J(h1m, b1, aggA, NA), J(h1d, b3, aggB, NA), bucket);
  }
  sage5<0, 0, 0, 0, 0><<<g8(tA), 512, SMEM, stream>>>(aggA, h1a,
      wl2 + 1 * 16384, wr2 + 1 * 16384, c2bl + 1 * D128, nullptr, nullptr, nullptr, h2a, tA);
  sage5<0, 1, 0, 0, 1><<<g8(tA), 512, SMEM, stream>>>(aggB, h1a,
      wl2 + 3 * 16384, wr2 + 3 * 16384, c2bl + 3 * D128, h2a, clfW, clfb, out, tA);
}

// Round 13
// 554.055 us; speedup vs baseline: 1.3178x; 1.2308x over previous
//
#include <hip/hip_runtime.h>
#include <hip/hip_bf16.h>

#define D128 128

typedef __attribute__((ext_vector_type(8))) short bf16x8;
typedef __attribute__((ext_vector_type(4))) float f32x4;
typedef __attribute__((ext_vector_type(2))) float f32x2;
typedef unsigned int uint;
typedef unsigned short ushort_t;

union U4 { uint4 u; bf16x8 h; };
__device__ __forceinline__ bf16x8 as_h(uint4 u) { U4 x; x.u = u; return x.h; }

__device__ __forceinline__ short f2bf(float f) {
  union { float f; unsigned u; } v; v.f = f;
  unsigned r = v.u + 0x7FFFu + ((v.u >> 16) & 1u);  // RNE
  return (short)(r >> 16);
}
__device__ __forceinline__ float bf_lo(uint v) {
  union { uint u; float f; } x; x.u = v << 16; return x.f;
}
__device__ __forceinline__ float bf_hi(uint v) {
  union { uint u; float f; } x; x.u = v & 0xFFFF0000u; return x.f;
}
__device__ __forceinline__ uint pack2(float a, float b) {
  return (uint)(unsigned short)f2bf(a) | ((uint)(unsigned short)f2bf(b) << 16);
}

// ---- 4 weight tensors in one launch (65536 f32 each = 16384 float4) ----
__global__ __launch_bounds__(256)
void cvtW_k(const float* __restrict__ w0, const float* __restrict__ w1,
            const float* __restrict__ w2, const float* __restrict__ w3,
            ushort_t* __restrict__ o0, ushort_t* __restrict__ o1,
            ushort_t* __restrict__ o2, ushort_t* __restrict__ o3) {
  int y = blockIdx.y;
  const float* in = y == 0 ? w0 : y == 1 ? w1 : y == 2 ? w2 : w3;
  ushort_t* out = y == 0 ? o0 : y == 1 ? o1 : y == 2 ? o2 : o3;
  int i = blockIdx.x * 256 + threadIdx.x;
  if (i >= 16384) return;
  float4 v = ((const float4*)in)[i];
  ushort4 o;
  o.x = (unsigned short)f2bf(v.x); o.y = (unsigned short)f2bf(v.y);
  o.z = (unsigned short)f2bf(v.z); o.w = (unsigned short)f2bf(v.w);
  ((ushort4*)out)[i] = o;
}

// ---- fused preprocessing, interleaved cvt ∥ poscount (R11-proven) ----
__global__ __launch_bounds__(256)
void pre2_k(const float* __restrict__ ia, const float* __restrict__ im,
            const float* __restrict__ id, ushort_t* __restrict__ oa,
            ushort_t* __restrict__ om, ushort_t* __restrict__ od,
            int na4, int nm4, int nd4, int nbC,
            const int* __restrict__ d0, const int* __restrict__ d1,
            const int* __restrict__ d2, const int* __restrict__ d3,
            int* __restrict__ cnt, int* __restrict__ pos,
            int nE, int nbE4, int nbA,
            int b0, int b1, int b2, int b3) {
  int bx = blockIdx.x, tid = threadIdx.x;
  int total = nbC + nbA;
  long long s = ((long long)bx * nbA) / total;
  long long t = ((long long)(bx + 1) * nbA) / total;
  if (t > s) {
    int ab = (int)s;
    int y = ab / nbE4;
    int blk = ab - y * nbE4;
    const int* d = y == 0 ? d0 : y == 1 ? d1 : y == 2 ? d2 : d3;
    int base = y == 0 ? b0 : y == 1 ? b1 : y == 2 ? b2 : b3;
#pragma unroll
    for (int u = 0; u < 4; u++) {
      int i = blk * 1024 + u * 256 + tid;
      if (i < nE) {
        int p = atomicAdd(&cnt[base + d[i]], 1);
        pos[(size_t)y * nE + i] = p;
      }
    }
  } else {
    int i = (int)(bx - s) * 256 + tid;
    const float* in; ushort_t* out; int k;
    if (i < na4) { in = ia; out = oa; k = i; }
    else if (i < na4 + nm4) { in = im; out = om; k = i - na4; }
    else if (i < na4 + nm4 + nd4) { in = id; out = od; k = i - na4 - nm4; }
    else return;
    float4 v = ((const float4*)in)[k];
    ushort4 o;
    o.x = (unsigned short)f2bf(v.x); o.y = (unsigned short)f2bf(v.y);
    o.z = (unsigned short)f2bf(v.z); o.w = (unsigned short)f2bf(v.w);
    ((ushort4*)out)[k] = o;
  }
}

// ---- scan stage 1 ----
__device__ __forceinline__ int wave_incl_scan(int v, int lane) {
#pragma unroll
  for (int off = 1; off < 64; off <<= 1) {
    int y = __shfl_up(v, off);
    if (lane >= off) v += y;
  }
  return v;
}

__global__ __launch_bounds__(256) void scan1_k(const int* __restrict__ cnt,
                                               int* __restrict__ bsum, int n) {
  int b = blockIdx.x, tid = threadIdx.x;
  int i = b * 256 + tid;
  int v = (i < n) ? cnt[i] : 0;
  int lane = tid & 63, wid = tid >> 6;
  __shared__ int ws[4];
  int s = wave_incl_scan(v, lane);
  if (lane == 63) ws[wid] = s;
  __syncthreads();
  if (tid == 0) bsum[b] = ws[0] + ws[1] + ws[2] + ws[3];
}

// ---- scan stage 2 (+ inv fold) ----
__global__ __launch_bounds__(256) void scan2_k(const int* __restrict__ cnt,
                                               const int* __restrict__ bsum,
                                               int* __restrict__ ofs,
                                               float* __restrict__ inv, int n) {
  int b = blockIdx.x, tid = threadIdx.x;
  int lane = tid & 63, wid = tid >> 6;
  __shared__ int wsA[4], wsB[4];
  int p = 0;
  for (int j = tid; j < b; j += 256) p += bsum[j];
#pragma unroll
  for (int off = 32; off; off >>= 1) p += __shfl_xor(p, off);
  if (lane == 0) wsA[wid] = p;
  __syncthreads();
  int base = wsA[0] + wsA[1] + wsA[2] + wsA[3];
  int i = b * 256 + tid;
  int v = (i < n) ? cnt[i] : 0;
  int s = wave_incl_scan(v, lane);
  if (lane == 63) wsB[wid] = s;
  __syncthreads();
  int woff = 0;
  for (int w = 0; w < wid; w++) woff += wsB[w];
  int excl = base + woff + s - v;
  if (i < n) {
    ofs[i] = excl;
    inv[i] = 1.0f / (float)(v > 1 ? v : 1);
  }
}

// ---- reorder: bucket fill with NO atomics, 2 edges/thread ----
__global__ __launch_bounds__(256)
void reorder4_k(const int* __restrict__ e0, const int* __restrict__ e1,
                const int* __restrict__ e2, const int* __restrict__ e3,
                const int* __restrict__ ofs, const int* __restrict__ pos,
                int* __restrict__ bucket,
                int nE, int b0, int b1, int b2, int b3) {
  int y = blockIdx.y;
  const int* e = y == 0 ? e0 : y == 1 ? e1 : y == 2 ? e2 : e3;
  int base = y == 0 ? b0 : y == 1 ? b1 : y == 2 ? b2 : b3;
#pragma unroll
  for (int u = 0; u < 2; u++) {
    int i = blockIdx.x * 512 + u * 256 + threadIdx.x;
    if (i < nE) {
      int s = e[i];
      int d = e[nE + i];
      int p = pos[(size_t)y * nE + i];
      bucket[ofs[base + d] + p] = s;
    }
  }
}

// ---- dual CSR gather-mean, GROUP-PER-NODE:
//  each wave's four 16-lane groups each own one node (16B/lane = 256B row).
//  4 independent serial edge chains per wave x unroll-2 = 8 row loads in
//  flight, NO cross-lane reduction. Store = 256B coalesced per group. ----
struct GJob {
  const ushort_t* x;
  const int* ofs;
  const int* cnt;
  const float* inv;
  ushort_t* agg;
  int n;
};

template <int RELU>
__global__ __launch_bounds__(256)
void agg2_k(GJob A, GJob B, const int* __restrict__ bucket) {
  const GJob& J = blockIdx.y ? B : A;
  int gwave = (int)(((size_t)blockIdx.x * 256 + threadIdx.x) >> 6);
  int lane = threadIdx.x & 63;
  int g = lane >> 4, sl = lane & 15;
  int node = gwave * 4 + g;
  if (node >= J.n) return;
  int beg = J.ofs[node], c = J.cnt[node];
  float iv = J.inv[node];
  const ushort_t* xsrc = J.x;

  f32x2 a0 = {0.f, 0.f}, a1 = {0.f, 0.f}, a2 = {0.f, 0.f}, a3 = {0.f, 0.f};
  auto accum = [&](uint4 v) {
    f32x2 p0 = {bf_lo(v.x), bf_hi(v.x)};
    f32x2 p1 = {bf_lo(v.y), bf_hi(v.y)};
    f32x2 p2 = {bf_lo(v.z), bf_hi(v.z)};
    f32x2 p3 = {bf_lo(v.w), bf_hi(v.w)};
    if (RELU) {
      p0[0] = fmaxf(p0[0], 0.f); p0[1] = fmaxf(p0[1], 0.f);
      p1[0] = fmaxf(p1[0], 0.f); p1[1] = fmaxf(p1[1], 0.f);
      p2[0] = fmaxf(p2[0], 0.f); p2[1] = fmaxf(p2[1], 0.f);
      p3[0] = fmaxf(p3[0], 0.f); p3[1] = fmaxf(p3[1], 0.f);
    }
    a0 += p0; a1 += p1; a2 += p2; a3 += p3;
  };

  int j = 0;
  for (; j + 2 <= c; j += 2) {
    int s0 = bucket[beg + j], s1 = bucket[beg + j + 1];
    uint4 v0 = *(const uint4*)(xsrc + (size_t)s0 * D128 + sl * 8);
    uint4 v1 = *(const uint4*)(xsrc + (size_t)s1 * D128 + sl * 8);
    accum(v0); accum(v1);
  }
  if (j < c) {
    uint4 v0 = *(const uint4*)(xsrc + (size_t)bucket[beg + j] * D128 + sl * 8);
    accum(v0);
  }

  uint4 o;
  o.x = pack2(a0[0] * iv, a0[1] * iv);
  o.y = pack2(a1[0] * iv, a1[1] * iv);
  o.z = pack2(a2[0] * iv, a2[1] * iv);
  o.w = pack2(a3[0] * iv, a3[1] * iv);
  *(uint4*)(J.agg + (size_t)node * D128 + sl * 8) = o;
}

// ---- fused SAGE transform (single edge type), LDS-staged weights ----
//  (unchanged -- proven since R5)
template <int XBF, int ACC, int BFOUT, int OUTRELU, int CLF>
__global__ __launch_bounds__(512)
void sage5(const ushort_t* __restrict__ agg, const void* __restrict__ xv,
           const ushort_t* __restrict__ wl, const ushort_t* __restrict__ wr,
           const float* __restrict__ bias, const float* __restrict__ prevf,
           const float* __restrict__ clfW, const float* __restrict__ clfb,
           void* __restrict__ outv, int ntiles) {
  extern __shared__ char smem[];
  const int tid = threadIdx.x;

  for (int c = tid; c < 4096; c += 512) {
    int m = c >> 11, cc = c & 2047;
    int row = cc >> 4, slot = cc & 15;
    const ushort_t* W = m ? wr : wl;
    uint4 v = *((const uint4*)W + cc);
    *(uint4*)(smem + m * 32768 + row * 256 + ((slot ^ (row & 15)) << 4)) = v;
  }
  __syncthreads();

  int wid = tid >> 6, lane = tid & 63;
  int r = lane & 15, kh = lane >> 4;
  int tile = blockIdx.x * 8 + wid;
  if (tile >= ntiles) return;
  size_t n0 = (size_t)tile * 16;

  const ushort_t* ap = agg + (n0 + r) * D128 + kh * 8;
  uint4 A[4];
  bf16x8 XF[4];
#pragma unroll
  for (int kk = 0; kk < 4; kk++) A[kk] = *(const uint4*)(ap + kk * 32);
  if (XBF) {
    const ushort_t* xp = (const ushort_t*)xv + (n0 + r) * D128 + kh * 8;
#pragma unroll
    for (int kk = 0; kk < 4; kk++) XF[kk] = as_h(*(const uint4*)(xp + kk * 32));
  } else {
    const float* xp = (const float*)xv + (n0 + r) * D128 + kh * 8;
#pragma unroll
    for (int kk = 0; kk < 4; kk++) {
      f32x4 x0 = *(const f32x4*)(xp + kk * 32);
      f32x4 x1 = *(const f32x4*)(xp + kk * 32 + 4);
#pragma unroll
      for (int j = 0; j < 4; j++) {
        XF[kk][j] = f2bf(x0[j]);
        XF[kk][j + 4] = f2bf(x1[j]);
      }
    }
  }

  f32x4 acc[8];
#pragma unroll
  for (int t = 0; t < 8; t++) acc[t] = (f32x4){0.f, 0.f, 0.f, 0.f};

#pragma unroll
  for (int kk = 0; kk < 4; kk++) {
    int so = (((kk << 2) + kh) ^ r) << 4;
    bf16x8 af = as_h(A[kk]);
    bf16x8 xf = XF[kk];
#pragma unroll
    for (int t = 0; t < 8; t++) {
      const char* p = smem + t * 4096 + r * 256 + so;
      bf16x8 bwl = *(const bf16x8*)(p);
      bf16x8 bwr = *(const bf16x8*)(p + 32768);
      acc[t] = __builtin_amdgcn_mfma_f32_16x16x32_bf16(af, bwl, acc[t], 0, 0, 0);
      acc[t] = __builtin_amdgcn_mfma_f32_16x16x32_bf16(xf, bwr, acc[t], 0, 0, 0);
    }
  }

  float s[4] = {0.f, 0.f, 0.f, 0.f};
#pragma unroll
  for (int t = 0; t < 8; t++) {
    float bv = bias[t * 16 + r];
#pragma unroll
    for (int q = 0; q < 4; q++) {
      float c = acc[t][q] + bv;
      acc[t][q] = c;
      s[q] += c * c;
    }
  }
#pragma unroll
  for (int off = 1; off < 16; off <<= 1) {
#pragma unroll
    for (int q = 0; q < 4; q++) s[q] += __shfl_xor(s[q], off);
  }
  float rn[4];
#pragma unroll
  for (int q = 0; q < 4; q++) rn[q] = 1.0f / fmaxf(sqrtf(s[q]), 1e-12f);

  if (CLF) {
    float w0[8], w1[8];
#pragma unroll
    for (int t = 0; t < 8; t++) {
      w0[t] = clfW[t * 16 + r];
      w1[t] = clfW[D128 + t * 16 + r];
    }
    float p0[4] = {0.f, 0.f, 0.f, 0.f}, p1[4] = {0.f, 0.f, 0.f, 0.f};
#pragma unroll
    for (int t = 0; t < 8; t++) {
#pragma unroll
      for (int q = 0; q < 4; q++) {
        float val = acc[t][q] * rn[q];
        if (ACC) {
          size_t node = n0 + kh * 4 + q;
          val += prevf[node * D128 + t * 16 + r];
        }
        p0[q] += val * w0[t];
        p1[q] += val * w1[t];
      }
    }
#pragma unroll
    for (int off = 1; off < 16; off <<= 1) {
#pragma unroll
      for (int q = 0; q < 4; q++) {
        p0[q] += __shfl_xor(p0[q], off);
        p1[q] += __shfl_xor(p1[q], off);
      }
    }
    if (r == 0) {
      float cb0 = clfb[0], cb1 = clfb[1];
#pragma unroll
      for (int q = 0; q < 4; q++) {
        size_t node = n0 + kh * 4 + q;
        float2 o; o.x = p0[q] + cb0; o.y = p1[q] + cb1;
        *(float2*)((float*)outv + node * 2) = o;
      }
    }
  } else {
#pragma unroll
    for (int t = 0; t < 8; t++) {
#pragma unroll
      for (int q = 0; q < 4; q++) {
        float val = acc[t][q] * rn[q];
        size_t node = n0 + kh * 4 + q;
        if (ACC) val += prevf[node * D128 + t * 16 + r];
        if (OUTRELU) val = fmaxf(val, 0.f);
        if (BFOUT) {
          float pv = __shfl_xor(val, 1);
          if ((r & 1) == 0)
            *(uint*)((ushort_t*)outv + node * D128 + t * 16 + r) = pack2(val, pv);
        } else {
          ((float*)outv)[node * D128 + t * 16 + r] = val;
        }
      }
    }
  }
}

// ---- dual SAGE: two independent (XBF=1, BFOUT=1, OUTRELU=1) jobs ----
struct SJob {
  const ushort_t* agg;
  const ushort_t* x;
  const ushort_t* wl;
  const ushort_t* wr;
  const float* bias;
  ushort_t* out;
  int ntiles;
};

__global__ __launch_bounds__(512)
void sage_pair(SJob A, SJob B) {
  extern __shared__ char smem[];
  const SJob& J = blockIdx.y ? B : A;
  const int tid = threadIdx.x;

  for (int c = tid; c < 4096; c += 512) {
    int m = c >> 11, cc = c & 2047;
    int row = cc >> 4, slot = cc & 15;
    const ushort_t* W = m ? J.wr : J.wl;
    uint4 v = *((const uint4*)W + cc);
    *(uint4*)(smem + m * 32768 + row * 256 + ((slot ^ (row & 15)) << 4)) = v;
  }
  __syncthreads();

  int wid = tid >> 6, lane = tid & 63;
  int r = lane & 15, kh = lane >> 4;
  int tile = blockIdx.x * 8 + wid;
  if (tile >= J.ntiles) return;
  size_t n0 = (size_t)tile * 16;

  const ushort_t* ap = J.agg + (n0 + r) * D128 + kh * 8;
  const ushort_t* xp = J.x + (n0 + r) * D128 + kh * 8;
  uint4 A4[4], X4[4];
#pragma unroll
  for (int kk = 0; kk < 4; kk++) {
    A4[kk] = *(const uint4*)(ap + kk * 32);
    X4[kk] = *(const uint4*)(xp + kk * 32);
  }

  f32x4 acc[8];
#pragma unroll
  for (int t = 0; t < 8; t++) acc[t] = (f32x4){0.f, 0.f, 0.f, 0.f};

#pragma unroll
  for (int kk = 0; kk < 4; kk++) {
    int so = (((kk << 2) + kh) ^ r) << 4;
    bf16x8 af = as_h(A4[kk]);
    bf16x8 xf = as_h(X4[kk]);
#pragma unroll
    for (int t = 0; t < 8; t++) {
      const char* p = smem + t * 4096 + r * 256 + so;
      bf16x8 bwl = *(const bf16x8*)(p);
      bf16x8 bwr = *(const bf16x8*)(p + 32768);
      acc[t] = __builtin_amdgcn_mfma_f32_16x16x32_bf16(af, bwl, acc[t], 0, 0, 0);
      acc[t] = __builtin_amdgcn_mfma_f32_16x16x32_bf16(xf, bwr, acc[t], 0, 0, 0);
    }
  }

  float s[4] = {0.f, 0.f, 0.f, 0.f};
#pragma unroll
  for (int t = 0; t < 8; t++) {
    float bv = J.bias[t * 16 + r];
#pragma unroll
    for (int q = 0; q < 4; q++) {
      float c = acc[t][q] + bv;
      acc[t][q] = c;
      s[q] += c * c;
    }
  }
#pragma unroll
  for (int off = 1; off < 16; off <<= 1) {
#pragma unroll
    for (int q = 0; q < 4; q++) s[q] += __shfl_xor(s[q], off);
  }
  float rn[4];
#pragma unroll
  for (int q = 0; q < 4; q++) rn[q] = 1.0f / fmaxf(sqrtf(s[q]), 1e-12f);

#pragma unroll
  for (int t = 0; t < 8; t++) {
#pragma unroll
    for (int q = 0; q < 4; q++) {
      float val = fmaxf(acc[t][q] * rn[q], 0.f);
      float pv = __shfl_xor(val, 1);
      if ((r & 1) == 0) {
        size_t node = n0 + kh * 4 + q;
        *(uint*)(J.out + node * D128 + t * 16 + r) = pack2(val, pv);
      }
    }
  }
}

extern "C" void kernel_launch(void* const* d_in, const int* in_sizes, int n_in,
                              void* d_out, int out_size, void* d_ws, size_t ws_size,
                              hipStream_t stream) {
  const float* emb_app = (const float*)d_in[0];
  const float* emb_mer = (const float*)d_in[1];
  const float* emb_dev = (const float*)d_in[2];
  const float* c1Wl = (const float*)d_in[3];
  const float* c1bl = (const float*)d_in[4];
  const float* c1Wr = (const float*)d_in[5];
  const float* c2Wl = (const float*)d_in[6];
  const float* c2bl = (const float*)d_in[7];
  const float* c2Wr = (const float*)d_in[8];
  const float* clfW = (const float*)d_in[9];
  const float* clfb = (const float*)d_in[10];
  const int* e0 = (const int*)d_in[11];
  const int* e1 = (const int*)d_in[12];
  const int* e2 = (const int*)d_in[13];
  const int* e3 = (const int*)d_in[14];

  const int NA = in_sizes[0] / D128;
  const int NM = in_sizes[1] / D128;
  const int ND = in_sizes[2] / D128;
  const int E = in_sizes[11] / 2;
  float* out = (float*)d_out;

  char* wsb = (char*)d_ws;
  size_t off = 0;
  auto alloc = [&](size_t bytes) -> char* {
    char* p = wsb + off;
    off += (bytes + 511) & ~(size_t)511;
    return p;
  };
  ushort_t* wl1 = (ushort_t*)alloc((size_t)4 * 16384 * 2);
  ushort_t* wr1 = (ushort_t*)alloc((size_t)4 * 16384 * 2);
  ushort_t* wl2 = (ushort_t*)alloc((size_t)4 * 16384 * 2);
  ushort_t* wr2 = (ushort_t*)alloc((size_t)4 * 16384 * 2);

  // overlay: L1 = [emer | edev | eapp] bf16, L2 = h2a f32 (proven R9)
  size_t embBytes = ((size_t)NM + ND + NA) * D128 * 2;
  size_t h2aBytes = (size_t)NA * D128 * 4;
  char* big = alloc(embBytes > h2aBytes ? embBytes : h2aBytes);
  ushort_t* emer = (ushort_t*)big;
  ushort_t* edev = emer + (size_t)NM * D128;
  ushort_t* eapp = edev + (size_t)ND * D128;
  float* h2a = (float*)big;

  ushort_t* h1m = (ushort_t*)alloc((size_t)NM * D128 * 2);
  ushort_t* h1d = (ushort_t*)alloc((size_t)ND * D128 * 2);
  float* h1a = (float*)alloc((size_t)NA * D128 * 4);
  ushort_t* aggA = (ushort_t*)alloc((size_t)NA * D128 * 2);
  ushort_t* aggB = (ushort_t*)alloc((size_t)NA * D128 * 2);
  int ncnt = NM + NA + ND + NA;
  int nb = (ncnt + 255) / 256;
  int* cnt = (int*)alloc((size_t)ncnt * 4);
  float* inv = (float*)alloc((size_t)ncnt * 4);
  int* ofs = (int*)alloc((size_t)ncnt * 4);
  int* bsum = (int*)alloc((size_t)nb * 4);
  int* pos = (int*)alloc((size_t)4 * E * 4);
  int* bucket = (int*)alloc((size_t)4 * E * 4);
  (void)ws_size;  // ~369 MB total (R9-proven)

  int b0 = 0, b1 = NM, b2 = NM + NA, b3 = NM + NA + ND;

  const int SMEM = 65536;
  hipFuncSetAttribute((const void*)sage5<1, 0, 0, 0, 0>,
                      hipFuncAttributeMaxDynamicSharedMemorySize, SMEM);
  hipFuncSetAttribute((const void*)sage5<1, 1, 0, 1, 0>,
                      hipFuncAttributeMaxDynamicSharedMemorySize, SMEM);
  hipFuncSetAttribute((const void*)sage5<0, 0, 0, 0, 0>,
                      hipFuncAttributeMaxDynamicSharedMemorySize, SMEM);
  hipFuncSetAttribute((const void*)sage5<0, 1, 0, 0, 1>,
                      hipFuncAttributeMaxDynamicSharedMemorySize, SMEM);
  hipFuncSetAttribute((const void*)sage_pair,
                      hipFuncAttributeMaxDynamicSharedMemorySize, SMEM);

  // ---- weights cvt + interleaved {embedding cvt ∥ poscount} ----
  dim3 wg(64, 4);
  cvtW_k<<<wg, 256, 0, stream>>>(c1Wl, c1Wr, c2Wl, c2Wr, wl1, wr1, wl2, wr2);
  hipMemsetAsync(cnt, 0, (size_t)ncnt * 4, stream);
  int na4 = NA * 32, nm4 = NM * 32, nd4 = ND * 32;
  int nbC = (na4 + nm4 + nd4 + 255) / 256;
  int nbE4 = (E + 1023) / 1024;
  int nbA = 4 * nbE4;
  pre2_k<<<nbC + nbA, 256, 0, stream>>>(
      emb_app, emb_mer, emb_dev, eapp, emer, edev, na4, nm4, nd4, nbC,
      e0 + E, e1 + E, e2 + E, e3 + E, cnt, pos, E, nbE4, nbA, b0, b1, b2, b3);
  scan1_k<<<nb, 256, 0, stream>>>(cnt, bsum, ncnt);
  scan2_k<<<nb, 256, 0, stream>>>(cnt, bsum, ofs, inv, ncnt);
  dim3 eg((E + 511) / 512, 4);
  reorder4_k<<<eg, 256, 0, stream>>>(e0, e1, e2, e3, ofs, pos, bucket,
                                     E, b0, b1, b2, b3);

  auto ngrid = [](int n) { return (n + 15) / 16; };  // 16 nodes per block
  auto g8 = [](int nt) { return (nt + 7) / 8; };
  int tA = NA / 16, tM = NM / 16, tD = ND / 16;

  auto J = [&](const ushort_t* x, int b, ushort_t* a, int n) {
    GJob j; j.x = x; j.ofs = ofs + b; j.cnt = cnt + b; j.inv = inv + b;
    j.agg = a; j.n = n; return j;
  };

  // ---- layer 1 ----
  // k0 (app->mer) + k2 (app->dev)
  {
    dim3 gg(ngrid(NM > ND ? NM : ND), 2);
    agg2_k<0><<<gg, 256, 0, stream>>>(J(eapp, b0, aggA, NM), J(eapp, b2, aggB, ND), bucket);
  }
  {
    SJob SA; SA.agg = aggA; SA.x = emer; SA.wl = wl1 + 0 * 16384;
    SA.wr = wr1 + 0 * 16384; SA.bias = c1bl + 0 * D128; SA.out = h1m; SA.ntiles = tM;
    SJob SB; SB.agg = aggB; SB.x = edev; SB.wl = wl1 + 2 * 16384;
    SB.wr = wr1 + 2 * 16384; SB.bias = c1bl + 2 * D128; SB.out = h1d; SB.ntiles = tD;
    dim3 sg(g8(tM > tD ? tM : tD), 2);
    sage_pair<<<sg, 512, SMEM, stream>>>(SA, SB);
  }
  // k1 (mer->app) + k3 (dev->app)
  {
    dim3 gg(ngrid(NA), 2);
    agg2_k<0><<<gg, 256, 0, stream>>>(J(emer, b1, aggA, NA), J(edev, b3, aggB, NA), bucket);
  }
  sage5<1, 0, 0, 0, 0><<<g8(tA), 512, SMEM, stream>>>(aggA, eapp,
      wl1 + 1 * 16384, wr1 + 1 * 16384, c1bl + 1 * D128, nullptr, nullptr, nullptr, h1a, tA);
  sage5<1, 1, 0, 1, 0><<<g8(tA), 512, SMEM, stream>>>(aggB, eapp,
      wl1 + 3 * 16384, wr1 + 3 * 16384, c1bl + 3 * D128, h1a, nullptr, nullptr, h1a, tA);

  // ---- layer 2 (dst=app only; `big` region reused as h2a) ----
  {
    dim3 gg(ngrid(NA), 2);
    agg2_k<1><<<gg, 256, 0, stream>>>(J(h1m, b1, aggA, NA), J(h1d, b3, aggB, NA), bucket);
  }
  sage5<0, 0, 0, 0, 0><<<g8(tA), 512, SMEM, stream>>>(aggA, h1a,
      wl2 + 1 * 16384, wr2 + 1 * 16384, c2bl + 1 * D128, nullptr, nullptr, nullptr, h2a, tA);
  sage5<0, 1, 0, 0, 1><<<g8(tA), 512, SMEM, stream>>>(aggB, h1a,
      wl2 + 3 * 16384, wr2 + 3 * 16384, c2bl + 3 * D128, h2a, clfW, clfb, out, tA);
}

// Round 14
// 536.566 us; speedup vs baseline: 1.3607x; 1.0326x over previous
//
#include <hip/hip_runtime.h>
#include <hip/hip_bf16.h>

#define D128 128

typedef __attribute__((ext_vector_type(8))) short bf16x8;
typedef __attribute__((ext_vector_type(4))) float f32x4;
typedef __attribute__((ext_vector_type(2))) float f32x2;
typedef unsigned int uint;
typedef unsigned short ushort_t;

union U4 { uint4 u; bf16x8 h; };
__device__ __forceinline__ bf16x8 as_h(uint4 u) { U4 x; x.u = u; return x.h; }

__device__ __forceinline__ short f2bf(float f) {
  union { float f; unsigned u; } v; v.f = f;
  unsigned r = v.u + 0x7FFFu + ((v.u >> 16) & 1u);  // RNE
  return (short)(r >> 16);
}
__device__ __forceinline__ float bf_lo(uint v) {
  union { uint u; float f; } x; x.u = v << 16; return x.f;
}
__device__ __forceinline__ float bf_hi(uint v) {
  union { uint u; float f; } x; x.u = v & 0xFFFF0000u; return x.f;
}
__device__ __forceinline__ uint pack2(float a, float b) {
  return (uint)(unsigned short)f2bf(a) | ((uint)(unsigned short)f2bf(b) << 16);
}

// ---- 4 weight tensors in one launch (65536 f32 each = 16384 float4) ----
__global__ __launch_bounds__(256)
void cvtW_k(const float* __restrict__ w0, const float* __restrict__ w1,
            const float* __restrict__ w2, const float* __restrict__ w3,
            ushort_t* __restrict__ o0, ushort_t* __restrict__ o1,
            ushort_t* __restrict__ o2, ushort_t* __restrict__ o3) {
  int y = blockIdx.y;
  const float* in = y == 0 ? w0 : y == 1 ? w1 : y == 2 ? w2 : w3;
  ushort_t* out = y == 0 ? o0 : y == 1 ? o1 : y == 2 ? o2 : o3;
  int i = blockIdx.x * 256 + threadIdx.x;
  if (i >= 16384) return;
  float4 v = ((const float4*)in)[i];
  ushort4 o;
  o.x = (unsigned short)f2bf(v.x); o.y = (unsigned short)f2bf(v.y);
  o.z = (unsigned short)f2bf(v.z); o.w = (unsigned short)f2bf(v.w);
  ((ushort4*)out)[i] = o;
}

// ---- fused preprocessing, interleaved cvt ∥ poscount (R11-proven) ----
__global__ __launch_bounds__(256)
void pre2_k(const float* __restrict__ ia, const float* __restrict__ im,
            const float* __restrict__ id, ushort_t* __restrict__ oa,
            ushort_t* __restrict__ om, ushort_t* __restrict__ od,
            int na4, int nm4, int nd4, int nbC,
            const int* __restrict__ d0, const int* __restrict__ d1,
            const int* __restrict__ d2, const int* __restrict__ d3,
            int* __restrict__ cnt, int* __restrict__ pos,
            int nE, int nbE4, int nbA,
            int b0, int b1, int b2, int b3) {
  int bx = blockIdx.x, tid = threadIdx.x;
  int total = nbC + nbA;
  long long s = ((long long)bx * nbA) / total;
  long long t = ((long long)(bx + 1) * nbA) / total;
  if (t > s) {
    int ab = (int)s;
    int y = ab / nbE4;
    int blk = ab - y * nbE4;
    const int* d = y == 0 ? d0 : y == 1 ? d1 : y == 2 ? d2 : d3;
    int base = y == 0 ? b0 : y == 1 ? b1 : y == 2 ? b2 : b3;
#pragma unroll
    for (int u = 0; u < 4; u++) {
      int i = blk * 1024 + u * 256 + tid;
      if (i < nE) {
        int p = atomicAdd(&cnt[base + d[i]], 1);
        pos[(size_t)y * nE + i] = p;
      }
    }
  } else {
    int i = (int)(bx - s) * 256 + tid;
    const float* in; ushort_t* out; int k;
    if (i < na4) { in = ia; out = oa; k = i; }
    else if (i < na4 + nm4) { in = im; out = om; k = i - na4; }
    else if (i < na4 + nm4 + nd4) { in = id; out = od; k = i - na4 - nm4; }
    else return;
    float4 v = ((const float4*)in)[k];
    ushort4 o;
    o.x = (unsigned short)f2bf(v.x); o.y = (unsigned short)f2bf(v.y);
    o.z = (unsigned short)f2bf(v.z); o.w = (unsigned short)f2bf(v.w);
    ((ushort4*)out)[k] = o;
  }
}

// ---- scan stage 1 ----
__device__ __forceinline__ int wave_incl_scan(int v, int lane) {
#pragma unroll
  for (int off = 1; off < 64; off <<= 1) {
    int y = __shfl_up(v, off);
    if (lane >= off) v += y;
  }
  return v;
}

__global__ __launch_bounds__(256) void scan1_k(const int* __restrict__ cnt,
                                               int* __restrict__ bsum, int n) {
  int b = blockIdx.x, tid = threadIdx.x;
  int i = b * 256 + tid;
  int v = (i < n) ? cnt[i] : 0;
  int lane = tid & 63, wid = tid >> 6;
  __shared__ int ws[4];
  int s = wave_incl_scan(v, lane);
  if (lane == 63) ws[wid] = s;
  __syncthreads();
  if (tid == 0) bsum[b] = ws[0] + ws[1] + ws[2] + ws[3];
}

// ---- scan stage 2 (+ inv fold) ----
__global__ __launch_bounds__(256) void scan2_k(const int* __restrict__ cnt,
                                               const int* __restrict__ bsum,
                                               int* __restrict__ ofs,
                                               float* __restrict__ inv, int n) {
  int b = blockIdx.x, tid = threadIdx.x;
  int lane = tid & 63, wid = tid >> 6;
  __shared__ int wsA[4], wsB[4];
  int p = 0;
  for (int j = tid; j < b; j += 256) p += bsum[j];
#pragma unroll
  for (int off = 32; off; off >>= 1) p += __shfl_xor(p, off);
  if (lane == 0) wsA[wid] = p;
  __syncthreads();
  int base = wsA[0] + wsA[1] + wsA[2] + wsA[3];
  int i = b * 256 + tid;
  int v = (i < n) ? cnt[i] : 0;
  int s = wave_incl_scan(v, lane);
  if (lane == 63) wsB[wid] = s;
  __syncthreads();
  int woff = 0;
  for (int w = 0; w < wid; w++) woff += wsB[w];
  int excl = base + woff + s - v;
  if (i < n) {
    ofs[i] = excl;
    inv[i] = 1.0f / (float)(v > 1 ? v : 1);
  }
}

// ---- reorder: bucket fill with NO atomics, 2 edges/thread ----
__global__ __launch_bounds__(256)
void reorder4_k(const int* __restrict__ e0, const int* __restrict__ e1,
                const int* __restrict__ e2, const int* __restrict__ e3,
                const int* __restrict__ ofs, const int* __restrict__ pos,
                int* __restrict__ bucket,
                int nE, int b0, int b1, int b2, int b3) {
  int y = blockIdx.y;
  const int* e = y == 0 ? e0 : y == 1 ? e1 : y == 2 ? e2 : e3;
  int base = y == 0 ? b0 : y == 1 ? b1 : y == 2 ? b2 : b3;
#pragma unroll
  for (int u = 0; u < 2; u++) {
    int i = blockIdx.x * 512 + u * 256 + threadIdx.x;
    if (i < nE) {
      int s = e[i];
      int d = e[nE + i];
      int p = pos[(size_t)y * nE + i];
      bucket[ofs[base + d] + p] = s;
    }
  }
}

// ---- dual CSR gather-mean, GROUP-PER-NODE (R13-proven) ----
struct GJob {
  const ushort_t* x;
  const int* ofs;
  const int* cnt;
  const float* inv;
  ushort_t* agg;
  int n;
};

template <int RELU>
__global__ __launch_bounds__(256)
void agg2_k(GJob A, GJob B, const int* __restrict__ bucket) {
  const GJob& J = blockIdx.y ? B : A;
  int gwave = (int)(((size_t)blockIdx.x * 256 + threadIdx.x) >> 6);
  int lane = threadIdx.x & 63;
  int g = lane >> 4, sl = lane & 15;
  int node = gwave * 4 + g;
  if (node >= J.n) return;
  int beg = J.ofs[node], c = J.cnt[node];
  float iv = J.inv[node];
  const ushort_t* xsrc = J.x;

  f32x2 a0 = {0.f, 0.f}, a1 = {0.f, 0.f}, a2 = {0.f, 0.f}, a3 = {0.f, 0.f};
  auto accum = [&](uint4 v) {
    f32x2 p0 = {bf_lo(v.x), bf_hi(v.x)};
    f32x2 p1 = {bf_lo(v.y), bf_hi(v.y)};
    f32x2 p2 = {bf_lo(v.z), bf_hi(v.z)};
    f32x2 p3 = {bf_lo(v.w), bf_hi(v.w)};
    if (RELU) {
      p0[0] = fmaxf(p0[0], 0.f); p0[1] = fmaxf(p0[1], 0.f);
      p1[0] = fmaxf(p1[0], 0.f); p1[1] = fmaxf(p1[1], 0.f);
      p2[0] = fmaxf(p2[0], 0.f); p2[1] = fmaxf(p2[1], 0.f);
      p3[0] = fmaxf(p3[0], 0.f); p3[1] = fmaxf(p3[1], 0.f);
    }
    a0 += p0; a1 += p1; a2 += p2; a3 += p3;
  };

  int j = 0;
  for (; j + 2 <= c; j += 2) {
    int s0 = bucket[beg + j], s1 = bucket[beg + j + 1];
    uint4 v0 = *(const uint4*)(xsrc + (size_t)s0 * D128 + sl * 8);
    uint4 v1 = *(const uint4*)(xsrc + (size_t)s1 * D128 + sl * 8);
    accum(v0); accum(v1);
  }
  if (j < c) {
    uint4 v0 = *(const uint4*)(xsrc + (size_t)bucket[beg + j] * D128 + sl * 8);
    accum(v0);
  }

  uint4 o;
  o.x = pack2(a0[0] * iv, a0[1] * iv);
  o.y = pack2(a1[0] * iv, a1[1] * iv);
  o.z = pack2(a2[0] * iv, a2[1] * iv);
  o.w = pack2(a3[0] * iv, a3[1] * iv);
  *(uint4*)(J.agg + (size_t)node * D128 + sl * 8) = o;
}

// ---- DUAL-EDGE-TYPE SAGE for app dst: both contributions in one pass ----
//  v = l2n(aggA@WlA^T+bA + x@WrA^T) + l2n(aggB@WlB^T+bB + x@WrB^T)
//  4 weight matrices in 128KB swizzled LDS (1 block/CU; VGPRs free headroom).
//  Dual compute + CLF numerics proven in R3; epilogues are the safe patterns:
//  OUT=0: relu(v) -> f32 scalar store (64B chunks, R2-proven no amplification)
//  OUT=1: classifier logits f32 (h2a round-trip eliminated)
template <int XBF, int CLF>
__global__ __launch_bounds__(512)
void sage_dual2(const ushort_t* __restrict__ aggA, const ushort_t* __restrict__ aggB,
                const void* __restrict__ xv,
                const ushort_t* __restrict__ wlA, const ushort_t* __restrict__ wrA,
                const ushort_t* __restrict__ wlB, const ushort_t* __restrict__ wrB,
                const float* __restrict__ biasA, const float* __restrict__ biasB,
                const float* __restrict__ clfW, const float* __restrict__ clfb,
                void* __restrict__ outv, int ntiles) {
  extern __shared__ char smem[];  // 131072 = 4 x (128x128 bf16) swizzled
  const int tid = threadIdx.x;

  for (int c = tid; c < 8192; c += 512) {
    int m = c >> 11, cc = c & 2047;
    int row = cc >> 4, slot = cc & 15;
    const ushort_t* W = m == 0 ? wlA : m == 1 ? wrA : m == 2 ? wlB : wrB;
    uint4 v = *((const uint4*)W + cc);
    *(uint4*)(smem + m * 32768 + row * 256 + ((slot ^ (row & 15)) << 4)) = v;
  }
  __syncthreads();

  int wid = tid >> 6, lane = tid & 63;
  int r = lane & 15, kh = lane >> 4;
  int tile = blockIdx.x * 8 + wid;
  if (tile >= ntiles) return;
  size_t n0 = (size_t)tile * 16;
  size_t rowe = (n0 + r) * D128 + kh * 8;

  uint4 A1[4], A3[4];
  bf16x8 XF[4];
#pragma unroll
  for (int kk = 0; kk < 4; kk++) {
    A1[kk] = *(const uint4*)(aggA + rowe + kk * 32);
    A3[kk] = *(const uint4*)(aggB + rowe + kk * 32);
  }
  if (XBF) {
    const ushort_t* xp = (const ushort_t*)xv + rowe;
#pragma unroll
    for (int kk = 0; kk < 4; kk++) XF[kk] = as_h(*(const uint4*)(xp + kk * 32));
  } else {
    const float* xp = (const float*)xv + rowe;
#pragma unroll
    for (int kk = 0; kk < 4; kk++) {
      f32x4 x0 = *(const f32x4*)(xp + kk * 32);
      f32x4 x1 = *(const f32x4*)(xp + kk * 32 + 4);
#pragma unroll
      for (int j = 0; j < 4; j++) {
        XF[kk][j] = f2bf(x0[j]);
        XF[kk][j + 4] = f2bf(x1[j]);
      }
    }
  }

  f32x4 acc1[8], acc3[8];
#pragma unroll
  for (int t = 0; t < 8; t++) {
    acc1[t] = (f32x4){0.f, 0.f, 0.f, 0.f};
    acc3[t] = (f32x4){0.f, 0.f, 0.f, 0.f};
  }

#pragma unroll
  for (int kk = 0; kk < 4; kk++) {
    int so = (((kk << 2) + kh) ^ r) << 4;
    bf16x8 af1 = as_h(A1[kk]);
    bf16x8 af3 = as_h(A3[kk]);
    bf16x8 xf = XF[kk];
#pragma unroll
    for (int t = 0; t < 8; t++) {
      const char* p = smem + t * 4096 + r * 256 + so;
      bf16x8 wla = *(const bf16x8*)(p);
      bf16x8 wra = *(const bf16x8*)(p + 32768);
      bf16x8 wlb = *(const bf16x8*)(p + 65536);
      bf16x8 wrb = *(const bf16x8*)(p + 98304);
      acc1[t] = __builtin_amdgcn_mfma_f32_16x16x32_bf16(af1, wla, acc1[t], 0, 0, 0);
      acc1[t] = __builtin_amdgcn_mfma_f32_16x16x32_bf16(xf, wra, acc1[t], 0, 0, 0);
      acc3[t] = __builtin_amdgcn_mfma_f32_16x16x32_bf16(af3, wlb, acc3[t], 0, 0, 0);
      acc3[t] = __builtin_amdgcn_mfma_f32_16x16x32_bf16(xf, wrb, acc3[t], 0, 0, 0);
    }
  }

  float s1[4] = {0.f, 0.f, 0.f, 0.f}, s3[4] = {0.f, 0.f, 0.f, 0.f};
#pragma unroll
  for (int t = 0; t < 8; t++) {
    float bvA = biasA[t * 16 + r];
    float bvB = biasB[t * 16 + r];
#pragma unroll
    for (int q = 0; q < 4; q++) {
      float c1 = acc1[t][q] + bvA;
      acc1[t][q] = c1; s1[q] += c1 * c1;
      float c3 = acc3[t][q] + bvB;
      acc3[t][q] = c3; s3[q] += c3 * c3;
    }
  }
#pragma unroll
  for (int off = 1; off < 16; off <<= 1) {
#pragma unroll
    for (int q = 0; q < 4; q++) {
      s1[q] += __shfl_xor(s1[q], off);
      s3[q] += __shfl_xor(s3[q], off);
    }
  }
  float rn1[4], rn3[4];
#pragma unroll
  for (int q = 0; q < 4; q++) {
    rn1[q] = 1.0f / fmaxf(sqrtf(s1[q]), 1e-12f);
    rn3[q] = 1.0f / fmaxf(sqrtf(s3[q]), 1e-12f);
  }

  if (CLF) {
    float w0[8], w1[8];
#pragma unroll
    for (int t = 0; t < 8; t++) {
      w0[t] = clfW[t * 16 + r];
      w1[t] = clfW[D128 + t * 16 + r];
    }
    float p0[4] = {0.f, 0.f, 0.f, 0.f}, p1[4] = {0.f, 0.f, 0.f, 0.f};
#pragma unroll
    for (int t = 0; t < 8; t++) {
#pragma unroll
      for (int q = 0; q < 4; q++) {
        float val = acc1[t][q] * rn1[q] + acc3[t][q] * rn3[q];
        p0[q] += val * w0[t];
        p1[q] += val * w1[t];
      }
    }
#pragma unroll
    for (int off = 1; off < 16; off <<= 1) {
#pragma unroll
      for (int q = 0; q < 4; q++) {
        p0[q] += __shfl_xor(p0[q], off);
        p1[q] += __shfl_xor(p1[q], off);
      }
    }
    if (r == 0) {
      float cb0 = clfb[0], cb1 = clfb[1];
#pragma unroll
      for (int q = 0; q < 4; q++) {
        size_t node = n0 + kh * 4 + q;
        float2 o; o.x = p0[q] + cb0; o.y = p1[q] + cb1;
        *(float2*)((float*)outv + node * 2) = o;
      }
    }
  } else {
#pragma unroll
    for (int t = 0; t < 8; t++) {
#pragma unroll
      for (int q = 0; q < 4; q++) {
        float val = acc1[t][q] * rn1[q] + acc3[t][q] * rn3[q];
        size_t node = n0 + kh * 4 + q;
        ((float*)outv)[node * D128 + t * 16 + r] = fmaxf(val, 0.f);
      }
    }
  }
}

// ---- dual SAGE: two independent (XBF=1, BFOUT=1, OUTRELU=1) jobs ----
struct SJob {
  const ushort_t* agg;
  const ushort_t* x;
  const ushort_t* wl;
  const ushort_t* wr;
  const float* bias;
  ushort_t* out;
  int ntiles;
};

__global__ __launch_bounds__(512)
void sage_pair(SJob A, SJob B) {
  extern __shared__ char smem[];
  const SJob& J = blockIdx.y ? B : A;
  const int tid = threadIdx.x;

  for (int c = tid; c < 4096; c += 512) {
    int m = c >> 11, cc = c & 2047;
    int row = cc >> 4, slot = cc & 15;
    const ushort_t* W = m ? J.wr : J.wl;
    uint4 v = *((const uint4*)W + cc);
    *(uint4*)(smem + m * 32768 + row * 256 + ((slot ^ (row & 15)) << 4)) = v;
  }
  __syncthreads();

  int wid = tid >> 6, lane = tid & 63;
  int r = lane & 15, kh = lane >> 4;
  int tile = blockIdx.x * 8 + wid;
  if (tile >= J.ntiles) return;
  size_t n0 = (size_t)tile * 16;

  const ushort_t* ap = J.agg + (n0 + r) * D128 + kh * 8;
  const ushort_t* xp = J.x + (n0 + r) * D128 + kh * 8;
  uint4 A4[4], X4[4];
#pragma unroll
  for (int kk = 0; kk < 4; kk++) {
    A4[kk] = *(const uint4*)(ap + kk * 32);
    X4[kk] = *(const uint4*)(xp + kk * 32);
  }

  f32x4 acc[8];
#pragma unroll
  for (int t = 0; t < 8; t++) acc[t] = (f32x4){0.f, 0.f, 0.f, 0.f};

#pragma unroll
  for (int kk = 0; kk < 4; kk++) {
    int so = (((kk << 2) + kh) ^ r) << 4;
    bf16x8 af = as_h(A4[kk]);
    bf16x8 xf = as_h(X4[kk]);
#pragma unroll
    for (int t = 0; t < 8; t++) {
      const char* p = smem + t * 4096 + r * 256 + so;
      bf16x8 bwl = *(const bf16x8*)(p);
      bf16x8 bwr = *(const bf16x8*)(p + 32768);
      acc[t] = __builtin_amdgcn_mfma_f32_16x16x32_bf16(af, bwl, acc[t], 0, 0, 0);
      acc[t] = __builtin_amdgcn_mfma_f32_16x16x32_bf16(xf, bwr, acc[t], 0, 0, 0);
    }
  }

  float s[4] = {0.f, 0.f, 0.f, 0.f};
#pragma unroll
  for (int t = 0; t < 8; t++) {
    float bv = J.bias[t * 16 + r];
#pragma unroll
    for (int q = 0; q < 4; q++) {
      float c = acc[t][q] + bv;
      acc[t][q] = c;
      s[q] += c * c;
    }
  }
#pragma unroll
  for (int off = 1; off < 16; off <<= 1) {
#pragma unroll
    for (int q = 0; q < 4; q++) s[q] += __shfl_xor(s[q], off);
  }
  float rn[4];
#pragma unroll
  for (int q = 0; q < 4; q++) rn[q] = 1.0f / fmaxf(sqrtf(s[q]), 1e-12f);

#pragma unroll
  for (int t = 0; t < 8; t++) {
#pragma unroll
    for (int q = 0; q < 4; q++) {
      float val = fmaxf(acc[t][q] * rn[q], 0.f);
      float pv = __shfl_xor(val, 1);
      if ((r & 1) == 0) {
        size_t node = n0 + kh * 4 + q;
        *(uint*)(J.out + node * D128 + t * 16 + r) = pack2(val, pv);
      }
    }
  }
}

extern "C" void kernel_launch(void* const* d_in, const int* in_sizes, int n_in,
                              void* d_out, int out_size, void* d_ws, size_t ws_size,
                              hipStream_t stream) {
  const float* emb_app = (const float*)d_in[0];
  const float* emb_mer = (const float*)d_in[1];
  const float* emb_dev = (const float*)d_in[2];
  const float* c1Wl = (const float*)d_in[3];
  const float* c1bl = (const float*)d_in[4];
  const float* c1Wr = (const float*)d_in[5];
  const float* c2Wl = (const float*)d_in[6];
  const float* c2bl = (const float*)d_in[7];
  const float* c2Wr = (const float*)d_in[8];
  const float* clfW = (const float*)d_in[9];
  const float* clfb = (const float*)d_in[10];
  const int* e0 = (const int*)d_in[11];
  const int* e1 = (const int*)d_in[12];
  const int* e2 = (const int*)d_in[13];
  const int* e3 = (const int*)d_in[14];

  const int NA = in_sizes[0] / D128;
  const int NM = in_sizes[1] / D128;
  const int ND = in_sizes[2] / D128;
  const int E = in_sizes[11] / 2;
  float* out = (float*)d_out;

  char* wsb = (char*)d_ws;
  size_t off = 0;
  auto alloc = [&](size_t bytes) -> char* {
    char* p = wsb + off;
    off += (bytes + 511) & ~(size_t)511;
    return p;
  };
  ushort_t* wl1 = (ushort_t*)alloc((size_t)4 * 16384 * 2);
  ushort_t* wr1 = (ushort_t*)alloc((size_t)4 * 16384 * 2);
  ushort_t* wl2 = (ushort_t*)alloc((size_t)4 * 16384 * 2);
  ushort_t* wr2 = (ushort_t*)alloc((size_t)4 * 16384 * 2);

  // overlay region (R9-proven): embeddings bf16 live through layer 1 only
  size_t embBytes = ((size_t)NM + ND + NA) * D128 * 2;
  char* big = alloc(embBytes);
  ushort_t* emer = (ushort_t*)big;
  ushort_t* edev = emer + (size_t)NM * D128;
  ushort_t* eapp = edev + (size_t)ND * D128;

  ushort_t* h1m = (ushort_t*)alloc((size_t)NM * D128 * 2);
  ushort_t* h1d = (ushort_t*)alloc((size_t)ND * D128 * 2);
  float* h1a = (float*)alloc((size_t)NA * D128 * 4);
  ushort_t* aggA = (ushort_t*)alloc((size_t)NA * D128 * 2);
  ushort_t* aggB = (ushort_t*)alloc((size_t)NA * D128 * 2);
  int ncnt = NM + NA + ND + NA;
  int nb = (ncnt + 255) / 256;
  int* cnt = (int*)alloc((size_t)ncnt * 4);
  float* inv = (float*)alloc((size_t)ncnt * 4);
  int* ofs = (int*)alloc((size_t)ncnt * 4);
  int* bsum = (int*)alloc((size_t)nb * 4);
  int* pos = (int*)alloc((size_t)4 * E * 4);
  int* bucket = (int*)alloc((size_t)4 * E * 4);
  (void)ws_size;  // ~355 MB (< R9's proven ~369 MB)

  int b0 = 0, b1 = NM, b2 = NM + NA, b3 = NM + NA + ND;

  const int SMEM = 65536;
  const int SMEM2 = 131072;
  hipFuncSetAttribute((const void*)sage_pair,
                      hipFuncAttributeMaxDynamicSharedMemorySize, SMEM);
  hipFuncSetAttribute((const void*)sage_dual2<1, 0>,
                      hipFuncAttributeMaxDynamicSharedMemorySize, SMEM2);
  hipFuncSetAttribute((const void*)sage_dual2<0, 1>,
                      hipFuncAttributeMaxDynamicSharedMemorySize, SMEM2);

  // ---- weights cvt + interleaved {embedding cvt ∥ poscount} ----
  dim3 wg(64, 4);
  cvtW_k<<<wg, 256, 0, stream>>>(c1Wl, c1Wr, c2Wl, c2Wr, wl1, wr1, wl2, wr2);
  hipMemsetAsync(cnt, 0, (size_t)ncnt * 4, stream);
  int na4 = NA * 32, nm4 = NM * 32, nd4 = ND * 32;
  int nbC = (na4 + nm4 + nd4 + 255) / 256;
  int nbE4 = (E + 1023) / 1024;
  int nbA = 4 * nbE4;
  pre2_k<<<nbC + nbA, 256, 0, stream>>>(
      emb_app, emb_mer, emb_dev, eapp, emer, edev, na4, nm4, nd4, nbC,
      e0 + E, e1 + E, e2 + E, e3 + E, cnt, pos, E, nbE4, nbA, b0, b1, b2, b3);
  scan1_k<<<nb, 256, 0, stream>>>(cnt, bsum, ncnt);
  scan2_k<<<nb, 256, 0, stream>>>(cnt, bsum, ofs, inv, ncnt);
  dim3 eg((E + 511) / 512, 4);
  reorder4_k<<<eg, 256, 0, stream>>>(e0, e1, e2, e3, ofs, pos, bucket,
                                     E, b0, b1, b2, b3);

  auto ngrid = [](int n) { return (n + 15) / 16; };  // 16 nodes per block
  auto g8 = [](int nt) { return (nt + 7) / 8; };
  int tA = NA / 16, tM = NM / 16, tD = ND / 16;

  auto J = [&](const ushort_t* x, int b, ushort_t* a, int n) {
    GJob j; j.x = x; j.ofs = ofs + b; j.cnt = cnt + b; j.inv = inv + b;
    j.agg = a; j.n = n; return j;
  };

  // ---- layer 1 ----
  // k0 (app->mer) + k2 (app->dev)
  {
    dim3 gg(ngrid(NM > ND ? NM : ND), 2);
    agg2_k<0><<<gg, 256, 0, stream>>>(J(eapp, b0, aggA, NM), J(eapp, b2, aggB, ND), bucket);
  }
  {
    SJob SA; SA.agg = aggA; SA.x = emer; SA.wl = wl1 + 0 * 16384;
    SA.wr = wr1 + 0 * 16384; SA.bias = c1bl + 0 * D128; SA.out = h1m; SA.ntiles = tM;
    SJob SB; SB.agg = aggB; SB.x = edev; SB.wl = wl1 + 2 * 16384;
    SB.wr = wr1 + 2 * 16384; SB.bias = c1bl + 2 * D128; SB.out = h1d; SB.ntiles = tD;
    dim3 sg(g8(tM > tD ? tM : tD), 2);
    sage_pair<<<sg, 512, SMEM, stream>>>(SA, SB);
  }
  // k1 (mer->app) + k3 (dev->app) gathers, then ONE dual sage -> relu'd f32 h1a
  {
    dim3 gg(ngrid(NA), 2);
    agg2_k<0><<<gg, 256, 0, stream>>>(J(emer, b1, aggA, NA), J(edev, b3, aggB, NA), bucket);
  }
  sage_dual2<1, 0><<<g8(tA), 512, SMEM2, stream>>>(aggA, aggB, eapp,
      wl1 + 1 * 16384, wr1 + 1 * 16384, wl1 + 3 * 16384, wr1 + 3 * 16384,
      c1bl + 1 * D128, c1bl + 3 * D128, nullptr, nullptr, h1a, tA);

  // ---- layer 2 (dst=app only): gathers then ONE dual sage + fused classifier ----
  {
    dim3 gg(ngrid(NA), 2);
    agg2_k<1><<<gg, 256, 0, stream>>>(J(h1m, b1, aggA, NA), J(h1d, b3, aggB, NA), bucket);
  }
  sage_dual2<0, 1><<<g8(tA), 512, SMEM2, stream>>>(aggA, aggB, h1a,
      wl2 + 1 * 16384, wr2 + 1 * 16384, wl2 + 3 * 16384, wr2 + 3 * 16384,
      c2bl + 1 * D128, c2bl + 3 * D128, clfW, clfb, out, tA);
}

// Round 15
// 534.280 us; speedup vs baseline: 1.3666x; 1.0043x over previous
//
#include <hip/hip_runtime.h>
#include <hip/hip_bf16.h>

#define D128 128

typedef __attribute__((ext_vector_type(8))) short bf16x8;
typedef __attribute__((ext_vector_type(4))) float f32x4;
typedef __attribute__((ext_vector_type(2))) float f32x2;
typedef unsigned int uint;
typedef unsigned short ushort_t;

union U4 { uint4 u; bf16x8 h; };
__device__ __forceinline__ bf16x8 as_h(uint4 u) { U4 x; x.u = u; return x.h; }

__device__ __forceinline__ short f2bf(float f) {
  union { float f; unsigned u; } v; v.f = f;
  unsigned r = v.u + 0x7FFFu + ((v.u >> 16) & 1u);  // RNE
  return (short)(r >> 16);
}
__device__ __forceinline__ float bf_lo(uint v) {
  union { uint u; float f; } x; x.u = v << 16; return x.f;
}
__device__ __forceinline__ float bf_hi(uint v) {
  union { uint u; float f; } x; x.u = v & 0xFFFF0000u; return x.f;
}
__device__ __forceinline__ uint pack2(float a, float b) {
  return (uint)(unsigned short)f2bf(a) | ((uint)(unsigned short)f2bf(b) << 16);
}

// ---- 4 weight tensors in one launch (65536 f32 each = 16384 float4) ----
__global__ __launch_bounds__(256)
void cvtW_k(const float* __restrict__ w0, const float* __restrict__ w1,
            const float* __restrict__ w2, const float* __restrict__ w3,
            ushort_t* __restrict__ o0, ushort_t* __restrict__ o1,
            ushort_t* __restrict__ o2, ushort_t* __restrict__ o3) {
  int y = blockIdx.y;
  const float* in = y == 0 ? w0 : y == 1 ? w1 : y == 2 ? w2 : w3;
  ushort_t* out = y == 0 ? o0 : y == 1 ? o1 : y == 2 ? o2 : o3;
  int i = blockIdx.x * 256 + threadIdx.x;
  if (i >= 16384) return;
  float4 v = ((const float4*)in)[i];
  ushort4 o;
  o.x = (unsigned short)f2bf(v.x); o.y = (unsigned short)f2bf(v.y);
  o.z = (unsigned short)f2bf(v.z); o.w = (unsigned short)f2bf(v.w);
  ((ushort4*)out)[i] = o;
}

// ---- fused preprocessing, interleaved cvt ∥ poscount (R11-proven) ----
__global__ __launch_bounds__(256)
void pre2_k(const float* __restrict__ ia, const float* __restrict__ im,
            const float* __restrict__ id, ushort_t* __restrict__ oa,
            ushort_t* __restrict__ om, ushort_t* __restrict__ od,
            int na4, int nm4, int nd4, int nbC,
            const int* __restrict__ d0, const int* __restrict__ d1,
            const int* __restrict__ d2, const int* __restrict__ d3,
            int* __restrict__ cnt, int* __restrict__ pos,
            int nE, int nbE4, int nbA,
            int b0, int b1, int b2, int b3) {
  int bx = blockIdx.x, tid = threadIdx.x;
  int total = nbC + nbA;
  long long s = ((long long)bx * nbA) / total;
  long long t = ((long long)(bx + 1) * nbA) / total;
  if (t > s) {
    int ab = (int)s;
    int y = ab / nbE4;
    int blk = ab - y * nbE4;
    const int* d = y == 0 ? d0 : y == 1 ? d1 : y == 2 ? d2 : d3;
    int base = y == 0 ? b0 : y == 1 ? b1 : y == 2 ? b2 : b3;
#pragma unroll
    for (int u = 0; u < 4; u++) {
      int i = blk * 1024 + u * 256 + tid;
      if (i < nE) {
        int p = atomicAdd(&cnt[base + d[i]], 1);
        pos[(size_t)y * nE + i] = p;
      }
    }
  } else {
    int i = (int)(bx - s) * 256 + tid;
    const float* in; ushort_t* out; int k;
    if (i < na4) { in = ia; out = oa; k = i; }
    else if (i < na4 + nm4) { in = im; out = om; k = i - na4; }
    else if (i < na4 + nm4 + nd4) { in = id; out = od; k = i - na4 - nm4; }
    else return;
    float4 v = ((const float4*)in)[k];
    ushort4 o;
    o.x = (unsigned short)f2bf(v.x); o.y = (unsigned short)f2bf(v.y);
    o.z = (unsigned short)f2bf(v.z); o.w = (unsigned short)f2bf(v.w);
    ((ushort4*)out)[k] = o;
  }
}

// ---- scan stage 1 ----
__device__ __forceinline__ int wave_incl_scan(int v, int lane) {
#pragma unroll
  for (int off = 1; off < 64; off <<= 1) {
    int y = __shfl_up(v, off);
    if (lane >= off) v += y;
  }
  return v;
}

__global__ __launch_bounds__(256) void scan1_k(const int* __restrict__ cnt,
                                               int* __restrict__ bsum, int n) {
  int b = blockIdx.x, tid = threadIdx.x;
  int i = b * 256 + tid;
  int v = (i < n) ? cnt[i] : 0;
  int lane = tid & 63, wid = tid >> 6;
  __shared__ int ws[4];
  int s = wave_incl_scan(v, lane);
  if (lane == 63) ws[wid] = s;
  __syncthreads();
  if (tid == 0) bsum[b] = ws[0] + ws[1] + ws[2] + ws[3];
}

// ---- scan stage 2 (+ inv fold) ----
__global__ __launch_bounds__(256) void scan2_k(const int* __restrict__ cnt,
                                               const int* __restrict__ bsum,
                                               int* __restrict__ ofs,
                                               float* __restrict__ inv, int n) {
  int b = blockIdx.x, tid = threadIdx.x;
  int lane = tid & 63, wid = tid >> 6;
  __shared__ int wsA[4], wsB[4];
  int p = 0;
  for (int j = tid; j < b; j += 256) p += bsum[j];
#pragma unroll
  for (int off = 32; off; off >>= 1) p += __shfl_xor(p, off);
  if (lane == 0) wsA[wid] = p;
  __syncthreads();
  int base = wsA[0] + wsA[1] + wsA[2] + wsA[3];
  int i = b * 256 + tid;
  int v = (i < n) ? cnt[i] : 0;
  int s = wave_incl_scan(v, lane);
  if (lane == 63) wsB[wid] = s;
  __syncthreads();
  int woff = 0;
  for (int w = 0; w < wid; w++) woff += wsB[w];
  int excl = base + woff + s - v;
  if (i < n) {
    ofs[i] = excl;
    inv[i] = 1.0f / (float)(v > 1 ? v : 1);
  }
}

// ---- reorder: bucket fill with NO atomics, 2 edges/thread ----
__global__ __launch_bounds__(256)
void reorder4_k(const int* __restrict__ e0, const int* __restrict__ e1,
                const int* __restrict__ e2, const int* __restrict__ e3,
                const int* __restrict__ ofs, const int* __restrict__ pos,
                int* __restrict__ bucket,
                int nE, int b0, int b1, int b2, int b3) {
  int y = blockIdx.y;
  const int* e = y == 0 ? e0 : y == 1 ? e1 : y == 2 ? e2 : e3;
  int base = y == 0 ? b0 : y == 1 ? b1 : y == 2 ? b2 : b3;
#pragma unroll
  for (int u = 0; u < 2; u++) {
    int i = blockIdx.x * 512 + u * 256 + threadIdx.x;
    if (i < nE) {
      int s = e[i];
      int d = e[nE + i];
      int p = pos[(size_t)y * nE + i];
      bucket[ofs[base + d] + p] = s;
    }
  }
}

// ---- dual CSR gather-mean, GROUP-PER-NODE (R13-proven) ----
struct GJob {
  const ushort_t* x;
  const int* ofs;
  const int* cnt;
  const float* inv;
  ushort_t* agg;
  int n;
};

template <int RELU>
__global__ __launch_bounds__(256)
void agg2_k(GJob A, GJob B, const int* __restrict__ bucket) {
  const GJob& J = blockIdx.y ? B : A;
  int gwave = (int)(((size_t)blockIdx.x * 256 + threadIdx.x) >> 6);
  int lane = threadIdx.x & 63;
  int g = lane >> 4, sl = lane & 15;
  int node = gwave * 4 + g;
  if (node >= J.n) return;
  int beg = J.ofs[node], c = J.cnt[node];
  float iv = J.inv[node];
  const ushort_t* xsrc = J.x;

  f32x2 a0 = {0.f, 0.f}, a1 = {0.f, 0.f}, a2 = {0.f, 0.f}, a3 = {0.f, 0.f};
  auto accum = [&](uint4 v) {
    f32x2 p0 = {bf_lo(v.x), bf_hi(v.x)};
    f32x2 p1 = {bf_lo(v.y), bf_hi(v.y)};
    f32x2 p2 = {bf_lo(v.z), bf_hi(v.z)};
    f32x2 p3 = {bf_lo(v.w), bf_hi(v.w)};
    if (RELU) {
      p0[0] = fmaxf(p0[0], 0.f); p0[1] = fmaxf(p0[1], 0.f);
      p1[0] = fmaxf(p1[0], 0.f); p1[1] = fmaxf(p1[1], 0.f);
      p2[0] = fmaxf(p2[0], 0.f); p2[1] = fmaxf(p2[1], 0.f);
      p3[0] = fmaxf(p3[0], 0.f); p3[1] = fmaxf(p3[1], 0.f);
    }
    a0 += p0; a1 += p1; a2 += p2; a3 += p3;
  };

  int j = 0;
  for (; j + 2 <= c; j += 2) {
    int s0 = bucket[beg + j], s1 = bucket[beg + j + 1];
    uint4 v0 = *(const uint4*)(xsrc + (size_t)s0 * D128 + sl * 8);
    uint4 v1 = *(const uint4*)(xsrc + (size_t)s1 * D128 + sl * 8);
    accum(v0); accum(v1);
  }
  if (j < c) {
    uint4 v0 = *(const uint4*)(xsrc + (size_t)bucket[beg + j] * D128 + sl * 8);
    accum(v0);
  }

  uint4 o;
  o.x = pack2(a0[0] * iv, a0[1] * iv);
  o.y = pack2(a1[0] * iv, a1[1] * iv);
  o.z = pack2(a2[0] * iv, a2[1] * iv);
  o.w = pack2(a3[0] * iv, a3[1] * iv);
  *(uint4*)(J.agg + (size_t)node * D128 + sl * 8) = o;
}

// ---- DUAL-EDGE-TYPE SAGE for app dst (R14 numerics) ----
//  Now 1024 threads (16 waves) per block: 128KB LDS caps at 1 block/CU, so
//  wider blocks double waves/CU (8 -> 16) for latency hiding. 68 VGPR << 128.
template <int XBF, int CLF>
__global__ __launch_bounds__(1024)
void sage_dual2(const ushort_t* __restrict__ aggA, const ushort_t* __restrict__ aggB,
                const void* __restrict__ xv,
                const ushort_t* __restrict__ wlA, const ushort_t* __restrict__ wrA,
                const ushort_t* __restrict__ wlB, const ushort_t* __restrict__ wrB,
                const float* __restrict__ biasA, const float* __restrict__ biasB,
                const float* __restrict__ clfW, const float* __restrict__ clfb,
                void* __restrict__ outv, int ntiles) {
  extern __shared__ char smem[];  // 131072 = 4 x (128x128 bf16) swizzled
  const int tid = threadIdx.x;

  for (int c = tid; c < 8192; c += 1024) {
    int m = c >> 11, cc = c & 2047;
    int row = cc >> 4, slot = cc & 15;
    const ushort_t* W = m == 0 ? wlA : m == 1 ? wrA : m == 2 ? wlB : wrB;
    uint4 v = *((const uint4*)W + cc);
    *(uint4*)(smem + m * 32768 + row * 256 + ((slot ^ (row & 15)) << 4)) = v;
  }
  __syncthreads();

  int wid = tid >> 6, lane = tid & 63;
  int r = lane & 15, kh = lane >> 4;
  int tile = blockIdx.x * 16 + wid;
  if (tile >= ntiles) return;
  size_t n0 = (size_t)tile * 16;
  size_t rowe = (n0 + r) * D128 + kh * 8;

  uint4 A1[4], A3[4];
  bf16x8 XF[4];
#pragma unroll
  for (int kk = 0; kk < 4; kk++) {
    A1[kk] = *(const uint4*)(aggA + rowe + kk * 32);
    A3[kk] = *(const uint4*)(aggB + rowe + kk * 32);
  }
  if (XBF) {
    const ushort_t* xp = (const ushort_t*)xv + rowe;
#pragma unroll
    for (int kk = 0; kk < 4; kk++) XF[kk] = as_h(*(const uint4*)(xp + kk * 32));
  } else {
    const float* xp = (const float*)xv + rowe;
#pragma unroll
    for (int kk = 0; kk < 4; kk++) {
      f32x4 x0 = *(const f32x4*)(xp + kk * 32);
      f32x4 x1 = *(const f32x4*)(xp + kk * 32 + 4);
#pragma unroll
      for (int j = 0; j < 4; j++) {
        XF[kk][j] = f2bf(x0[j]);
        XF[kk][j + 4] = f2bf(x1[j]);
      }
    }
  }

  f32x4 acc1[8], acc3[8];
#pragma unroll
  for (int t = 0; t < 8; t++) {
    acc1[t] = (f32x4){0.f, 0.f, 0.f, 0.f};
    acc3[t] = (f32x4){0.f, 0.f, 0.f, 0.f};
  }

#pragma unroll
  for (int kk = 0; kk < 4; kk++) {
    int so = (((kk << 2) + kh) ^ r) << 4;
    bf16x8 af1 = as_h(A1[kk]);
    bf16x8 af3 = as_h(A3[kk]);
    bf16x8 xf = XF[kk];
#pragma unroll
    for (int t = 0; t < 8; t++) {
      const char* p = smem + t * 4096 + r * 256 + so;
      bf16x8 wla = *(const bf16x8*)(p);
      bf16x8 wra = *(const bf16x8*)(p + 32768);
      bf16x8 wlb = *(const bf16x8*)(p + 65536);
      bf16x8 wrb = *(const bf16x8*)(p + 98304);
      acc1[t] = __builtin_amdgcn_mfma_f32_16x16x32_bf16(af1, wla, acc1[t], 0, 0, 0);
      acc1[t] = __builtin_amdgcn_mfma_f32_16x16x32_bf16(xf, wra, acc1[t], 0, 0, 0);
      acc3[t] = __builtin_amdgcn_mfma_f32_16x16x32_bf16(af3, wlb, acc3[t], 0, 0, 0);
      acc3[t] = __builtin_amdgcn_mfma_f32_16x16x32_bf16(xf, wrb, acc3[t], 0, 0, 0);
    }
  }

  float s1[4] = {0.f, 0.f, 0.f, 0.f}, s3[4] = {0.f, 0.f, 0.f, 0.f};
#pragma unroll
  for (int t = 0; t < 8; t++) {
    float bvA = biasA[t * 16 + r];
    float bvB = biasB[t * 16 + r];
#pragma unroll
    for (int q = 0; q < 4; q++) {
      float c1 = acc1[t][q] + bvA;
      acc1[t][q] = c1; s1[q] += c1 * c1;
      float c3 = acc3[t][q] + bvB;
      acc3[t][q] = c3; s3[q] += c3 * c3;
    }
  }
#pragma unroll
  for (int off = 1; off < 16; off <<= 1) {
#pragma unroll
    for (int q = 0; q < 4; q++) {
      s1[q] += __shfl_xor(s1[q], off);
      s3[q] += __shfl_xor(s3[q], off);
    }
  }
  float rn1[4], rn3[4];
#pragma unroll
  for (int q = 0; q < 4; q++) {
    rn1[q] = 1.0f / fmaxf(sqrtf(s1[q]), 1e-12f);
    rn3[q] = 1.0f / fmaxf(sqrtf(s3[q]), 1e-12f);
  }

  if (CLF) {
    float w0[8], w1[8];
#pragma unroll
    for (int t = 0; t < 8; t++) {
      w0[t] = clfW[t * 16 + r];
      w1[t] = clfW[D128 + t * 16 + r];
    }
    float p0[4] = {0.f, 0.f, 0.f, 0.f}, p1[4] = {0.f, 0.f, 0.f, 0.f};
#pragma unroll
    for (int t = 0; t < 8; t++) {
#pragma unroll
      for (int q = 0; q < 4; q++) {
        float val = acc1[t][q] * rn1[q] + acc3[t][q] * rn3[q];
        p0[q] += val * w0[t];
        p1[q] += val * w1[t];
      }
    }
#pragma unroll
    for (int off = 1; off < 16; off <<= 1) {
#pragma unroll
      for (int q = 0; q < 4; q++) {
        p0[q] += __shfl_xor(p0[q], off);
        p1[q] += __shfl_xor(p1[q], off);
      }
    }
    if (r == 0) {
      float cb0 = clfb[0], cb1 = clfb[1];
#pragma unroll
      for (int q = 0; q < 4; q++) {
        size_t node = n0 + kh * 4 + q;
        float2 o; o.x = p0[q] + cb0; o.y = p1[q] + cb1;
        *(float2*)((float*)outv + node * 2) = o;
      }
    }
  } else {
#pragma unroll
    for (int t = 0; t < 8; t++) {
#pragma unroll
      for (int q = 0; q < 4; q++) {
        float val = acc1[t][q] * rn1[q] + acc3[t][q] * rn3[q];
        size_t node = n0 + kh * 4 + q;
        ((float*)outv)[node * D128 + t * 16 + r] = fmaxf(val, 0.f);
      }
    }
  }
}

// ---- dual SAGE: two independent (XBF=1, BFOUT=1, OUTRELU=1) jobs ----
struct SJob {
  const ushort_t* agg;
  const ushort_t* x;
  const ushort_t* wl;
  const ushort_t* wr;
  const float* bias;
  ushort_t* out;
  int ntiles;
};

__global__ __launch_bounds__(512)
void sage_pair(SJob A, SJob B) {
  extern __shared__ char smem[];
  const SJob& J = blockIdx.y ? B : A;
  const int tid = threadIdx.x;

  for (int c = tid; c < 4096; c += 512) {
    int m = c >> 11, cc = c & 2047;
    int row = cc >> 4, slot = cc & 15;
    const ushort_t* W = m ? J.wr : J.wl;
    uint4 v = *((const uint4*)W + cc);
    *(uint4*)(smem + m * 32768 + row * 256 + ((slot ^ (row & 15)) << 4)) = v;
  }
  __syncthreads();

  int wid = tid >> 6, lane = tid & 63;
  int r = lane & 15, kh = lane >> 4;
  int tile = blockIdx.x * 8 + wid;
  if (tile >= J.ntiles) return;
  size_t n0 = (size_t)tile * 16;

  const ushort_t* ap = J.agg + (n0 + r) * D128 + kh * 8;
  const ushort_t* xp = J.x + (n0 + r) * D128 + kh * 8;
  uint4 A4[4], X4[4];
#pragma unroll
  for (int kk = 0; kk < 4; kk++) {
    A4[kk] = *(const uint4*)(ap + kk * 32);
    X4[kk] = *(const uint4*)(xp + kk * 32);
  }

  f32x4 acc[8];
#pragma unroll
  for (int t = 0; t < 8; t++) acc[t] = (f32x4){0.f, 0.f, 0.f, 0.f};

#pragma unroll
  for (int kk = 0; kk < 4; kk++) {
    int so = (((kk << 2) + kh) ^ r) << 4;
    bf16x8 af = as_h(A4[kk]);
    bf16x8 xf = as_h(X4[kk]);
#pragma unroll
    for (int t = 0; t < 8; t++) {
      const char* p = smem + t * 4096 + r * 256 + so;
      bf16x8 bwl = *(const bf16x8*)(p);
      bf16x8 bwr = *(const bf16x8*)(p + 32768);
      acc[t] = __builtin_amdgcn_mfma_f32_16x16x32_bf16(af, bwl, acc[t], 0, 0, 0);
      acc[t] = __builtin_amdgcn_mfma_f32_16x16x32_bf16(xf, bwr, acc[t], 0, 0, 0);
    }
  }

  float s[4] = {0.f, 0.f, 0.f, 0.f};
#pragma unroll
  for (int t = 0; t < 8; t++) {
    float bv = J.bias[t * 16 + r];
#pragma unroll
    for (int q = 0; q < 4; q++) {
      float c = acc[t][q] + bv;
      acc[t][q] = c;
      s[q] += c * c;
    }
  }
#pragma unroll
  for (int off = 1; off < 16; off <<= 1) {
#pragma unroll
    for (int q = 0; q < 4; q++) s[q] += __shfl_xor(s[q], off);
  }
  float rn[4];
#pragma unroll
  for (int q = 0; q < 4; q++) rn[q] = 1.0f / fmaxf(sqrtf(s[q]), 1e-12f);

#pragma unroll
  for (int t = 0; t < 8; t++) {
#pragma unroll
    for (int q = 0; q < 4; q++) {
      float val = fmaxf(acc[t][q] * rn[q], 0.f);
      float pv = __shfl_xor(val, 1);
      if ((r & 1) == 0) {
        size_t node = n0 + kh * 4 + q;
        *(uint*)(J.out + node * D128 + t * 16 + r) = pack2(val, pv);
      }
    }
  }
}

extern "C" void kernel_launch(void* const* d_in, const int* in_sizes, int n_in,
                              void* d_out, int out_size, void* d_ws, size_t ws_size,
                              hipStream_t stream) {
  const float* emb_app = (const float*)d_in[0];
  const float* emb_mer = (const float*)d_in[1];
  const float* emb_dev = (const float*)d_in[2];
  const float* c1Wl = (const float*)d_in[3];
  const float* c1bl = (const float*)d_in[4];
  const float* c1Wr = (const float*)d_in[5];
  const float* c2Wl = (const float*)d_in[6];
  const float* c2bl = (const float*)d_in[7];
  const float* c2Wr = (const float*)d_in[8];
  const float* clfW = (const float*)d_in[9];
  const float* clfb = (const float*)d_in[10];
  const int* e0 = (const int*)d_in[11];
  const int* e1 = (const int*)d_in[12];
  const int* e2 = (const int*)d_in[13];
  const int* e3 = (const int*)d_in[14];

  const int NA = in_sizes[0] / D128;
  const int NM = in_sizes[1] / D128;
  const int ND = in_sizes[2] / D128;
  const int E = in_sizes[11] / 2;
  float* out = (float*)d_out;

  char* wsb = (char*)d_ws;
  size_t off = 0;
  auto alloc = [&](size_t bytes) -> char* {
    char* p = wsb + off;
    off += (bytes + 511) & ~(size_t)511;
    return p;
  };
  ushort_t* wl1 = (ushort_t*)alloc((size_t)4 * 16384 * 2);
  ushort_t* wr1 = (ushort_t*)alloc((size_t)4 * 16384 * 2);
  ushort_t* wl2 = (ushort_t*)alloc((size_t)4 * 16384 * 2);
  ushort_t* wr2 = (ushort_t*)alloc((size_t)4 * 16384 * 2);

  // overlay region (R9-proven): embeddings bf16 live through layer 1 only
  size_t embBytes = ((size_t)NM + ND + NA) * D128 * 2;
  char* big = alloc(embBytes);
  ushort_t* emer = (ushort_t*)big;
  ushort_t* edev = emer + (size_t)NM * D128;
  ushort_t* eapp = edev + (size_t)ND * D128;

  ushort_t* h1m = (ushort_t*)alloc((size_t)NM * D128 * 2);
  ushort_t* h1d = (ushort_t*)alloc((size_t)ND * D128 * 2);
  float* h1a = (float*)alloc((size_t)NA * D128 * 4);
  ushort_t* aggA = (ushort_t*)alloc((size_t)NA * D128 * 2);
  ushort_t* aggB = (ushort_t*)alloc((size_t)NA * D128 * 2);
  int ncnt = NM + NA + ND + NA;
  int nb = (ncnt + 255) / 256;
  int* cnt = (int*)alloc((size_t)ncnt * 4);
  float* inv = (float*)alloc((size_t)ncnt * 4);
  int* ofs = (int*)alloc((size_t)ncnt * 4);
  int* bsum = (int*)alloc((size_t)nb * 4);
  int* pos = (int*)alloc((size_t)4 * E * 4);
  int* bucket = (int*)alloc((size_t)4 * E * 4);
  (void)ws_size;  // ~355 MB

  int b0 = 0, b1 = NM, b2 = NM + NA, b3 = NM + NA + ND;

  const int SMEM = 65536;
  const int SMEM2 = 131072;
  hipFuncSetAttribute((const void*)sage_pair,
                      hipFuncAttributeMaxDynamicSharedMemorySize, SMEM);
  hipFuncSetAttribute((const void*)sage_dual2<1, 0>,
                      hipFuncAttributeMaxDynamicSharedMemorySize, SMEM2);
  hipFuncSetAttribute((const void*)sage_dual2<0, 1>,
                      hipFuncAttributeMaxDynamicSharedMemorySize, SMEM2);

  // ---- weights cvt + interleaved {embedding cvt ∥ poscount} ----
  dim3 wg(64, 4);
  cvtW_k<<<wg, 256, 0, stream>>>(c1Wl, c1Wr, c2Wl, c2Wr, wl1, wr1, wl2, wr2);
  hipMemsetAsync(cnt, 0, (size_t)ncnt * 4, stream);
  int na4 = NA * 32, nm4 = NM * 32, nd4 = ND * 32;
  int nbC = (na4 + nm4 + nd4 + 255) / 256;
  int nbE4 = (E + 1023) / 1024;
  int nbA = 4 * nbE4;
  pre2_k<<<nbC + nbA, 256, 0, stream>>>(
      emb_app, emb_mer, emb_dev, eapp, emer, edev, na4, nm4, nd4, nbC,
      e0 + E, e1 + E, e2 + E, e3 + E, cnt, pos, E, nbE4, nbA, b0, b1, b2, b3);
  scan1_k<<<nb, 256, 0, stream>>>(cnt, bsum, ncnt);
  scan2_k<<<nb, 256, 0, stream>>>(cnt, bsum, ofs, inv, ncnt);
  dim3 eg((E + 511) / 512, 4);
  reorder4_k<<<eg, 256, 0, stream>>>(e0, e1, e2, e3, ofs, pos, bucket,
                                     E, b0, b1, b2, b3);

  auto ngrid = [](int n) { return (n + 15) / 16; };   // 16 nodes per block
  auto g8 = [](int nt) { return (nt + 7) / 8; };      // 8 waves/block
  auto g16 = [](int nt) { return (nt + 15) / 16; };   // 16 waves/block
  int tA = NA / 16, tM = NM / 16, tD = ND / 16;

  auto J = [&](const ushort_t* x, int b, ushort_t* a, int n) {
    GJob j; j.x = x; j.ofs = ofs + b; j.cnt = cnt + b; j.inv = inv + b;
    j.agg = a; j.n = n; return j;
  };

  // ---- layer 1 ----
  // k0 (app->mer) + k2 (app->dev)
  {
    dim3 gg(ngrid(NM > ND ? NM : ND), 2);
    agg2_k<0><<<gg, 256, 0, stream>>>(J(eapp, b0, aggA, NM), J(eapp, b2, aggB, ND), bucket);
  }
  {
    SJob SA; SA.agg = aggA; SA.x = emer; SA.wl = wl1 + 0 * 16384;
    SA.wr = wr1 + 0 * 16384; SA.bias = c1bl + 0 * D128; SA.out = h1m; SA.ntiles = tM;
    SJob SB; SB.agg = aggB; SB.x = edev; SB.wl = wl1 + 2 * 16384;
    SB.wr = wr1 + 2 * 16384; SB.bias = c1bl + 2 * D128; SB.out = h1d; SB.ntiles = tD;
    dim3 sg(g8(tM > tD ? tM : tD), 2);
    sage_pair<<<sg, 512, SMEM, stream>>>(SA, SB);
  }
  // k1 (mer->app) + k3 (dev->app) gathers, then ONE dual sage -> relu'd f32 h1a
  {
    dim3 gg(ngrid(NA), 2);
    agg2_k<0><<<gg, 256, 0, stream>>>(J(emer, b1, aggA, NA), J(edev, b3, aggB, NA), bucket);
  }
  sage_dual2<1, 0><<<g16(tA), 1024, SMEM2, stream>>>(aggA, aggB, eapp,
      wl1 + 1 * 16384, wr1 + 1 * 16384, wl1 + 3 * 16384, wr1 + 3 * 16384,
      c1bl + 1 * D128, c1bl + 3 * D128, nullptr, nullptr, h1a, tA);

  // ---- layer 2 (dst=app only): gathers then ONE dual sage + fused classifier ----
  {
    dim3 gg(ngrid(NA), 2);
    agg2_k<1><<<gg, 256, 0, stream>>>(J(h1m, b1, aggA, NA), J(h1d, b3, aggB, NA), bucket);
  }
  sage_dual2<0, 1><<<g16(tA), 1024, SMEM2, stream>>>(aggA, aggB, h1a,
      wl2 + 1 * 16384, wr2 + 1 * 16384, wl2 + 3 * 16384, wr2 + 3 * 16384,
      c2bl + 1 * D128, c2bl + 3 * D128, clfW, clfb, out, tA);
}

// Round 16
// 489.130 us; speedup vs baseline: 1.4927x; 1.0923x over previous
//
#include <hip/hip_runtime.h>
#include <hip/hip_bf16.h>

#define D128 128

typedef __attribute__((ext_vector_type(8))) short bf16x8;
typedef __attribute__((ext_vector_type(4))) float f32x4;
typedef __attribute__((ext_vector_type(2))) float f32x2;
typedef unsigned int uint;
typedef unsigned short ushort_t;

union U4 { uint4 u; bf16x8 h; };
__device__ __forceinline__ bf16x8 as_h(uint4 u) { U4 x; x.u = u; return x.h; }

__device__ __forceinline__ short f2bf(float f) {
  union { float f; unsigned u; } v; v.f = f;
  unsigned r = v.u + 0x7FFFu + ((v.u >> 16) & 1u);  // RNE
  return (short)(r >> 16);
}
__device__ __forceinline__ float bf_lo(uint v) {
  union { uint u; float f; } x; x.u = v << 16; return x.f;
}
__device__ __forceinline__ float bf_hi(uint v) {
  union { uint u; float f; } x; x.u = v & 0xFFFF0000u; return x.f;
}
__device__ __forceinline__ uint pack2(float a, float b) {
  return (uint)(unsigned short)f2bf(a) | ((uint)(unsigned short)f2bf(b) << 16);
}

// bf16 row write, 64B-contiguous per node per instruction (paired-t trick):
// even-r lanes cover cols [t0*16, t0*16+16), odd-r lanes [t1*16, t1*16+16);
// together bytes [t0*32, t0*32+64) -- same granularity as the proven f32 path.
__device__ __forceinline__ void store_pair_bf16(ushort_t* rowp, int r,
                                                int t0, int t1, float a, float b) {
  float sa = __shfl_xor(a, 1);
  float sb = __shfl_xor(b, 1);
  uint w; int colb;
  if ((r & 1) == 0) { w = pack2(a, sa); colb = t0 * 16 + r; }
  else             { w = pack2(sb, b); colb = t1 * 16 + (r - 1); }
  *(uint*)(rowp + colb) = w;
}

// ---- 4 weight tensors in one launch (65536 f32 each = 16384 float4) ----
__global__ __launch_bounds__(256)
void cvtW_k(const float* __restrict__ w0, const float* __restrict__ w1,
            const float* __restrict__ w2, const float* __restrict__ w3,
            ushort_t* __restrict__ o0, ushort_t* __restrict__ o1,
            ushort_t* __restrict__ o2, ushort_t* __restrict__ o3) {
  int y = blockIdx.y;
  const float* in = y == 0 ? w0 : y == 1 ? w1 : y == 2 ? w2 : w3;
  ushort_t* out = y == 0 ? o0 : y == 1 ? o1 : y == 2 ? o2 : o3;
  int i = blockIdx.x * 256 + threadIdx.x;
  if (i >= 16384) return;
  float4 v = ((const float4*)in)[i];
  ushort4 o;
  o.x = (unsigned short)f2bf(v.x); o.y = (unsigned short)f2bf(v.y);
  o.z = (unsigned short)f2bf(v.z); o.w = (unsigned short)f2bf(v.w);
  ((ushort4*)out)[i] = o;
}

// ---- fused preprocessing, interleaved cvt ∥ poscount (R11-proven) ----
__global__ __launch_bounds__(256)
void pre2_k(const float* __restrict__ ia, const float* __restrict__ im,
            const float* __restrict__ id, ushort_t* __restrict__ oa,
            ushort_t* __restrict__ om, ushort_t* __restrict__ od,
            int na4, int nm4, int nd4, int nbC,
            const int* __restrict__ d0, const int* __restrict__ d1,
            const int* __restrict__ d2, const int* __restrict__ d3,
            int* __restrict__ cnt, int* __restrict__ pos,
            int nE, int nbE4, int nbA,
            int b0, int b1, int b2, int b3) {
  int bx = blockIdx.x, tid = threadIdx.x;
  int total = nbC + nbA;
  long long s = ((long long)bx * nbA) / total;
  long long t = ((long long)(bx + 1) * nbA) / total;
  if (t > s) {
    int ab = (int)s;
    int y = ab / nbE4;
    int blk = ab - y * nbE4;
    const int* d = y == 0 ? d0 : y == 1 ? d1 : y == 2 ? d2 : d3;
    int base = y == 0 ? b0 : y == 1 ? b1 : y == 2 ? b2 : b3;
#pragma unroll
    for (int u = 0; u < 4; u++) {
      int i = blk * 1024 + u * 256 + tid;
      if (i < nE) {
        int p = atomicAdd(&cnt[base + d[i]], 1);
        pos[(size_t)y * nE + i] = p;
      }
    }
  } else {
    int i = (int)(bx - s) * 256 + tid;
    const float* in; ushort_t* out; int k;
    if (i < na4) { in = ia; out = oa; k = i; }
    else if (i < na4 + nm4) { in = im; out = om; k = i - na4; }
    else if (i < na4 + nm4 + nd4) { in = id; out = od; k = i - na4 - nm4; }
    else return;
    float4 v = ((const float4*)in)[k];
    ushort4 o;
    o.x = (unsigned short)f2bf(v.x); o.y = (unsigned short)f2bf(v.y);
    o.z = (unsigned short)f2bf(v.z); o.w = (unsigned short)f2bf(v.w);
    ((ushort4*)out)[k] = o;
  }
}

// ---- scan stage 1 ----
__device__ __forceinline__ int wave_incl_scan(int v, int lane) {
#pragma unroll
  for (int off = 1; off < 64; off <<= 1) {
    int y = __shfl_up(v, off);
    if (lane >= off) v += y;
  }
  return v;
}

__global__ __launch_bounds__(256) void scan1_k(const int* __restrict__ cnt,
                                               int* __restrict__ bsum, int n) {
  int b = blockIdx.x, tid = threadIdx.x;
  int i = b * 256 + tid;
  int v = (i < n) ? cnt[i] : 0;
  int lane = tid & 63, wid = tid >> 6;
  __shared__ int ws[4];
  int s = wave_incl_scan(v, lane);
  if (lane == 63) ws[wid] = s;
  __syncthreads();
  if (tid == 0) bsum[b] = ws[0] + ws[1] + ws[2] + ws[3];
}

// ---- scan stage 2 (+ inv fold) ----
__global__ __launch_bounds__(256) void scan2_k(const int* __restrict__ cnt,
                                               const int* __restrict__ bsum,
                                               int* __restrict__ ofs,
                                               float* __restrict__ inv, int n) {
  int b = blockIdx.x, tid = threadIdx.x;
  int lane = tid & 63, wid = tid >> 6;
  __shared__ int wsA[4], wsB[4];
  int p = 0;
  for (int j = tid; j < b; j += 256) p += bsum[j];
#pragma unroll
  for (int off = 32; off; off >>= 1) p += __shfl_xor(p, off);
  if (lane == 0) wsA[wid] = p;
  __syncthreads();
  int base = wsA[0] + wsA[1] + wsA[2] + wsA[3];
  int i = b * 256 + tid;
  int v = (i < n) ? cnt[i] : 0;
  int s = wave_incl_scan(v, lane);
  if (lane == 63) wsB[wid] = s;
  __syncthreads();
  int woff = 0;
  for (int w = 0; w < wid; w++) woff += wsB[w];
  int excl = base + woff + s - v;
  if (i < n) {
    ofs[i] = excl;
    inv[i] = 1.0f / (float)(v > 1 ? v : 1);
  }
}

// ---- reorder: bucket fill with NO atomics, 2 edges/thread ----
__global__ __launch_bounds__(256)
void reorder4_k(const int* __restrict__ e0, const int* __restrict__ e1,
                const int* __restrict__ e2, const int* __restrict__ e3,
                const int* __restrict__ ofs, const int* __restrict__ pos,
                int* __restrict__ bucket,
                int nE, int b0, int b1, int b2, int b3) {
  int y = blockIdx.y;
  const int* e = y == 0 ? e0 : y == 1 ? e1 : y == 2 ? e2 : e3;
  int base = y == 0 ? b0 : y == 1 ? b1 : y == 2 ? b2 : b3;
#pragma unroll
  for (int u = 0; u < 2; u++) {
    int i = blockIdx.x * 512 + u * 256 + threadIdx.x;
    if (i < nE) {
      int s = e[i];
      int d = e[nE + i];
      int p = pos[(size_t)y * nE + i];
      bucket[ofs[base + d] + p] = s;
    }
  }
}

// ---- dual CSR gather-mean, GROUP-PER-NODE (R13-proven) ----
struct GJob {
  const ushort_t* x;
  const int* ofs;
  const int* cnt;
  const float* inv;
  ushort_t* agg;
  int n;
};

template <int RELU>
__global__ __launch_bounds__(256)
void agg2_k(GJob A, GJob B, const int* __restrict__ bucket) {
  const GJob& J = blockIdx.y ? B : A;
  int gwave = (int)(((size_t)blockIdx.x * 256 + threadIdx.x) >> 6);
  int lane = threadIdx.x & 63;
  int g = lane >> 4, sl = lane & 15;
  int node = gwave * 4 + g;
  if (node >= J.n) return;
  int beg = J.ofs[node], c = J.cnt[node];
  float iv = J.inv[node];
  const ushort_t* xsrc = J.x;

  f32x2 a0 = {0.f, 0.f}, a1 = {0.f, 0.f}, a2 = {0.f, 0.f}, a3 = {0.f, 0.f};
  auto accum = [&](uint4 v) {
    f32x2 p0 = {bf_lo(v.x), bf_hi(v.x)};
    f32x2 p1 = {bf_lo(v.y), bf_hi(v.y)};
    f32x2 p2 = {bf_lo(v.z), bf_hi(v.z)};
    f32x2 p3 = {bf_lo(v.w), bf_hi(v.w)};
    if (RELU) {
      p0[0] = fmaxf(p0[0], 0.f); p0[1] = fmaxf(p0[1], 0.f);
      p1[0] = fmaxf(p1[0], 0.f); p1[1] = fmaxf(p1[1], 0.f);
      p2[0] = fmaxf(p2[0], 0.f); p2[1] = fmaxf(p2[1], 0.f);
      p3[0] = fmaxf(p3[0], 0.f); p3[1] = fmaxf(p3[1], 0.f);
    }
    a0 += p0; a1 += p1; a2 += p2; a3 += p3;
  };

  int j = 0;
  for (; j + 2 <= c; j += 2) {
    int s0 = bucket[beg + j], s1 = bucket[beg + j + 1];
    uint4 v0 = *(const uint4*)(xsrc + (size_t)s0 * D128 + sl * 8);
    uint4 v1 = *(const uint4*)(xsrc + (size_t)s1 * D128 + sl * 8);
    accum(v0); accum(v1);
  }
  if (j < c) {
    uint4 v0 = *(const uint4*)(xsrc + (size_t)bucket[beg + j] * D128 + sl * 8);
    accum(v0);
  }

  uint4 o;
  o.x = pack2(a0[0] * iv, a0[1] * iv);
  o.y = pack2(a1[0] * iv, a1[1] * iv);
  o.z = pack2(a2[0] * iv, a2[1] * iv);
  o.w = pack2(a3[0] * iv, a3[1] * iv);
  *(uint4*)(J.agg + (size_t)node * D128 + sl * 8) = o;
}

// ---- DUAL-EDGE-TYPE SAGE for app dst (R14/R15 numerics) ----
//  OUT=0: relu(v) -> bf16 row via 64B paired-t writes (h1a now bf16, R3-proven)
//  OUT=1 (CLF): classifier logits f32
template <int CLF>
__global__ __launch_bounds__(1024)
void sage_dual2(const ushort_t* __restrict__ aggA, const ushort_t* __restrict__ aggB,
                const ushort_t* __restrict__ xv,
                const ushort_t* __restrict__ wlA, const ushort_t* __restrict__ wrA,
                const ushort_t* __restrict__ wlB, const ushort_t* __restrict__ wrB,
                const float* __restrict__ biasA, const float* __restrict__ biasB,
                const float* __restrict__ clfW, const float* __restrict__ clfb,
                void* __restrict__ outv, int ntiles) {
  extern __shared__ char smem[];  // 131072 = 4 x (128x128 bf16) swizzled
  const int tid = threadIdx.x;

  for (int c = tid; c < 8192; c += 1024) {
    int m = c >> 11, cc = c & 2047;
    int row = cc >> 4, slot = cc & 15;
    const ushort_t* W = m == 0 ? wlA : m == 1 ? wrA : m == 2 ? wlB : wrB;
    uint4 v = *((const uint4*)W + cc);
    *(uint4*)(smem + m * 32768 + row * 256 + ((slot ^ (row & 15)) << 4)) = v;
  }
  __syncthreads();

  int wid = tid >> 6, lane = tid & 63;
  int r = lane & 15, kh = lane >> 4;
  int tile = blockIdx.x * 16 + wid;
  if (tile >= ntiles) return;
  size_t n0 = (size_t)tile * 16;
  size_t rowe = (n0 + r) * D128 + kh * 8;

  uint4 A1[4], A3[4];
  bf16x8 XF[4];
#pragma unroll
  for (int kk = 0; kk < 4; kk++) {
    A1[kk] = *(const uint4*)(aggA + rowe + kk * 32);
    A3[kk] = *(const uint4*)(aggB + rowe + kk * 32);
    XF[kk] = as_h(*(const uint4*)(xv + rowe + kk * 32));
  }

  f32x4 acc1[8], acc3[8];
#pragma unroll
  for (int t = 0; t < 8; t++) {
    acc1[t] = (f32x4){0.f, 0.f, 0.f, 0.f};
    acc3[t] = (f32x4){0.f, 0.f, 0.f, 0.f};
  }

#pragma unroll
  for (int kk = 0; kk < 4; kk++) {
    int so = (((kk << 2) + kh) ^ r) << 4;
    bf16x8 af1 = as_h(A1[kk]);
    bf16x8 af3 = as_h(A3[kk]);
    bf16x8 xf = XF[kk];
#pragma unroll
    for (int t = 0; t < 8; t++) {
      const char* p = smem + t * 4096 + r * 256 + so;
      bf16x8 wla = *(const bf16x8*)(p);
      bf16x8 wra = *(const bf16x8*)(p + 32768);
      bf16x8 wlb = *(const bf16x8*)(p + 65536);
      bf16x8 wrb = *(const bf16x8*)(p + 98304);
      acc1[t] = __builtin_amdgcn_mfma_f32_16x16x32_bf16(af1, wla, acc1[t], 0, 0, 0);
      acc1[t] = __builtin_amdgcn_mfma_f32_16x16x32_bf16(xf, wra, acc1[t], 0, 0, 0);
      acc3[t] = __builtin_amdgcn_mfma_f32_16x16x32_bf16(af3, wlb, acc3[t], 0, 0, 0);
      acc3[t] = __builtin_amdgcn_mfma_f32_16x16x32_bf16(xf, wrb, acc3[t], 0, 0, 0);
    }
  }

  float s1[4] = {0.f, 0.f, 0.f, 0.f}, s3[4] = {0.f, 0.f, 0.f, 0.f};
#pragma unroll
  for (int t = 0; t < 8; t++) {
    float bvA = biasA[t * 16 + r];
    float bvB = biasB[t * 16 + r];
#pragma unroll
    for (int q = 0; q < 4; q++) {
      float c1 = acc1[t][q] + bvA;
      acc1[t][q] = c1; s1[q] += c1 * c1;
      float c3 = acc3[t][q] + bvB;
      acc3[t][q] = c3; s3[q] += c3 * c3;
    }
  }
#pragma unroll
  for (int off = 1; off < 16; off <<= 1) {
#pragma unroll
    for (int q = 0; q < 4; q++) {
      s1[q] += __shfl_xor(s1[q], off);
      s3[q] += __shfl_xor(s3[q], off);
    }
  }
  float rn1[4], rn3[4];
#pragma unroll
  for (int q = 0; q < 4; q++) {
    rn1[q] = 1.0f / fmaxf(sqrtf(s1[q]), 1e-12f);
    rn3[q] = 1.0f / fmaxf(sqrtf(s3[q]), 1e-12f);
  }

  if (CLF) {
    float w0[8], w1[8];
#pragma unroll
    for (int t = 0; t < 8; t++) {
      w0[t] = clfW[t * 16 + r];
      w1[t] = clfW[D128 + t * 16 + r];
    }
    float p0[4] = {0.f, 0.f, 0.f, 0.f}, p1[4] = {0.f, 0.f, 0.f, 0.f};
#pragma unroll
    for (int t = 0; t < 8; t++) {
#pragma unroll
      for (int q = 0; q < 4; q++) {
        float val = acc1[t][q] * rn1[q] + acc3[t][q] * rn3[q];
        p0[q] += val * w0[t];
        p1[q] += val * w1[t];
      }
    }
#pragma unroll
    for (int off = 1; off < 16; off <<= 1) {
#pragma unroll
      for (int q = 0; q < 4; q++) {
        p0[q] += __shfl_xor(p0[q], off);
        p1[q] += __shfl_xor(p1[q], off);
      }
    }
    if (r == 0) {
      float cb0 = clfb[0], cb1 = clfb[1];
#pragma unroll
      for (int q = 0; q < 4; q++) {
        size_t node = n0 + kh * 4 + q;
        float2 o; o.x = p0[q] + cb0; o.y = p1[q] + cb1;
        *(float2*)((float*)outv + node * 2) = o;
      }
    }
  } else {
#pragma unroll
    for (int tp = 0; tp < 4; tp++) {
      int t0 = 2 * tp, t1 = 2 * tp + 1;
#pragma unroll
      for (int q = 0; q < 4; q++) {
        float a = fmaxf(acc1[t0][q] * rn1[q] + acc3[t0][q] * rn3[q], 0.f);
        float b = fmaxf(acc1[t1][q] * rn1[q] + acc3[t1][q] * rn3[q], 0.f);
        size_t node = n0 + kh * 4 + q;
        store_pair_bf16((ushort_t*)outv + node * D128, r, t0, t1, a, b);
      }
    }
  }
}

// ---- dual SAGE: two independent jobs; bf16 out via 64B paired-t writes ----
struct SJob {
  const ushort_t* agg;
  const ushort_t* x;
  const ushort_t* wl;
  const ushort_t* wr;
  const float* bias;
  ushort_t* out;
  int ntiles;
};

__global__ __launch_bounds__(512)
void sage_pair(SJob A, SJob B) {
  extern __shared__ char smem[];
  const SJob& J = blockIdx.y ? B : A;
  const int tid = threadIdx.x;

  for (int c = tid; c < 4096; c += 512) {
    int m = c >> 11, cc = c & 2047;
    int row = cc >> 4, slot = cc & 15;
    const ushort_t* W = m ? J.wr : J.wl;
    uint4 v = *((const uint4*)W + cc);
    *(uint4*)(smem + m * 32768 + row * 256 + ((slot ^ (row & 15)) << 4)) = v;
  }
  __syncthreads();

  int wid = tid >> 6, lane = tid & 63;
  int r = lane & 15, kh = lane >> 4;
  int tile = blockIdx.x * 8 + wid;
  if (tile >= J.ntiles) return;
  size_t n0 = (size_t)tile * 16;

  const ushort_t* ap = J.agg + (n0 + r) * D128 + kh * 8;
  const ushort_t* xp = J.x + (n0 + r) * D128 + kh * 8;
  uint4 A4[4], X4[4];
#pragma unroll
  for (int kk = 0; kk < 4; kk++) {
    A4[kk] = *(const uint4*)(ap + kk * 32);
    X4[kk] = *(const uint4*)(xp + kk * 32);
  }

  f32x4 acc[8];
#pragma unroll
  for (int t = 0; t < 8; t++) acc[t] = (f32x4){0.f, 0.f, 0.f, 0.f};

#pragma unroll
  for (int kk = 0; kk < 4; kk++) {
    int so = (((kk << 2) + kh) ^ r) << 4;
    bf16x8 af = as_h(A4[kk]);
    bf16x8 xf = as_h(X4[kk]);
#pragma unroll
    for (int t = 0; t < 8; t++) {
      const char* p = smem + t * 4096 + r * 256 + so;
      bf16x8 bwl = *(const bf16x8*)(p);
      bf16x8 bwr = *(const bf16x8*)(p + 32768);
      acc[t] = __builtin_amdgcn_mfma_f32_16x16x32_bf16(af, bwl, acc[t], 0, 0, 0);
      acc[t] = __builtin_amdgcn_mfma_f32_16x16x32_bf16(xf, bwr, acc[t], 0, 0, 0);
    }
  }

  float s[4] = {0.f, 0.f, 0.f, 0.f};
#pragma unroll
  for (int t = 0; t < 8; t++) {
    float bv = J.bias[t * 16 + r];
#pragma unroll
    for (int q = 0; q < 4; q++) {
      float c = acc[t][q] + bv;
      acc[t][q] = c;
      s[q] += c * c;
    }
  }
#pragma unroll
  for (int off = 1; off < 16; off <<= 1) {
#pragma unroll
    for (int q = 0; q < 4; q++) s[q] += __shfl_xor(s[q], off);
  }
  float rn[4];
#pragma unroll
  for (int q = 0; q < 4; q++) rn[q] = 1.0f / fmaxf(sqrtf(s[q]), 1e-12f);

#pragma unroll
  for (int tp = 0; tp < 4; tp++) {
    int t0 = 2 * tp, t1 = 2 * tp + 1;
#pragma unroll
    for (int q = 0; q < 4; q++) {
      float a = fmaxf(acc[t0][q] * rn[q], 0.f);
      float b = fmaxf(acc[t1][q] * rn[q], 0.f);
      size_t node = n0 + kh * 4 + q;
      store_pair_bf16(J.out + node * D128, r, t0, t1, a, b);
    }
  }
}

extern "C" void kernel_launch(void* const* d_in, const int* in_sizes, int n_in,
                              void* d_out, int out_size, void* d_ws, size_t ws_size,
                              hipStream_t stream) {
  const float* emb_app = (const float*)d_in[0];
  const float* emb_mer = (const float*)d_in[1];
  const float* emb_dev = (const float*)d_in[2];
  const float* c1Wl = (const float*)d_in[3];
  const float* c1bl = (const float*)d_in[4];
  const float* c1Wr = (const float*)d_in[5];
  const float* c2Wl = (const float*)d_in[6];
  const float* c2bl = (const float*)d_in[7];
  const float* c2Wr = (const float*)d_in[8];
  const float* clfW = (const float*)d_in[9];
  const float* clfb = (const float*)d_in[10];
  const int* e0 = (const int*)d_in[11];
  const int* e1 = (const int*)d_in[12];
  const int* e2 = (const int*)d_in[13];
  const int* e3 = (const int*)d_in[14];

  const int NA = in_sizes[0] / D128;
  const int NM = in_sizes[1] / D128;
  const int ND = in_sizes[2] / D128;
  const int E = in_sizes[11] / 2;
  float* out = (float*)d_out;

  char* wsb = (char*)d_ws;
  size_t off = 0;
  auto alloc = [&](size_t bytes) -> char* {
    char* p = wsb + off;
    off += (bytes + 511) & ~(size_t)511;
    return p;
  };
  ushort_t* wl1 = (ushort_t*)alloc((size_t)4 * 16384 * 2);
  ushort_t* wr1 = (ushort_t*)alloc((size_t)4 * 16384 * 2);
  ushort_t* wl2 = (ushort_t*)alloc((size_t)4 * 16384 * 2);
  ushort_t* wr2 = (ushort_t*)alloc((size_t)4 * 16384 * 2);

  // overlay region (R9-proven): embeddings bf16 live through layer 1 only
  size_t embBytes = ((size_t)NM + ND + NA) * D128 * 2;
  char* big = alloc(embBytes);
  ushort_t* emer = (ushort_t*)big;
  ushort_t* edev = emer + (size_t)NM * D128;
  ushort_t* eapp = edev + (size_t)ND * D128;

  ushort_t* h1m = (ushort_t*)alloc((size_t)NM * D128 * 2);
  ushort_t* h1d = (ushort_t*)alloc((size_t)ND * D128 * 2);
  ushort_t* h1a = (ushort_t*)alloc((size_t)NA * D128 * 2);  // bf16 (R3-proven)
  ushort_t* aggA = (ushort_t*)alloc((size_t)NA * D128 * 2);
  ushort_t* aggB = (ushort_t*)alloc((size_t)NA * D128 * 2);
  int ncnt = NM + NA + ND + NA;
  int nb = (ncnt + 255) / 256;
  int* cnt = (int*)alloc((size_t)ncnt * 4);
  float* inv = (float*)alloc((size_t)ncnt * 4);
  int* ofs = (int*)alloc((size_t)ncnt * 4);
  int* bsum = (int*)alloc((size_t)nb * 4);
  int* pos = (int*)alloc((size_t)4 * E * 4);
  int* bucket = (int*)alloc((size_t)4 * E * 4);
  (void)ws_size;  // ~305 MB

  int b0 = 0, b1 = NM, b2 = NM + NA, b3 = NM + NA + ND;

  const int SMEM = 65536;
  const int SMEM2 = 131072;
  hipFuncSetAttribute((const void*)sage_pair,
                      hipFuncAttributeMaxDynamicSharedMemorySize, SMEM);
  hipFuncSetAttribute((const void*)sage_dual2<0>,
                      hipFuncAttributeMaxDynamicSharedMemorySize, SMEM2);
  hipFuncSetAttribute((const void*)sage_dual2<1>,
                      hipFuncAttributeMaxDynamicSharedMemorySize, SMEM2);

  // ---- weights cvt + interleaved {embedding cvt ∥ poscount} ----
  dim3 wg(64, 4);
  cvtW_k<<<wg, 256, 0, stream>>>(c1Wl, c1Wr, c2Wl, c2Wr, wl1, wr1, wl2, wr2);
  hipMemsetAsync(cnt, 0, (size_t)ncnt * 4, stream);
  int na4 = NA * 32, nm4 = NM * 32, nd4 = ND * 32;
  int nbC = (na4 + nm4 + nd4 + 255) / 256;
  int nbE4 = (E + 1023) / 1024;
  int nbA = 4 * nbE4;
  pre2_k<<<nbC + nbA, 256, 0, stream>>>(
      emb_app, emb_mer, emb_dev, eapp, emer, edev, na4, nm4, nd4, nbC,
      e0 + E, e1 + E, e2 + E, e3 + E, cnt, pos, E, nbE4, nbA, b0, b1, b2, b3);
  scan1_k<<<nb, 256, 0, stream>>>(cnt, bsum, ncnt);
  scan2_k<<<nb, 256, 0, stream>>>(cnt, bsum, ofs, inv, ncnt);
  dim3 eg((E + 511) / 512, 4);
  reorder4_k<<<eg, 256, 0, stream>>>(e0, e1, e2, e3, ofs, pos, bucket,
                                     E, b0, b1, b2, b3);

  auto ngrid = [](int n) { return (n + 15) / 16; };   // 16 nodes per block
  auto g8 = [](int nt) { return (nt + 7) / 8; };      // 8 waves/block
  auto g16 = [](int nt) { return (nt + 15) / 16; };   // 16 waves/block
  int tA = NA / 16, tM = NM / 16, tD = ND / 16;

  auto J = [&](const ushort_t* x, int b, ushort_t* a, int n) {
    GJob j; j.x = x; j.ofs = ofs + b; j.cnt = cnt + b; j.inv = inv + b;
    j.agg = a; j.n = n; return j;
  };

  // ---- layer 1 ----
  // k0 (app->mer) + k2 (app->dev)
  {
    dim3 gg(ngrid(NM > ND ? NM : ND), 2);
    agg2_k<0><<<gg, 256, 0, stream>>>(J(eapp, b0, aggA, NM), J(eapp, b2, aggB, ND), bucket);
  }
  {
    SJob SA; SA.agg = aggA; SA.x = emer; SA.wl = wl1 + 0 * 16384;
    SA.wr = wr1 + 0 * 16384; SA.bias = c1bl + 0 * D128; SA.out = h1m; SA.ntiles = tM;
    SJob SB; SB.agg = aggB; SB.x = edev; SB.wl = wl1 + 2 * 16384;
    SB.wr = wr1 + 2 * 16384; SB.bias = c1bl + 2 * D128; SB.out = h1d; SB.ntiles = tD;
    dim3 sg(g8(tM > tD ? tM : tD), 2);
    sage_pair<<<sg, 512, SMEM, stream>>>(SA, SB);
  }
  // k1 (mer->app) + k3 (dev->app) gathers, then ONE dual sage -> relu'd bf16 h1a
  {
    dim3 gg(ngrid(NA), 2);
    agg2_k<0><<<gg, 256, 0, stream>>>(J(emer, b1, aggA, NA), J(edev, b3, aggB, NA), bucket);
  }
  sage_dual2<0><<<g16(tA), 1024, SMEM2, stream>>>(aggA, aggB, eapp,
      wl1 + 1 * 16384, wr1 + 1 * 16384, wl1 + 3 * 16384, wr1 + 3 * 16384,
      c1bl + 1 * D128, c1bl + 3 * D128, nullptr, nullptr, h1a, tA);

  // ---- layer 2 (dst=app only): gathers then ONE dual sage + fused classifier ----
  {
    dim3 gg(ngrid(NA), 2);
    agg2_k<1><<<gg, 256, 0, stream>>>(J(h1m, b1, aggA, NA), J(h1d, b3, aggB, NA), bucket);
  }
  sage_dual2<1><<<g16(tA), 1024, SMEM2, stream>>>(aggA, aggB, h1a,
      wl2 + 1 * 16384, wr2 + 1 * 16384, wl2 + 3 * 16384, wr2 + 3 * 16384,
      c2bl + 1 * D128, c2bl + 3 * D128, clfW, clfb, out, tA);
}

// Round 17
// 478.835 us; speedup vs baseline: 1.5248x; 1.0215x over previous
//
#include <hip/hip_runtime.h>
#include <hip/hip_bf16.h>

#define D128 128

typedef __attribute__((ext_vector_type(8))) short bf16x8;
typedef __attribute__((ext_vector_type(4))) float f32x4;
typedef __attribute__((ext_vector_type(2))) float f32x2;
typedef unsigned int uint;
typedef unsigned short ushort_t;

union U4 { uint4 u; bf16x8 h; };
__device__ __forceinline__ bf16x8 as_h(uint4 u) { U4 x; x.u = u; return x.h; }

__device__ __forceinline__ short f2bf(float f) {
  union { float f; unsigned u; } v; v.f = f;
  unsigned r = v.u + 0x7FFFu + ((v.u >> 16) & 1u);  // RNE
  return (short)(r >> 16);
}
__device__ __forceinline__ float bf_lo(uint v) {
  union { uint u; float f; } x; x.u = v << 16; return x.f;
}
__device__ __forceinline__ float bf_hi(uint v) {
  union { uint u; float f; } x; x.u = v & 0xFFFF0000u; return x.f;
}
__device__ __forceinline__ uint pack2(float a, float b) {
  return (uint)(unsigned short)f2bf(a) | ((uint)(unsigned short)f2bf(b) << 16);
}

// bf16 row write, 64B-contiguous per node per instruction (R16-proven)
__device__ __forceinline__ void store_pair_bf16(ushort_t* rowp, int r,
                                                int t0, int t1, float a, float b) {
  float sa = __shfl_xor(a, 1);
  float sb = __shfl_xor(b, 1);
  uint w; int colb;
  if ((r & 1) == 0) { w = pack2(a, sa); colb = t0 * 16 + r; }
  else             { w = pack2(sb, b); colb = t1 * 16 + (r - 1); }
  *(uint*)(rowp + colb) = w;
}

// ---- 4 weight tensors in one launch ----
__global__ __launch_bounds__(256)
void cvtW_k(const float* __restrict__ w0, const float* __restrict__ w1,
            const float* __restrict__ w2, const float* __restrict__ w3,
            ushort_t* __restrict__ o0, ushort_t* __restrict__ o1,
            ushort_t* __restrict__ o2, ushort_t* __restrict__ o3) {
  int y = blockIdx.y;
  const float* in = y == 0 ? w0 : y == 1 ? w1 : y == 2 ? w2 : w3;
  ushort_t* out = y == 0 ? o0 : y == 1 ? o1 : y == 2 ? o2 : o3;
  int i = blockIdx.x * 256 + threadIdx.x;
  if (i >= 16384) return;
  float4 v = ((const float4*)in)[i];
  ushort4 o;
  o.x = (unsigned short)f2bf(v.x); o.y = (unsigned short)f2bf(v.y);
  o.z = (unsigned short)f2bf(v.z); o.w = (unsigned short)f2bf(v.w);
  ((ushort4*)out)[i] = o;
}

// ---- fused preprocessing, interleaved cvt ∥ poscount (R11-proven) ----
__global__ __launch_bounds__(256)
void pre2_k(const float* __restrict__ ia, const float* __restrict__ im,
            const float* __restrict__ id, ushort_t* __restrict__ oa,
            ushort_t* __restrict__ om, ushort_t* __restrict__ od,
            int na4, int nm4, int nd4, int nbC,
            const int* __restrict__ d0, const int* __restrict__ d1,
            const int* __restrict__ d2, const int* __restrict__ d3,
            int* __restrict__ cnt, int* __restrict__ pos,
            int nE, int nbE4, int nbA,
            int b0, int b1, int b2, int b3) {
  int bx = blockIdx.x, tid = threadIdx.x;
  int total = nbC + nbA;
  long long s = ((long long)bx * nbA) / total;
  long long t = ((long long)(bx + 1) * nbA) / total;
  if (t > s) {
    int ab = (int)s;
    int y = ab / nbE4;
    int blk = ab - y * nbE4;
    const int* d = y == 0 ? d0 : y == 1 ? d1 : y == 2 ? d2 : d3;
    int base = y == 0 ? b0 : y == 1 ? b1 : y == 2 ? b2 : b3;
#pragma unroll
    for (int u = 0; u < 4; u++) {
      int i = blk * 1024 + u * 256 + tid;
      if (i < nE) {
        int p = atomicAdd(&cnt[base + d[i]], 1);
        pos[(size_t)y * nE + i] = p;
      }
    }
  } else {
    int i = (int)(bx - s) * 256 + tid;
    const float* in; ushort_t* out; int k;
    if (i < na4) { in = ia; out = oa; k = i; }
    else if (i < na4 + nm4) { in = im; out = om; k = i - na4; }
    else if (i < na4 + nm4 + nd4) { in = id; out = od; k = i - na4 - nm4; }
    else return;
    float4 v = ((const float4*)in)[k];
    ushort4 o;
    o.x = (unsigned short)f2bf(v.x); o.y = (unsigned short)f2bf(v.y);
    o.z = (unsigned short)f2bf(v.z); o.w = (unsigned short)f2bf(v.w);
    ((ushort4*)out)[k] = o;
  }
}

// ---- scan stage 1 ----
__device__ __forceinline__ int wave_incl_scan(int v, int lane) {
#pragma unroll
  for (int off = 1; off < 64; off <<= 1) {
    int y = __shfl_up(v, off);
    if (lane >= off) v += y;
  }
  return v;
}

__global__ __launch_bounds__(256) void scan1_k(const int* __restrict__ cnt,
                                               int* __restrict__ bsum, int n) {
  int b = blockIdx.x, tid = threadIdx.x;
  int i = b * 256 + tid;
  int v = (i < n) ? cnt[i] : 0;
  int lane = tid & 63, wid = tid >> 6;
  __shared__ int ws[4];
  int s = wave_incl_scan(v, lane);
  if (lane == 63) ws[wid] = s;
  __syncthreads();
  if (tid == 0) bsum[b] = ws[0] + ws[1] + ws[2] + ws[3];
}

// ---- scan stage 2 (+ inv fold) ----
__global__ __launch_bounds__(256) void scan2_k(const int* __restrict__ cnt,
                                               const int* __restrict__ bsum,
                                               int* __restrict__ ofs,
                                               float* __restrict__ inv, int n) {
  int b = blockIdx.x, tid = threadIdx.x;
  int lane = tid & 63, wid = tid >> 6;
  __shared__ int wsA[4], wsB[4];
  int p = 0;
  for (int j = tid; j < b; j += 256) p += bsum[j];
#pragma unroll
  for (int off = 32; off; off >>= 1) p += __shfl_xor(p, off);
  if (lane == 0) wsA[wid] = p;
  __syncthreads();
  int base = wsA[0] + wsA[1] + wsA[2] + wsA[3];
  int i = b * 256 + tid;
  int v = (i < n) ? cnt[i] : 0;
  int s = wave_incl_scan(v, lane);
  if (lane == 63) wsB[wid] = s;
  __syncthreads();
  int woff = 0;
  for (int w = 0; w < wid; w++) woff += wsB[w];
  int excl = base + woff + s - v;
  if (i < n) {
    ofs[i] = excl;
    inv[i] = 1.0f / (float)(v > 1 ? v : 1);
  }
}

// ---- reorder: bucket fill with NO atomics, 2 edges/thread ----
__global__ __launch_bounds__(256)
void reorder4_k(const int* __restrict__ e0, const int* __restrict__ e1,
                const int* __restrict__ e2, const int* __restrict__ e3,
                const int* __restrict__ ofs, const int* __restrict__ pos,
                int* __restrict__ bucket,
                int nE, int b0, int b1, int b2, int b3) {
  int y = blockIdx.y;
  const int* e = y == 0 ? e0 : y == 1 ? e1 : y == 2 ? e2 : e3;
  int base = y == 0 ? b0 : y == 1 ? b1 : y == 2 ? b2 : b3;
#pragma unroll
  for (int u = 0; u < 2; u++) {
    int i = blockIdx.x * 512 + u * 256 + threadIdx.x;
    if (i < nE) {
      int s = e[i];
      int d = e[nE + i];
      int p = pos[(size_t)y * nE + i];
      bucket[ofs[base + d] + p] = s;
    }
  }
}

// ---- CSR gather-mean, GROUP-PER-NODE (R13-proven body), N jobs per launch ----
struct GJob {
  const ushort_t* x;
  const int* ofs;
  const int* cnt;
  const float* inv;
  ushort_t* agg;
  int n;
};

template <int RELU>
__device__ __forceinline__ void agg_body(const GJob& J, const int* bucket) {
  int gwave = (int)(((size_t)blockIdx.x * 256 + threadIdx.x) >> 6);
  int lane = threadIdx.x & 63;
  int g = lane >> 4, sl = lane & 15;
  int node = gwave * 4 + g;
  if (node >= J.n) return;
  int beg = J.ofs[node], c = J.cnt[node];
  float iv = J.inv[node];
  const ushort_t* xsrc = J.x;

  f32x2 a0 = {0.f, 0.f}, a1 = {0.f, 0.f}, a2 = {0.f, 0.f}, a3 = {0.f, 0.f};
  auto accum = [&](uint4 v) {
    f32x2 p0 = {bf_lo(v.x), bf_hi(v.x)};
    f32x2 p1 = {bf_lo(v.y), bf_hi(v.y)};
    f32x2 p2 = {bf_lo(v.z), bf_hi(v.z)};
    f32x2 p3 = {bf_lo(v.w), bf_hi(v.w)};
    if (RELU) {
      p0[0] = fmaxf(p0[0], 0.f); p0[1] = fmaxf(p0[1], 0.f);
      p1[0] = fmaxf(p1[0], 0.f); p1[1] = fmaxf(p1[1], 0.f);
      p2[0] = fmaxf(p2[0], 0.f); p2[1] = fmaxf(p2[1], 0.f);
      p3[0] = fmaxf(p3[0], 0.f); p3[1] = fmaxf(p3[1], 0.f);
    }
    a0 += p0; a1 += p1; a2 += p2; a3 += p3;
  };

  int j = 0;
  for (; j + 2 <= c; j += 2) {
    int s0 = bucket[beg + j], s1 = bucket[beg + j + 1];
    uint4 v0 = *(const uint4*)(xsrc + (size_t)s0 * D128 + sl * 8);
    uint4 v1 = *(const uint4*)(xsrc + (size_t)s1 * D128 + sl * 8);
    accum(v0); accum(v1);
  }
  if (j < c) {
    uint4 v0 = *(const uint4*)(xsrc + (size_t)bucket[beg + j] * D128 + sl * 8);
    accum(v0);
  }

  uint4 o;
  o.x = pack2(a0[0] * iv, a0[1] * iv);
  o.y = pack2(a1[0] * iv, a1[1] * iv);
  o.z = pack2(a2[0] * iv, a2[1] * iv);
  o.w = pack2(a3[0] * iv, a3[1] * iv);
  *(uint4*)(J.agg + (size_t)node * D128 + sl * 8) = o;
}

template <int RELU>
__global__ __launch_bounds__(256)
void agg2_k(GJob A, GJob B, const int* __restrict__ bucket) {
  agg_body<RELU>(blockIdx.y ? B : A, bucket);
}

__global__ __launch_bounds__(256)
void agg4_k(GJob A, GJob B, GJob C, GJob D, const int* __restrict__ bucket) {
  int y = blockIdx.y;
  const GJob& J = y == 0 ? A : y == 1 ? B : y == 2 ? C : D;
  agg_body<0>(J, bucket);
}

// ---- single-edge-type sage body (R16 sage_pair body, 16 waves) ----
struct SJob {
  const ushort_t* agg;
  const ushort_t* x;
  const ushort_t* wl;
  const ushort_t* wr;
  const float* bias;
  ushort_t* out;
  int ntiles;
};

__device__ __forceinline__ void sage_single_body(const SJob& J, char* smem,
                                                 int nthreads) {
  const int tid = threadIdx.x;
  for (int c = tid; c < 4096; c += nthreads) {
    int m = c >> 11, cc = c & 2047;
    int row = cc >> 4, slot = cc & 15;
    const ushort_t* W = m ? J.wr : J.wl;
    uint4 v = *((const uint4*)W + cc);
    *(uint4*)(smem + m * 32768 + row * 256 + ((slot ^ (row & 15)) << 4)) = v;
  }
  __syncthreads();

  int wid = tid >> 6, lane = tid & 63;
  int r = lane & 15, kh = lane >> 4;
  int tile = blockIdx.x * (nthreads >> 6) + wid;
  if (tile >= J.ntiles) return;
  size_t n0 = (size_t)tile * 16;

  const ushort_t* ap = J.agg + (n0 + r) * D128 + kh * 8;
  const ushort_t* xp = J.x + (n0 + r) * D128 + kh * 8;
  uint4 A4[4], X4[4];
#pragma unroll
  for (int kk = 0; kk < 4; kk++) {
    A4[kk] = *(const uint4*)(ap + kk * 32);
    X4[kk] = *(const uint4*)(xp + kk * 32);
  }

  f32x4 acc[8];
#pragma unroll
  for (int t = 0; t < 8; t++) acc[t] = (f32x4){0.f, 0.f, 0.f, 0.f};

#pragma unroll
  for (int kk = 0; kk < 4; kk++) {
    int so = (((kk << 2) + kh) ^ r) << 4;
    bf16x8 af = as_h(A4[kk]);
    bf16x8 xf = as_h(X4[kk]);
#pragma unroll
    for (int t = 0; t < 8; t++) {
      const char* p = smem + t * 4096 + r * 256 + so;
      bf16x8 bwl = *(const bf16x8*)(p);
      bf16x8 bwr = *(const bf16x8*)(p + 32768);
      acc[t] = __builtin_amdgcn_mfma_f32_16x16x32_bf16(af, bwl, acc[t], 0, 0, 0);
      acc[t] = __builtin_amdgcn_mfma_f32_16x16x32_bf16(xf, bwr, acc[t], 0, 0, 0);
    }
  }

  float s[4] = {0.f, 0.f, 0.f, 0.f};
#pragma unroll
  for (int t = 0; t < 8; t++) {
    float bv = J.bias[t * 16 + r];
#pragma unroll
    for (int q = 0; q < 4; q++) {
      float c = acc[t][q] + bv;
      acc[t][q] = c;
      s[q] += c * c;
    }
  }
#pragma unroll
  for (int off = 1; off < 16; off <<= 1) {
#pragma unroll
    for (int q = 0; q < 4; q++) s[q] += __shfl_xor(s[q], off);
  }
  float rn[4];
#pragma unroll
  for (int q = 0; q < 4; q++) rn[q] = 1.0f / fmaxf(sqrtf(s[q]), 1e-12f);

#pragma unroll
  for (int tp = 0; tp < 4; tp++) {
    int t0 = 2 * tp, t1 = 2 * tp + 1;
#pragma unroll
    for (int q = 0; q < 4; q++) {
      float a = fmaxf(acc[t0][q] * rn[q], 0.f);
      float b = fmaxf(acc[t1][q] * rn[q], 0.f);
      size_t node = n0 + kh * 4 + q;
      store_pair_bf16(J.out + node * D128, r, t0, t1, a, b);
    }
  }
}

// ---- dual-edge-type sage body (R16 sage_dual2 body) ----
struct DJob {
  const ushort_t* aggA;
  const ushort_t* aggB;
  const ushort_t* x;
  const ushort_t* wlA;
  const ushort_t* wrA;
  const ushort_t* wlB;
  const ushort_t* wrB;
  const float* biasA;
  const float* biasB;
  void* out;
  int ntiles;
};

template <int CLF>
__device__ __forceinline__ void sage_dual_body(const DJob& J, char* smem,
                                               const float* clfW, const float* clfb) {
  const int tid = threadIdx.x;
  for (int c = tid; c < 8192; c += 1024) {
    int m = c >> 11, cc = c & 2047;
    int row = cc >> 4, slot = cc & 15;
    const ushort_t* W = m == 0 ? J.wlA : m == 1 ? J.wrA : m == 2 ? J.wlB : J.wrB;
    uint4 v = *((const uint4*)W + cc);
    *(uint4*)(smem + m * 32768 + row * 256 + ((slot ^ (row & 15)) << 4)) = v;
  }
  __syncthreads();

  int wid = tid >> 6, lane = tid & 63;
  int r = lane & 15, kh = lane >> 4;
  int tile = blockIdx.x * 16 + wid;
  if (tile >= J.ntiles) return;
  size_t n0 = (size_t)tile * 16;
  size_t rowe = (n0 + r) * D128 + kh * 8;

  uint4 A1[4], A3[4];
  bf16x8 XF[4];
#pragma unroll
  for (int kk = 0; kk < 4; kk++) {
    A1[kk] = *(const uint4*)(J.aggA + rowe + kk * 32);
    A3[kk] = *(const uint4*)(J.aggB + rowe + kk * 32);
    XF[kk] = as_h(*(const uint4*)(J.x + rowe + kk * 32));
  }

  f32x4 acc1[8], acc3[8];
#pragma unroll
  for (int t = 0; t < 8; t++) {
    acc1[t] = (f32x4){0.f, 0.f, 0.f, 0.f};
    acc3[t] = (f32x4){0.f, 0.f, 0.f, 0.f};
  }

#pragma unroll
  for (int kk = 0; kk < 4; kk++) {
    int so = (((kk << 2) + kh) ^ r) << 4;
    bf16x8 af1 = as_h(A1[kk]);
    bf16x8 af3 = as_h(A3[kk]);
    bf16x8 xf = XF[kk];
#pragma unroll
    for (int t = 0; t < 8; t++) {
      const char* p = smem + t * 4096 + r * 256 + so;
      bf16x8 wla = *(const bf16x8*)(p);
      bf16x8 wra = *(const bf16x8*)(p + 32768);
      bf16x8 wlb = *(const bf16x8*)(p + 65536);
      bf16x8 wrb = *(const bf16x8*)(p + 98304);
      acc1[t] = __builtin_amdgcn_mfma_f32_16x16x32_bf16(af1, wla, acc1[t], 0, 0, 0);
      acc1[t] = __builtin_amdgcn_mfma_f32_16x16x32_bf16(xf, wra, acc1[t], 0, 0, 0);
      acc3[t] = __builtin_amdgcn_mfma_f32_16x16x32_bf16(af3, wlb, acc3[t], 0, 0, 0);
      acc3[t] = __builtin_amdgcn_mfma_f32_16x16x32_bf16(xf, wrb, acc3[t], 0, 0, 0);
    }
  }

  float s1[4] = {0.f, 0.f, 0.f, 0.f}, s3[4] = {0.f, 0.f, 0.f, 0.f};
#pragma unroll
  for (int t = 0; t < 8; t++) {
    float bvA = J.biasA[t * 16 + r];
    float bvB = J.biasB[t * 16 + r];
#pragma unroll
    for (int q = 0; q < 4; q++) {
      float c1 = acc1[t][q] + bvA;
      acc1[t][q] = c1; s1[q] += c1 * c1;
      float c3 = acc3[t][q] + bvB;
      acc3[t][q] = c3; s3[q] += c3 * c3;
    }
  }
#pragma unroll
  for (int off = 1; off < 16; off <<= 1) {
#pragma unroll
    for (int q = 0; q < 4; q++) {
      s1[q] += __shfl_xor(s1[q], off);
      s3[q] += __shfl_xor(s3[q], off);
    }
  }
  float rn1[4], rn3[4];
#pragma unroll
  for (int q = 0; q < 4; q++) {
    rn1[q] = 1.0f / fmaxf(sqrtf(s1[q]), 1e-12f);
    rn3[q] = 1.0f / fmaxf(sqrtf(s3[q]), 1e-12f);
  }

  if (CLF) {
    float w0[8], w1[8];
#pragma unroll
    for (int t = 0; t < 8; t++) {
      w0[t] = clfW[t * 16 + r];
      w1[t] = clfW[D128 + t * 16 + r];
    }
    float p0[4] = {0.f, 0.f, 0.f, 0.f}, p1[4] = {0.f, 0.f, 0.f, 0.f};
#pragma unroll
    for (int t = 0; t < 8; t++) {
#pragma unroll
      for (int q = 0; q < 4; q++) {
        float val = acc1[t][q] * rn1[q] + acc3[t][q] * rn3[q];
        p0[q] += val * w0[t];
        p1[q] += val * w1[t];
      }
    }
#pragma unroll
    for (int off = 1; off < 16; off <<= 1) {
#pragma unroll
      for (int q = 0; q < 4; q++) {
        p0[q] += __shfl_xor(p0[q], off);
        p1[q] += __shfl_xor(p1[q], off);
      }
    }
    if (r == 0) {
      float cb0 = clfb[0], cb1 = clfb[1];
#pragma unroll
      for (int q = 0; q < 4; q++) {
        size_t node = n0 + kh * 4 + q;
        float2 o; o.x = p0[q] + cb0; o.y = p1[q] + cb1;
        *(float2*)((float*)J.out + node * 2) = o;
      }
    }
  } else {
#pragma unroll
    for (int tp = 0; tp < 4; tp++) {
      int t0 = 2 * tp, t1 = 2 * tp + 1;
#pragma unroll
      for (int q = 0; q < 4; q++) {
        float a = fmaxf(acc1[t0][q] * rn1[q] + acc3[t0][q] * rn3[q], 0.f);
        float b = fmaxf(acc1[t1][q] * rn1[q] + acc3[t1][q] * rn3[q], 0.f);
        size_t node = n0 + kh * 4 + q;
        store_pair_bf16((ushort_t*)J.out + node * D128, r, t0, t1, a, b);
      }
    }
  }
}

// ---- unified L1 sage: y=0 dual app (h1a), y=1 mer single, y=2 dev single ----
__global__ __launch_bounds__(1024)
void sageL1_k(DJob DJ, SJob S1, SJob S2) {
  extern __shared__ char smem[];
  int y = blockIdx.y;
  if (y == 0) {
    sage_dual_body<0>(DJ, smem, nullptr, nullptr);
  } else {
    const SJob& J = (y == 1) ? S1 : S2;
    if (blockIdx.x * 16 >= J.ntiles) return;
    sage_single_body(J, smem, 1024);
  }
}

// ---- L2 dual + classifier (standalone, R16-proven) ----
__global__ __launch_bounds__(1024)
void sageL2_k(DJob DJ, const float* __restrict__ clfW, const float* __restrict__ clfb) {
  extern __shared__ char smem[];
  sage_dual_body<1>(DJ, smem, clfW, clfb);
}

extern "C" void kernel_launch(void* const* d_in, const int* in_sizes, int n_in,
                              void* d_out, int out_size, void* d_ws, size_t ws_size,
                              hipStream_t stream) {
  const float* emb_app = (const float*)d_in[0];
  const float* emb_mer = (const float*)d_in[1];
  const float* emb_dev = (const float*)d_in[2];
  const float* c1Wl = (const float*)d_in[3];
  const float* c1bl = (const float*)d_in[4];
  const float* c1Wr = (const float*)d_in[5];
  const float* c2Wl = (const float*)d_in[6];
  const float* c2bl = (const float*)d_in[7];
  const float* c2Wr = (const float*)d_in[8];
  const float* clfW = (const float*)d_in[9];
  const float* clfb = (const float*)d_in[10];
  const int* e0 = (const int*)d_in[11];
  const int* e1 = (const int*)d_in[12];
  const int* e2 = (const int*)d_in[13];
  const int* e3 = (const int*)d_in[14];

  const int NA = in_sizes[0] / D128;
  const int NM = in_sizes[1] / D128;
  const int ND = in_sizes[2] / D128;
  const int E = in_sizes[11] / 2;
  float* out = (float*)d_out;

  char* wsb = (char*)d_ws;
  size_t off = 0;
  auto alloc = [&](size_t bytes) -> char* {
    char* p = wsb + off;
    off += (bytes + 511) & ~(size_t)511;
    return p;
  };
  ushort_t* wl1 = (ushort_t*)alloc((size_t)4 * 16384 * 2);
  ushort_t* wr1 = (ushort_t*)alloc((size_t)4 * 16384 * 2);
  ushort_t* wl2 = (ushort_t*)alloc((size_t)4 * 16384 * 2);
  ushort_t* wr2 = (ushort_t*)alloc((size_t)4 * 16384 * 2);

  // overlay region (R9-proven): embeddings bf16 live through layer 1 only
  size_t embBytes = ((size_t)NM + ND + NA) * D128 * 2;
  char* big = alloc(embBytes);
  ushort_t* emer = (ushort_t*)big;
  ushort_t* edev = emer + (size_t)NM * D128;
  ushort_t* eapp = edev + (size_t)ND * D128;

  ushort_t* h1m = (ushort_t*)alloc((size_t)NM * D128 * 2);
  ushort_t* h1d = (ushort_t*)alloc((size_t)ND * D128 * 2);
  ushort_t* h1a = (ushort_t*)alloc((size_t)NA * D128 * 2);  // bf16
  ushort_t* aggA = (ushort_t*)alloc((size_t)NA * D128 * 2);
  ushort_t* aggB = (ushort_t*)alloc((size_t)NA * D128 * 2);
  ushort_t* aggM = (ushort_t*)alloc((size_t)NM * D128 * 2);
  ushort_t* aggD = (ushort_t*)alloc((size_t)ND * D128 * 2);
  int ncnt = NM + NA + ND + NA;
  int nb = (ncnt + 255) / 256;
  int* cnt = (int*)alloc((size_t)ncnt * 4);
  float* inv = (float*)alloc((size_t)ncnt * 4);
  int* ofs = (int*)alloc((size_t)ncnt * 4);
  int* bsum = (int*)alloc((size_t)nb * 4);
  int* pos = (int*)alloc((size_t)4 * E * 4);
  int* bucket = (int*)alloc((size_t)4 * E * 4);
  (void)ws_size;  // ~343 MB (< R14's proven ~355 MB)

  int b0 = 0, b1 = NM, b2 = NM + NA, b3 = NM + NA + ND;

  const int SMEM2 = 131072;
  hipFuncSetAttribute((const void*)sageL1_k,
                      hipFuncAttributeMaxDynamicSharedMemorySize, SMEM2);
  hipFuncSetAttribute((const void*)sageL2_k,
                      hipFuncAttributeMaxDynamicSharedMemorySize, SMEM2);

  // ---- weights cvt + interleaved {embedding cvt ∥ poscount} ----
  dim3 wg(64, 4);
  cvtW_k<<<wg, 256, 0, stream>>>(c1Wl, c1Wr, c2Wl, c2Wr, wl1, wr1, wl2, wr2);
  hipMemsetAsync(cnt, 0, (size_t)ncnt * 4, stream);
  int na4 = NA * 32, nm4 = NM * 32, nd4 = ND * 32;
  int nbC = (na4 + nm4 + nd4 + 255) / 256;
  int nbE4 = (E + 1023) / 1024;
  int nbA = 4 * nbE4;
  pre2_k<<<nbC + nbA, 256, 0, stream>>>(
      emb_app, emb_mer, emb_dev, eapp, emer, edev, na4, nm4, nd4, nbC,
      e0 + E, e1 + E, e2 + E, e3 + E, cnt, pos, E, nbE4, nbA, b0, b1, b2, b3);
  scan1_k<<<nb, 256, 0, stream>>>(cnt, bsum, ncnt);
  scan2_k<<<nb, 256, 0, stream>>>(cnt, bsum, ofs, inv, ncnt);
  dim3 eg((E + 511) / 512, 4);
  reorder4_k<<<eg, 256, 0, stream>>>(e0, e1, e2, e3, ofs, pos, bucket,
                                     E, b0, b1, b2, b3);

  auto ngrid = [](int n) { return (n + 15) / 16; };
  auto g16 = [](int nt) { return (nt + 15) / 16; };
  int tA = NA / 16, tM = NM / 16, tD = ND / 16;

  auto J = [&](const ushort_t* x, int b, ushort_t* a, int n) {
    GJob j; j.x = x; j.ofs = ofs + b; j.cnt = cnt + b; j.inv = inv + b;
    j.agg = a; j.n = n; return j;
  };

  // ---- layer 1: ALL 4 gathers in one launch ----
  {
    dim3 gg(ngrid(NA), 4);
    agg4_k<<<gg, 256, 0, stream>>>(
        J(eapp, b0, aggM, NM),   // k0: app -> mer
        J(eapp, b2, aggD, ND),   // k2: app -> dev
        J(emer, b1, aggA, NA),   // k1: mer -> app
        J(edev, b3, aggB, NA),   // k3: dev -> app
        bucket);
  }
  // ---- layer 1: all 3 sage jobs in one launch ----
  {
    DJob DJ; DJ.aggA = aggA; DJ.aggB = aggB; DJ.x = eapp;
    DJ.wlA = wl1 + 1 * 16384; DJ.wrA = wr1 + 1 * 16384;
    DJ.wlB = wl1 + 3 * 16384; DJ.wrB = wr1 + 3 * 16384;
    DJ.biasA = c1bl + 1 * D128; DJ.biasB = c1bl + 3 * D128;
    DJ.out = h1a; DJ.ntiles = tA;
    SJob S1; S1.agg = aggM; S1.x = emer; S1.wl = wl1 + 0 * 16384;
    S1.wr = wr1 + 0 * 16384; S1.bias = c1bl + 0 * D128; S1.out = h1m; S1.ntiles = tM;
    SJob S2; S2.agg = aggD; S2.x = edev; S2.wl = wl1 + 2 * 16384;
    S2.wr = wr1 + 2 * 16384; S2.bias = c1bl + 2 * D128; S2.out = h1d; S2.ntiles = tD;
    dim3 sg(g16(tA), 3);
    sageL1_k<<<sg, 1024, SMEM2, stream>>>(DJ, S1, S2);
  }

  // ---- layer 2: gathers (relu'd h1m/h1d) then dual + fused classifier ----
  {
    dim3 gg(ngrid(NA), 2);
    agg2_k<1><<<gg, 256, 0, stream>>>(J(h1m, b1, aggA, NA), J(h1d, b3, aggB, NA), bucket);
  }
  {
    DJob DJ; DJ.aggA = aggA; DJ.aggB = aggB; DJ.x = h1a;
    DJ.wlA = wl2 + 1 * 16384; DJ.wrA = wr2 + 1 * 16384;
    DJ.wlB = wl2 + 3 * 16384; DJ.wrB = wr2 + 3 * 16384;
    DJ.biasA = c2bl + 1 * D128; DJ.biasB = c2bl + 3 * D128;
    DJ.out = out; DJ.ntiles = tA;
    sageL2_k<<<g16(tA), 1024, SMEM2, stream>>>(DJ, clfW, clfb);
  }
}

// Round 18
// 438.903 us; speedup vs baseline: 1.6635x; 1.0910x over previous
//
#include <hip/hip_runtime.h>
#include <hip/hip_bf16.h>

#define D128 128

typedef __attribute__((ext_vector_type(8))) short bf16x8;
typedef __attribute__((ext_vector_type(4))) float f32x4;
typedef __attribute__((ext_vector_type(2))) float f32x2;
typedef unsigned int uint;
typedef unsigned short ushort_t;

union U4 { uint4 u; bf16x8 h; };
__device__ __forceinline__ bf16x8 as_h(uint4 u) { U4 x; x.u = u; return x.h; }

__device__ __forceinline__ short f2bf(float f) {
  union { float f; unsigned u; } v; v.f = f;
  unsigned r = v.u + 0x7FFFu + ((v.u >> 16) & 1u);  // RNE
  return (short)(r >> 16);
}
__device__ __forceinline__ float bf_lo(uint v) {
  union { uint u; float f; } x; x.u = v << 16; return x.f;
}
__device__ __forceinline__ float bf_hi(uint v) {
  union { uint u; float f; } x; x.u = v & 0xFFFF0000u; return x.f;
}
__device__ __forceinline__ uint pack2(float a, float b) {
  return (uint)(unsigned short)f2bf(a) | ((uint)(unsigned short)f2bf(b) << 16);
}

// bf16 row write, 64B-contiguous per node per instruction (R16-proven)
__device__ __forceinline__ void store_pair_bf16(ushort_t* rowp, int r,
                                                int t0, int t1, float a, float b) {
  float sa = __shfl_xor(a, 1);
  float sb = __shfl_xor(b, 1);
  uint w; int colb;
  if ((r & 1) == 0) { w = pack2(a, sa); colb = t0 * 16 + r; }
  else             { w = pack2(sb, b); colb = t1 * 16 + (r - 1); }
  *(uint*)(rowp + colb) = w;
}

// ---- 4 weight tensors in one launch ----
__global__ __launch_bounds__(256)
void cvtW_k(const float* __restrict__ w0, const float* __restrict__ w1,
            const float* __restrict__ w2, const float* __restrict__ w3,
            ushort_t* __restrict__ o0, ushort_t* __restrict__ o1,
            ushort_t* __restrict__ o2, ushort_t* __restrict__ o3) {
  int y = blockIdx.y;
  const float* in = y == 0 ? w0 : y == 1 ? w1 : y == 2 ? w2 : w3;
  ushort_t* out = y == 0 ? o0 : y == 1 ? o1 : y == 2 ? o2 : o3;
  int i = blockIdx.x * 256 + threadIdx.x;
  if (i >= 16384) return;
  float4 v = ((const float4*)in)[i];
  ushort4 o;
  o.x = (unsigned short)f2bf(v.x); o.y = (unsigned short)f2bf(v.y);
  o.z = (unsigned short)f2bf(v.z); o.w = (unsigned short)f2bf(v.w);
  ((ushort4*)out)[i] = o;
}

// ---- fused preprocessing, interleaved cvt ∥ poscount (R11-proven) ----
__global__ __launch_bounds__(256)
void pre2_k(const float* __restrict__ ia, const float* __restrict__ im,
            const float* __restrict__ id, ushort_t* __restrict__ oa,
            ushort_t* __restrict__ om, ushort_t* __restrict__ od,
            int na4, int nm4, int nd4, int nbC,
            const int* __restrict__ d0, const int* __restrict__ d1,
            const int* __restrict__ d2, const int* __restrict__ d3,
            int* __restrict__ cnt, int* __restrict__ pos,
            int nE, int nbE4, int nbA,
            int b0, int b1, int b2, int b3) {
  int bx = blockIdx.x, tid = threadIdx.x;
  int total = nbC + nbA;
  long long s = ((long long)bx * nbA) / total;
  long long t = ((long long)(bx + 1) * nbA) / total;
  if (t > s) {
    int ab = (int)s;
    int y = ab / nbE4;
    int blk = ab - y * nbE4;
    const int* d = y == 0 ? d0 : y == 1 ? d1 : y == 2 ? d2 : d3;
    int base = y == 0 ? b0 : y == 1 ? b1 : y == 2 ? b2 : b3;
#pragma unroll
    for (int u = 0; u < 4; u++) {
      int i = blk * 1024 + u * 256 + tid;
      if (i < nE) {
        int p = atomicAdd(&cnt[base + d[i]], 1);
        pos[(size_t)y * nE + i] = p;
      }
    }
  } else {
    int i = (int)(bx - s) * 256 + tid;
    const float* in; ushort_t* out; int k;
    if (i < na4) { in = ia; out = oa; k = i; }
    else if (i < na4 + nm4) { in = im; out = om; k = i - na4; }
    else if (i < na4 + nm4 + nd4) { in = id; out = od; k = i - na4 - nm4; }
    else return;
    float4 v = ((const float4*)in)[k];
    ushort4 o;
    o.x = (unsigned short)f2bf(v.x); o.y = (unsigned short)f2bf(v.y);
    o.z = (unsigned short)f2bf(v.z); o.w = (unsigned short)f2bf(v.w);
    ((ushort4*)out)[k] = o;
  }
}

// ---- scan stage 1 ----
__device__ __forceinline__ int wave_incl_scan(int v, int lane) {
#pragma unroll
  for (int off = 1; off < 64; off <<= 1) {
    int y = __shfl_up(v, off);
    if (lane >= off) v += y;
  }
  return v;
}

__global__ __launch_bounds__(256) void scan1_k(const int* __restrict__ cnt,
                                               int* __restrict__ bsum, int n) {
  int b = blockIdx.x, tid = threadIdx.x;
  int i = b * 256 + tid;
  int v = (i < n) ? cnt[i] : 0;
  int lane = tid & 63, wid = tid >> 6;
  __shared__ int ws[4];
  int s = wave_incl_scan(v, lane);
  if (lane == 63) ws[wid] = s;
  __syncthreads();
  if (tid == 0) bsum[b] = ws[0] + ws[1] + ws[2] + ws[3];
}

// ---- scan stage 2 (+ inv fold) ----
__global__ __launch_bounds__(256) void scan2_k(const int* __restrict__ cnt,
                                               const int* __restrict__ bsum,
                                               int* __restrict__ ofs,
                                               float* __restrict__ inv, int n) {
  int b = blockIdx.x, tid = threadIdx.x;
  int lane = tid & 63, wid = tid >> 6;
  __shared__ int wsA[4], wsB[4];
  int p = 0;
  for (int j = tid; j < b; j += 256) p += bsum[j];
#pragma unroll
  for (int off = 32; off; off >>= 1) p += __shfl_xor(p, off);
  if (lane == 0) wsA[wid] = p;
  __syncthreads();
  int base = wsA[0] + wsA[1] + wsA[2] + wsA[3];
  int i = b * 256 + tid;
  int v = (i < n) ? cnt[i] : 0;
  int s = wave_incl_scan(v, lane);
  if (lane == 63) wsB[wid] = s;
  __syncthreads();
  int woff = 0;
  for (int w = 0; w < wid; w++) woff += wsB[w];
  int excl = base + woff + s - v;
  if (i < n) {
    ofs[i] = excl;
    inv[i] = 1.0f / (float)(v > 1 ? v : 1);
  }
}

// ---- reorder: bucket fill with NO atomics, 2 edges/thread ----
__global__ __launch_bounds__(256)
void reorder4_k(const int* __restrict__ e0, const int* __restrict__ e1,
                const int* __restrict__ e2, const int* __restrict__ e3,
                const int* __restrict__ ofs, const int* __restrict__ pos,
                int* __restrict__ bucket,
                int nE, int b0, int b1, int b2, int b3) {
  int y = blockIdx.y;
  const int* e = y == 0 ? e0 : y == 1 ? e1 : y == 2 ? e2 : e3;
  int base = y == 0 ? b0 : y == 1 ? b1 : y == 2 ? b2 : b3;
#pragma unroll
  for (int u = 0; u < 2; u++) {
    int i = blockIdx.x * 512 + u * 256 + threadIdx.x;
    if (i < nE) {
      int s = e[i];
      int d = e[nE + i];
      int p = pos[(size_t)y * nE + i];
      bucket[ofs[base + d] + p] = s;
    }
  }
}

// ---- in-register CSR gather -> MFMA A-fragments ----
//  Lane (r,kh) gathers node (n0+r)'s neighbors; accumulates f32 for its 4
//  16B fragment chunks [kk*32 + kh*8 .. +8); packs *iv to bf16.
//  Identical rounding to the old agg-buffer path (f32 sum -> *inv -> bf16).
__device__ __forceinline__ void gather_frags(const ushort_t* __restrict__ xsrc,
                                             const int* __restrict__ bucket,
                                             int beg, int c, float iv, int kh,
                                             uint4 out[4]) {
  f32x2 ac[4][4];
#pragma unroll
  for (int kk = 0; kk < 4; kk++)
#pragma unroll
    for (int p = 0; p < 4; p++) ac[kk][p] = (f32x2){0.f, 0.f};

  auto addv = [&](int kk, uint4 v) {
    f32x2 p0 = {bf_lo(v.x), bf_hi(v.x)};
    f32x2 p1 = {bf_lo(v.y), bf_hi(v.y)};
    f32x2 p2 = {bf_lo(v.z), bf_hi(v.z)};
    f32x2 p3 = {bf_lo(v.w), bf_hi(v.w)};
    ac[kk][0] += p0; ac[kk][1] += p1; ac[kk][2] += p2; ac[kk][3] += p3;
  };

  const ushort_t* base = xsrc + kh * 8;
  int j = 0;
  for (; j + 2 <= c; j += 2) {
    const ushort_t* r0 = base + (size_t)bucket[beg + j] * D128;
    const ushort_t* r1 = base + (size_t)bucket[beg + j + 1] * D128;
    uint4 v00 = *(const uint4*)(r0);
    uint4 v01 = *(const uint4*)(r0 + 32);
    uint4 v02 = *(const uint4*)(r0 + 64);
    uint4 v03 = *(const uint4*)(r0 + 96);
    uint4 v10 = *(const uint4*)(r1);
    uint4 v11 = *(const uint4*)(r1 + 32);
    uint4 v12 = *(const uint4*)(r1 + 64);
    uint4 v13 = *(const uint4*)(r1 + 96);
    addv(0, v00); addv(1, v01); addv(2, v02); addv(3, v03);
    addv(0, v10); addv(1, v11); addv(2, v12); addv(3, v13);
  }
  if (j < c) {
    const ushort_t* r0 = base + (size_t)bucket[beg + j] * D128;
    addv(0, *(const uint4*)(r0));
    addv(1, *(const uint4*)(r0 + 32));
    addv(2, *(const uint4*)(r0 + 64));
    addv(3, *(const uint4*)(r0 + 96));
  }
#pragma unroll
  for (int kk = 0; kk < 4; kk++) {
    uint4 o;
    o.x = pack2(ac[kk][0][0] * iv, ac[kk][0][1] * iv);
    o.y = pack2(ac[kk][1][0] * iv, ac[kk][1][1] * iv);
    o.z = pack2(ac[kk][2][0] * iv, ac[kk][2][1] * iv);
    o.w = pack2(ac[kk][3][0] * iv, ac[kk][3][1] * iv);
    out[kk] = o;
  }
}

// ---- fused gather+SAGE, single edge type ----
struct SJob {
  const ushort_t* xs;   // gather source rows
  const int* ofs;
  const int* cnt;
  const float* inv;
  const ushort_t* xd;   // dense lin_r input
  const ushort_t* wl;
  const ushort_t* wr;
  const float* bias;
  ushort_t* out;
  int ntiles;
};

__device__ __forceinline__ void sage_single_fused(const SJob& J, char* smem,
                                                  const int* __restrict__ bucket) {
  const int tid = threadIdx.x;
  for (int c = tid; c < 4096; c += 1024) {
    int m = c >> 11, cc = c & 2047;
    int row = cc >> 4, slot = cc & 15;
    const ushort_t* W = m ? J.wr : J.wl;
    uint4 v = *((const uint4*)W + cc);
    *(uint4*)(smem + m * 32768 + row * 256 + ((slot ^ (row & 15)) << 4)) = v;
  }
  __syncthreads();

  int wid = tid >> 6, lane = tid & 63;
  int r = lane & 15, kh = lane >> 4;
  int tile = blockIdx.x * 16 + wid;
  if (tile >= J.ntiles) return;
  size_t n0 = (size_t)tile * 16;
  int node = (int)n0 + r;

  uint4 A4[4];
  gather_frags(J.xs, bucket, J.ofs[node], J.cnt[node], J.inv[node], kh, A4);

  const ushort_t* xp = J.xd + (n0 + r) * D128 + kh * 8;
  uint4 X4[4];
#pragma unroll
  for (int kk = 0; kk < 4; kk++) X4[kk] = *(const uint4*)(xp + kk * 32);

  f32x4 acc[8];
#pragma unroll
  for (int t = 0; t < 8; t++) acc[t] = (f32x4){0.f, 0.f, 0.f, 0.f};

#pragma unroll
  for (int kk = 0; kk < 4; kk++) {
    int so = (((kk << 2) + kh) ^ r) << 4;
    bf16x8 af = as_h(A4[kk]);
    bf16x8 xf = as_h(X4[kk]);
#pragma unroll
    for (int t = 0; t < 8; t++) {
      const char* p = smem + t * 4096 + r * 256 + so;
      bf16x8 bwl = *(const bf16x8*)(p);
      bf16x8 bwr = *(const bf16x8*)(p + 32768);
      acc[t] = __builtin_amdgcn_mfma_f32_16x16x32_bf16(af, bwl, acc[t], 0, 0, 0);
      acc[t] = __builtin_amdgcn_mfma_f32_16x16x32_bf16(xf, bwr, acc[t], 0, 0, 0);
    }
  }

  float s[4] = {0.f, 0.f, 0.f, 0.f};
#pragma unroll
  for (int t = 0; t < 8; t++) {
    float bv = J.bias[t * 16 + r];
#pragma unroll
    for (int q = 0; q < 4; q++) {
      float c = acc[t][q] + bv;
      acc[t][q] = c;
      s[q] += c * c;
    }
  }
#pragma unroll
  for (int off = 1; off < 16; off <<= 1) {
#pragma unroll
    for (int q = 0; q < 4; q++) s[q] += __shfl_xor(s[q], off);
  }
  float rn[4];
#pragma unroll
  for (int q = 0; q < 4; q++) rn[q] = 1.0f / fmaxf(sqrtf(s[q]), 1e-12f);

#pragma unroll
  for (int tp = 0; tp < 4; tp++) {
    int t0 = 2 * tp, t1 = 2 * tp + 1;
#pragma unroll
    for (int q = 0; q < 4; q++) {
      float a = fmaxf(acc[t0][q] * rn[q], 0.f);
      float b = fmaxf(acc[t1][q] * rn[q], 0.f);
      size_t nd = n0 + kh * 4 + q;
      store_pair_bf16(J.out + nd * D128, r, t0, t1, a, b);
    }
  }
}

// ---- fused gather+SAGE, dual edge type (app dst) ----
struct DJob {
  const ushort_t* xsA;
  const int* ofsA;
  const int* cntA;
  const float* invA;
  const ushort_t* xsB;
  const int* ofsB;
  const int* cntB;
  const float* invB;
  const ushort_t* xd;
  const ushort_t* wlA;
  const ushort_t* wrA;
  const ushort_t* wlB;
  const ushort_t* wrB;
  const float* biasA;
  const float* biasB;
  void* out;
  int ntiles;
};

template <int CLF>
__device__ __forceinline__ void sage_dual_fused(const DJob& J, char* smem,
                                                const int* __restrict__ bucket,
                                                const float* clfW, const float* clfb) {
  const int tid = threadIdx.x;
  for (int c = tid; c < 8192; c += 1024) {
    int m = c >> 11, cc = c & 2047;
    int row = cc >> 4, slot = cc & 15;
    const ushort_t* W = m == 0 ? J.wlA : m == 1 ? J.wrA : m == 2 ? J.wlB : J.wrB;
    uint4 v = *((const uint4*)W + cc);
    *(uint4*)(smem + m * 32768 + row * 256 + ((slot ^ (row & 15)) << 4)) = v;
  }
  __syncthreads();

  int wid = tid >> 6, lane = tid & 63;
  int r = lane & 15, kh = lane >> 4;
  int tile = blockIdx.x * 16 + wid;
  if (tile >= J.ntiles) return;
  size_t n0 = (size_t)tile * 16;
  int node = (int)n0 + r;

  uint4 A1[4], A3[4];
  gather_frags(J.xsA, bucket, J.ofsA[node], J.cntA[node], J.invA[node], kh, A1);
  gather_frags(J.xsB, bucket, J.ofsB[node], J.cntB[node], J.invB[node], kh, A3);

  const ushort_t* xp = J.xd + (n0 + r) * D128 + kh * 8;
  uint4 X4[4];
#pragma unroll
  for (int kk = 0; kk < 4; kk++) X4[kk] = *(const uint4*)(xp + kk * 32);

  f32x4 acc1[8], acc3[8];
#pragma unroll
  for (int t = 0; t < 8; t++) {
    acc1[t] = (f32x4){0.f, 0.f, 0.f, 0.f};
    acc3[t] = (f32x4){0.f, 0.f, 0.f, 0.f};
  }

#pragma unroll
  for (int kk = 0; kk < 4; kk++) {
    int so = (((kk << 2) + kh) ^ r) << 4;
    bf16x8 af1 = as_h(A1[kk]);
    bf16x8 af3 = as_h(A3[kk]);
    bf16x8 xf = as_h(X4[kk]);
#pragma unroll
    for (int t = 0; t < 8; t++) {
      const char* p = smem + t * 4096 + r * 256 + so;
      bf16x8 wla = *(const bf16x8*)(p);
      bf16x8 wra = *(const bf16x8*)(p + 32768);
      bf16x8 wlb = *(const bf16x8*)(p + 65536);
      bf16x8 wrb = *(const bf16x8*)(p + 98304);
      acc1[t] = __builtin_amdgcn_mfma_f32_16x16x32_bf16(af1, wla, acc1[t], 0, 0, 0);
      acc1[t] = __builtin_amdgcn_mfma_f32_16x16x32_bf16(xf, wra, acc1[t], 0, 0, 0);
      acc3[t] = __builtin_amdgcn_mfma_f32_16x16x32_bf16(af3, wlb, acc3[t], 0, 0, 0);
      acc3[t] = __builtin_amdgcn_mfma_f32_16x16x32_bf16(xf, wrb, acc3[t], 0, 0, 0);
    }
  }

  float s1[4] = {0.f, 0.f, 0.f, 0.f}, s3[4] = {0.f, 0.f, 0.f, 0.f};
#pragma unroll
  for (int t = 0; t < 8; t++) {
    float bvA = J.biasA[t * 16 + r];
    float bvB = J.biasB[t * 16 + r];
#pragma unroll
    for (int q = 0; q < 4; q++) {
      float c1 = acc1[t][q] + bvA;
      acc1[t][q] = c1; s1[q] += c1 * c1;
      float c3 = acc3[t][q] + bvB;
      acc3[t][q] = c3; s3[q] += c3 * c3;
    }
  }
#pragma unroll
  for (int off = 1; off < 16; off <<= 1) {
#pragma unroll
    for (int q = 0; q < 4; q++) {
      s1[q] += __shfl_xor(s1[q], off);
      s3[q] += __shfl_xor(s3[q], off);
    }
  }
  float rn1[4], rn3[4];
#pragma unroll
  for (int q = 0; q < 4; q++) {
    rn1[q] = 1.0f / fmaxf(sqrtf(s1[q]), 1e-12f);
    rn3[q] = 1.0f / fmaxf(sqrtf(s3[q]), 1e-12f);
  }

  if (CLF) {
    float w0[8], w1[8];
#pragma unroll
    for (int t = 0; t < 8; t++) {
      w0[t] = clfW[t * 16 + r];
      w1[t] = clfW[D128 + t * 16 + r];
    }
    float p0[4] = {0.f, 0.f, 0.f, 0.f}, p1[4] = {0.f, 0.f, 0.f, 0.f};
#pragma unroll
    for (int t = 0; t < 8; t++) {
#pragma unroll
      for (int q = 0; q < 4; q++) {
        float val = acc1[t][q] * rn1[q] + acc3[t][q] * rn3[q];
        p0[q] += val * w0[t];
        p1[q] += val * w1[t];
      }
    }
#pragma unroll
    for (int off = 1; off < 16; off <<= 1) {
#pragma unroll
      for (int q = 0; q < 4; q++) {
        p0[q] += __shfl_xor(p0[q], off);
        p1[q] += __shfl_xor(p1[q], off);
      }
    }
    if (r == 0) {
      float cb0 = clfb[0], cb1 = clfb[1];
#pragma unroll
      for (int q = 0; q < 4; q++) {
        size_t nd = n0 + kh * 4 + q;
        float2 o; o.x = p0[q] + cb0; o.y = p1[q] + cb1;
        *(float2*)((float*)J.out + nd * 2) = o;
      }
    }
  } else {
#pragma unroll
    for (int tp = 0; tp < 4; tp++) {
      int t0 = 2 * tp, t1 = 2 * tp + 1;
#pragma unroll
      for (int q = 0; q < 4; q++) {
        float a = fmaxf(acc1[t0][q] * rn1[q] + acc3[t0][q] * rn3[q], 0.f);
        float b = fmaxf(acc1[t1][q] * rn1[q] + acc3[t1][q] * rn3[q], 0.f);
        size_t nd = n0 + kh * 4 + q;
        store_pair_bf16((ushort_t*)J.out + nd * D128, r, t0, t1, a, b);
      }
    }
  }
}

// ---- L1: y=0 dual app (h1a), y=1 mer single, y=2 dev single ----
__global__ __launch_bounds__(1024)
void sageL1_k(DJob DJ, SJob S1, SJob S2, const int* __restrict__ bucket) {
  extern __shared__ char smem[];
  int y = blockIdx.y;
  if (y == 0) {
    sage_dual_fused<0>(DJ, smem, bucket, nullptr, nullptr);
  } else {
    const SJob& J = (y == 1) ? S1 : S2;
    if (blockIdx.x * 16 >= J.ntiles) return;
    sage_single_fused(J, smem, bucket);
  }
}

// ---- L2: dual + classifier ----
__global__ __launch_bounds__(1024)
void sageL2_k(DJob DJ, const int* __restrict__ bucket,
              const float* __restrict__ clfW, const float* __restrict__ clfb) {
  extern __shared__ char smem[];
  sage_dual_fused<1>(DJ, smem, bucket, clfW, clfb);
}

extern "C" void kernel_launch(void* const* d_in, const int* in_sizes, int n_in,
                              void* d_out, int out_size, void* d_ws, size_t ws_size,
                              hipStream_t stream) {
  const float* emb_app = (const float*)d_in[0];
  const float* emb_mer = (const float*)d_in[1];
  const float* emb_dev = (const float*)d_in[2];
  const float* c1Wl = (const float*)d_in[3];
  const float* c1bl = (const float*)d_in[4];
  const float* c1Wr = (const float*)d_in[5];
  const float* c2Wl = (const float*)d_in[6];
  const float* c2bl = (const float*)d_in[7];
  const float* c2Wr = (const float*)d_in[8];
  const float* clfW = (const float*)d_in[9];
  const float* clfb = (const float*)d_in[10];
  const int* e0 = (const int*)d_in[11];
  const int* e1 = (const int*)d_in[12];
  const int* e2 = (const int*)d_in[13];
  const int* e3 = (const int*)d_in[14];

  const int NA = in_sizes[0] / D128;
  const int NM = in_sizes[1] / D128;
  const int ND = in_sizes[2] / D128;
  const int E = in_sizes[11] / 2;
  float* out = (float*)d_out;

  char* wsb = (char*)d_ws;
  size_t off = 0;
  auto alloc = [&](size_t bytes) -> char* {
    char* p = wsb + off;
    off += (bytes + 511) & ~(size_t)511;
    return p;
  };
  ushort_t* wl1 = (ushort_t*)alloc((size_t)4 * 16384 * 2);
  ushort_t* wr1 = (ushort_t*)alloc((size_t)4 * 16384 * 2);
  ushort_t* wl2 = (ushort_t*)alloc((size_t)4 * 16384 * 2);
  ushort_t* wr2 = (ushort_t*)alloc((size_t)4 * 16384 * 2);

  // embeddings bf16 (live through layer 1)
  size_t embBytes = ((size_t)NM + ND + NA) * D128 * 2;
  char* big = alloc(embBytes);
  ushort_t* emer = (ushort_t*)big;
  ushort_t* edev = emer + (size_t)NM * D128;
  ushort_t* eapp = edev + (size_t)ND * D128;

  ushort_t* h1m = (ushort_t*)alloc((size_t)NM * D128 * 2);
  ushort_t* h1d = (ushort_t*)alloc((size_t)ND * D128 * 2);
  ushort_t* h1a = (ushort_t*)alloc((size_t)NA * D128 * 2);
  int ncnt = NM + NA + ND + NA;
  int nb = (ncnt + 255) / 256;
  int* cnt = (int*)alloc((size_t)ncnt * 4);
  float* inv = (float*)alloc((size_t)ncnt * 4);
  int* ofs = (int*)alloc((size_t)ncnt * 4);
  int* bsum = (int*)alloc((size_t)nb * 4);
  int* pos = (int*)alloc((size_t)4 * E * 4);
  int* bucket = (int*)alloc((size_t)4 * E * 4);
  (void)ws_size;  // ~205 MB

  int b0 = 0, b1 = NM, b2 = NM + NA, b3 = NM + NA + ND;

  const int SMEM2 = 131072;
  hipFuncSetAttribute((const void*)sageL1_k,
                      hipFuncAttributeMaxDynamicSharedMemorySize, SMEM2);
  hipFuncSetAttribute((const void*)sageL2_k,
                      hipFuncAttributeMaxDynamicSharedMemorySize, SMEM2);

  // ---- weights cvt + interleaved {embedding cvt ∥ poscount} ----
  dim3 wg(64, 4);
  cvtW_k<<<wg, 256, 0, stream>>>(c1Wl, c1Wr, c2Wl, c2Wr, wl1, wr1, wl2, wr2);
  hipMemsetAsync(cnt, 0, (size_t)ncnt * 4, stream);
  int na4 = NA * 32, nm4 = NM * 32, nd4 = ND * 32;
  int nbC = (na4 + nm4 + nd4 + 255) / 256;
  int nbE4 = (E + 1023) / 1024;
  int nbA = 4 * nbE4;
  pre2_k<<<nbC + nbA, 256, 0, stream>>>(
      emb_app, emb_mer, emb_dev, eapp, emer, edev, na4, nm4, nd4, nbC,
      e0 + E, e1 + E, e2 + E, e3 + E, cnt, pos, E, nbE4, nbA, b0, b1, b2, b3);
  scan1_k<<<nb, 256, 0, stream>>>(cnt, bsum, ncnt);
  scan2_k<<<nb, 256, 0, stream>>>(cnt, bsum, ofs, inv, ncnt);
  dim3 eg((E + 511) / 512, 4);
  reorder4_k<<<eg, 256, 0, stream>>>(e0, e1, e2, e3, ofs, pos, bucket,
                                     E, b0, b1, b2, b3);

  auto g16 = [](int nt) { return (nt + 15) / 16; };
  int tA = NA / 16, tM = NM / 16, tD = ND / 16;

  // ---- layer 1: all 4 gathers fused into the 3 sage jobs, one launch ----
  {
    DJob DJ;
    DJ.xsA = emer; DJ.ofsA = ofs + b1; DJ.cntA = cnt + b1; DJ.invA = inv + b1;
    DJ.xsB = edev; DJ.ofsB = ofs + b3; DJ.cntB = cnt + b3; DJ.invB = inv + b3;
    DJ.xd = eapp;
    DJ.wlA = wl1 + 1 * 16384; DJ.wrA = wr1 + 1 * 16384;
    DJ.wlB = wl1 + 3 * 16384; DJ.wrB = wr1 + 3 * 16384;
    DJ.biasA = c1bl + 1 * D128; DJ.biasB = c1bl + 3 * D128;
    DJ.out = h1a; DJ.ntiles = tA;
    SJob S1;
    S1.xs = eapp; S1.ofs = ofs + b0; S1.cnt = cnt + b0; S1.inv = inv + b0;
    S1.xd = emer; S1.wl = wl1 + 0 * 16384; S1.wr = wr1 + 0 * 16384;
    S1.bias = c1bl + 0 * D128; S1.out = h1m; S1.ntiles = tM;
    SJob S2;
    S2.xs = eapp; S2.ofs = ofs + b2; S2.cnt = cnt + b2; S2.inv = inv + b2;
    S2.xd = edev; S2.wl = wl1 + 2 * 16384; S2.wr = wr1 + 2 * 16384;
    S2.bias = c1bl + 2 * D128; S2.out = h1d; S2.ntiles = tD;
    dim3 sg(g16(tA), 3);
    sageL1_k<<<sg, 1024, SMEM2, stream>>>(DJ, S1, S2, bucket);
  }

  // ---- layer 2: fused gathers (h1m/h1d post-relu) + dual + classifier ----
  {
    DJob DJ;
    DJ.xsA = h1m; DJ.ofsA = ofs + b1; DJ.cntA = cnt + b1; DJ.invA = inv + b1;
    DJ.xsB = h1d; DJ.ofsB = ofs + b3; DJ.cntB = cnt + b3; DJ.invB = inv + b3;
    DJ.xd = h1a;
    DJ.wlA = wl2 + 1 * 16384; DJ.wrA = wr2 + 1 * 16384;
    DJ.wlB = wl2 + 3 * 16384; DJ.wrB = wr2 + 3 * 16384;
    DJ.biasA = c2bl + 1 * D128; DJ.biasB = c2bl + 3 * D128;
    DJ.out = out; DJ.ntiles = tA;
    sageL2_k<<<g16(tA), 1024, SMEM2, stream>>>(DJ, bucket, clfW, clfb);
  }
}